// Round 2
// baseline (1683.332 us; speedup 1.0000x reference)
//
#include <hip/hip_runtime.h>
#include <hip/hip_bf16.h>

#define D_MODEL   1024
#define D_STATE   16
#define D_HEAD    64
#define D_CONV    4
#define FFN_DIM   2816
#define D_INNER   2048
#define N_HEADS   32
#define BATCH     4
#define SEQ       2048
#define ROWS      (BATCH*SEQ)     // 8192
#define PROJ_DIM  4160
#define PROJ_PAD  4224            // 33 * 128
#define CONV_CH   2080            // D_INNER + 2*D_STATE

typedef __bf16 bf16x8 __attribute__((ext_vector_type(8)));
typedef float  f32x4  __attribute__((ext_vector_type(4)));

__device__ __forceinline__ float siluf(float x) { return x / (1.0f + __expf(-x)); }

// ---------------------------------------------------------------- converts
__global__ void cvt_k(const float* __restrict__ src, __hip_bfloat16* __restrict__ dst, int n) {
  int i = blockIdx.x * blockDim.x + threadIdx.x;
  if (i < n) dst[i] = __float2bfloat16(src[i]);
}

// in_proj: [4160][1024] f32 -> [4224][1024] bf16, zero-padded rows
__global__ void cvt_pad_k(const float* __restrict__ src, __hip_bfloat16* __restrict__ dst) {
  int i = blockIdx.x * blockDim.x + threadIdx.x;
  if (i >= PROJ_PAD * D_MODEL) return;
  int row = i >> 10;
  dst[i] = (row < PROJ_DIM) ? __float2bfloat16(src[i]) : __float2bfloat16(0.0f);
}

// ---------------------------------------------------------------- rmsnorm (f32 in -> bf16 out, optional f32 out)
__global__ __launch_bounds__(256) void rmsnorm_k(const float* __restrict__ x,
                                                 const float* __restrict__ w,
                                                 __hip_bfloat16* __restrict__ out,
                                                 float* __restrict__ outf) {
  int row = blockIdx.x;
  int t = threadIdx.x;
  const float* xr = x + (size_t)row * D_MODEL;
  float4 v = ((const float4*)xr)[t];            // 256 threads * 4 = 1024
  float ss = v.x*v.x + v.y*v.y + v.z*v.z + v.w*v.w;
  #pragma unroll
  for (int o = 32; o > 0; o >>= 1) ss += __shfl_xor(ss, o);
  __shared__ float red[4];
  if ((t & 63) == 0) red[t >> 6] = ss;
  __syncthreads();
  ss = red[0] + red[1] + red[2] + red[3];
  float scale = rsqrtf(ss * (1.0f / D_MODEL) + 1e-6f);
  float4 wv = ((const float4*)w)[t];
  float4 r;
  r.x = v.x * scale * wv.x; r.y = v.y * scale * wv.y;
  r.z = v.z * scale * wv.z; r.w = v.w * scale * wv.w;
  __hip_bfloat16* orow = out + (size_t)row * D_MODEL + t * 4;
  orow[0] = __float2bfloat16(r.x);
  orow[1] = __float2bfloat16(r.y);
  orow[2] = __float2bfloat16(r.z);
  orow[3] = __float2bfloat16(r.w);
  if (outf) ((float4*)(outf + (size_t)row * D_MODEL))[t] = r;
}

// ---------------------------------------------------------------- dt projection in pure f32 (phase-critical path)
__global__ __launch_bounds__(256) void dtproj_k(const float* __restrict__ xn,
                                                const float* __restrict__ wi,
                                                const float* __restrict__ dtb,
                                                float* __restrict__ dtout) {
  int idx = blockIdx.x * 256 + threadIdx.x;     // r*32 + hh
  int hh = idx & 31, r = idx >> 5;
  const float4* xr = (const float4*)(xn + (size_t)r * D_MODEL);
  const float4* wr = (const float4*)(wi + (size_t)(2 * D_INNER + 2 * D_STATE + hh) * D_MODEL);
  float a0 = 0.f, a1 = 0.f, a2 = 0.f, a3 = 0.f;
  #pragma unroll 4
  for (int k = 0; k < D_MODEL / 4; ++k) {
    float4 a = xr[k], b = wr[k];
    a0 = fmaf(a.x, b.x, a0); a1 = fmaf(a.y, b.y, a1);
    a2 = fmaf(a.z, b.z, a2); a3 = fmaf(a.w, b.w, a3);
  }
  float xv = (a0 + a1) + (a2 + a3) + dtb[hh];
  dtout[idx] = (xv > 20.f) ? xv : log1pf(__expf(xv));
}

// ---------------------------------------------------------------- GEMM  C[M,N] = A[M,K] * Bw[N,K]^T
// EPI: 0 = store f32; 1 = f32 store of (acc + add_src); 2 = bf16 store of silu(acc);
//      3 = bf16 in-place: Cb *= acc
template<int EPI>
__global__ __launch_bounds__(256) void gemm_bt(
    const __hip_bfloat16* __restrict__ A,
    const __hip_bfloat16* __restrict__ Bw,
    float* __restrict__ Cf,
    __hip_bfloat16* __restrict__ Cb,
    const float* __restrict__ add_src,
    int M, int N, int K)
{
  const int tid  = threadIdx.x;
  const int wave = tid >> 6;
  const int lane = tid & 63;
  const int nTilesN = N >> 7;
  const int bm = (blockIdx.x / nTilesN) << 7;
  const int bn = (blockIdx.x % nTilesN) << 7;

  __shared__ __hip_bfloat16 As[128 * 32];
  __shared__ __hip_bfloat16 Bs[128 * 32];

  const int wm = (wave >> 1) << 6;   // 0 or 64
  const int wn = (wave & 1) << 6;    // 0 or 64
  const int r16 = lane & 15;
  const int kg  = lane >> 4;         // 0..3

  f32x4 acc[4][4] = {};

  for (int k0 = 0; k0 < K; k0 += 32) {
    #pragma unroll
    for (int i = 0; i < 2; ++i) {
      int q = tid + 256 * i;
      int row = q >> 2;
      int kc  = (q & 3) << 3;
      const __hip_bfloat16* ga = A  + (size_t)(bm + row) * K + k0 + kc;
      const __hip_bfloat16* gb = Bw + (size_t)(bn + row) * K + k0 + kc;
      __builtin_amdgcn_global_load_lds((const __attribute__((address_space(1))) unsigned int*)ga,
                                       (__attribute__((address_space(3))) unsigned int*)(As + q * 8),
                                       16, 0, 0);
      __builtin_amdgcn_global_load_lds((const __attribute__((address_space(1))) unsigned int*)gb,
                                       (__attribute__((address_space(3))) unsigned int*)(Bs + q * 8),
                                       16, 0, 0);
    }
    __syncthreads();

    bf16x8 af[4], bfr[4];
    #pragma unroll
    for (int i = 0; i < 4; ++i) {
      af[i]  = *(const bf16x8*)(As + (wm + i * 16 + r16) * 32 + kg * 8);
      bfr[i] = *(const bf16x8*)(Bs + (wn + i * 16 + r16) * 32 + kg * 8);
    }
    #pragma unroll
    for (int mi = 0; mi < 4; ++mi)
      #pragma unroll
      for (int ni = 0; ni < 4; ++ni)
        acc[mi][ni] = __builtin_amdgcn_mfma_f32_16x16x32_bf16(af[mi], bfr[ni], acc[mi][ni], 0, 0, 0);
    __syncthreads();
  }

  // C/D layout: col = lane&15, row = (lane>>4)*4 + j
  #pragma unroll
  for (int mi = 0; mi < 4; ++mi) {
    #pragma unroll
    for (int ni = 0; ni < 4; ++ni) {
      #pragma unroll
      for (int j = 0; j < 4; ++j) {
        int r = bm + wm + mi * 16 + kg * 4 + j;
        int c = bn + wn + ni * 16 + r16;
        size_t idx = (size_t)r * N + c;
        float v = acc[mi][ni][j];
        if constexpr (EPI == 0) {
          Cf[idx] = v;
        } else if constexpr (EPI == 1) {
          Cf[idx] = v + add_src[idx];
        } else if constexpr (EPI == 2) {
          Cb[idx] = __float2bfloat16(siluf(v));
        } else if constexpr (EPI == 3) {
          Cb[idx] = __float2bfloat16(v * __bfloat162float(Cb[idx]));
        }
      }
    }
  }
}

// ---------------------------------------------------------------- conv+silu+normalize for the 32 B/C channels
__global__ __launch_bounds__(256) void bcdt_k(const float* __restrict__ zx,
                                              const float* __restrict__ cw,
                                              const float* __restrict__ cb,
                                              float* __restrict__ bc) {
  int t = threadIdx.x;
  int r = blockIdx.x * 8 + (t >> 5);
  int ch = t & 31;
  int l = r & (SEQ - 1);
  int c = D_INNER + ch;                       // conv channel 2048+ch
  float acc = cb[c];
  #pragma unroll
  for (int k = 0; k < 4; ++k) {
    int lp = l - 3 + k;
    if (lp >= 0)
      acc = fmaf(zx[(size_t)(r - 3 + k) * PROJ_PAD + 2 * D_INNER + ch], cw[c * 4 + k], acc);
  }
  acc = siluf(acc);
  float ss = acc * acc;
  ss += __shfl_xor(ss, 1);
  ss += __shfl_xor(ss, 2);
  ss += __shfl_xor(ss, 4);
  ss += __shfl_xor(ss, 8);
  bc[r * 32 + ch] = acc / (sqrtf(ss) + 1e-6f);
}

// ---------------------------------------------------------------- sequential scan with on-the-fly u-conv
// block = (chunk, h, b); 64 threads: lane = d(0..15) + 16*ngroup(0..3), 4 n-cells per lane
__global__ __launch_bounds__(64) void scan_k(
    const float* __restrict__ zx, const float* __restrict__ bc,
    const float* __restrict__ dt, const float* __restrict__ A_log,
    const float* __restrict__ Dp, const float* __restrict__ cw,
    const float* __restrict__ cb, __hip_bfloat16* __restrict__ po)
{
  int blk = blockIdx.x;
  int chunk = blk & 3, h = (blk >> 2) & 31, b = blk >> 7;
  int t = threadIdx.x;
  int d = t & 15, ng = t >> 4;
  int n0 = ng * 4;
  int dcol = h * 64 + chunk * 16 + d;
  float A4[4];
  #pragma unroll
  for (int j = 0; j < 4; ++j) A4[j] = __expf(A_log[h * 16 + n0 + j]);
  float Dh = Dp[h];
  float c0 = cw[dcol * 4 + 0], c1 = cw[dcol * 4 + 1];
  float c2 = cw[dcol * 4 + 2], c3 = cw[dcol * 4 + 3];
  float cbv = cb[dcol];
  float w[4] = {0, 0, 0, 0}, ys[4] = {0, 0, 0, 0};
  size_t rowbase = (size_t)b * SEQ;

  // l = 0 state
  const float* zr0 = zx + rowbase * PROJ_PAD;
  float xw1 = 0.f, xw2 = 0.f, xw3 = zr0[D_INNER + dcol];
  float uv = siluf(fmaf(c3, xw3, cbv));
  float zv = zr0[dcol];
  float dtv = dt[rowbase * 32 + h];
  float4 Bv = *(const float4*)(bc + rowbase * 32 + n0);
  float4 Cv = *(const float4*)(bc + rowbase * 32 + 16 + n0);
  float Sv[4], dtA[4];
  #pragma unroll
  for (int j = 0; j < 4; ++j) {
    dtA[j] = dtv * A4[j];
    Sv[j] = 1.0f / fmaf(dtv * dtv, A4[j], 1.0f);
  }
  float du = dtv * uv;

  for (int l = 0; l < SEQ; ++l) {
    // ---- prefetch l+1 (off critical chain)
    float unext = 0.f, znext = 0.f, dtnext = 0.f, dun = 0.f;
    float4 Bn = {0, 0, 0, 0}, Cn = {0, 0, 0, 0};
    float Sn[4] = {0, 0, 0, 0}, dtAn[4] = {0, 0, 0, 0};
    float nx1 = xw2, nx2 = xw3, nx3 = 0.f;
    if (l + 1 < SEQ) {
      size_t r = rowbase + l + 1;
      const float* zr = zx + r * PROJ_PAD;
      nx3 = zr[D_INNER + dcol];
      float cacc = fmaf(c0, xw1, cbv);
      cacc = fmaf(c1, xw2, cacc);
      cacc = fmaf(c2, xw3, cacc);
      cacc = fmaf(c3, nx3, cacc);
      unext = siluf(cacc);
      znext = zr[dcol];
      dtnext = dt[r * 32 + h];
      Bn = *(const float4*)(bc + r * 32 + n0);
      Cn = *(const float4*)(bc + r * 32 + 16 + n0);
      float d2 = dtnext * dtnext;
      #pragma unroll
      for (int j = 0; j < 4; ++j) {
        dtAn[j] = dtnext * A4[j];
        Sn[j] = 1.0f / fmaf(d2, A4[j], 1.0f);
      }
      dun = dtnext * unext;
    }
    // ---- compute step l
    float o = 0.f;
    #pragma unroll
    for (int j = 0; j < 4; ++j) {
      float tmp = fmaf(-dtA[j], ys[j], w[j]);
      tmp = fmaf(du, ((const float*)&Bv)[j], tmp);
      w[j] = Sv[j] * tmp;
      ys[j] = fmaf(dtv, w[j], ys[j]);
      o = fmaf(ys[j], ((const float*)&Cv)[j], o);
    }
    o += __shfl_xor(o, 16);
    o += __shfl_xor(o, 32);
    if (ng == 0) {
      float yv = fmaf(Dh, uv, o);
      po[(rowbase + l) * D_INNER + dcol] = __float2bfloat16(yv * siluf(zv));
    }
    xw1 = nx1; xw2 = nx2; xw3 = nx3;
    uv = unext; zv = znext; dtv = dtnext; du = dun;
    Bv = Bn; Cv = Cn;
    #pragma unroll
    for (int j = 0; j < 4; ++j) { Sv[j] = Sn[j]; dtA[j] = dtAn[j]; }
  }
}

// ---------------------------------------------------------------- launch
extern "C" void kernel_launch(void* const* d_in, const int* in_sizes, int n_in,
                              void* d_out, int out_size, void* d_ws, size_t ws_size,
                              hipStream_t stream) {
  const float* x     = (const float*)d_in[0];
  const float* n1w   = (const float*)d_in[1];
  const float* wi    = (const float*)d_in[2];
  const float* cw    = (const float*)d_in[3];
  const float* cb    = (const float*)d_in[4];
  const float* A_log = (const float*)d_in[5];
  const float* dtb   = (const float*)d_in[6];
  const float* Dp    = (const float*)d_in[7];
  const float* wo    = (const float*)d_in[8];
  const float* n2w   = (const float*)d_in[9];
  const float* wg    = (const float*)d_in[10];
  const float* wu    = (const float*)d_in[11];
  const float* wd    = (const float*)d_in[12];
  float* out = (float*)d_out;

  char* p = (char*)d_ws;
  auto take = [&](size_t b) { char* q = p; p += (b + 255) & ~(size_t)255; return q; };
  __hip_bfloat16* wbi  = (__hip_bfloat16*)take((size_t)PROJ_PAD * D_MODEL * 2);   //  8.25 MB
  __hip_bfloat16* wbo  = (__hip_bfloat16*)take((size_t)D_MODEL * D_INNER * 2);    //  4    MB
  __hip_bfloat16* wbg  = (__hip_bfloat16*)take((size_t)FFN_DIM * D_MODEL * 2);    //  5.5  MB
  __hip_bfloat16* wbu  = (__hip_bfloat16*)take((size_t)FFN_DIM * D_MODEL * 2);    //  5.5  MB
  __hip_bfloat16* wbd  = (__hip_bfloat16*)take((size_t)D_MODEL * FFN_DIM * 2);    //  5.5  MB
  __hip_bfloat16* h0b  = (__hip_bfloat16*)take((size_t)ROWS * D_MODEL * 2);       // 16    MB
  float*          zx   = (float*)take((size_t)ROWS * PROJ_PAD * 4);               // 132   MB
  float*          bcb  = (float*)take((size_t)ROWS * 32 * 4);                     //  1    MB
  float*          dt   = (float*)take((size_t)ROWS * 32 * 4);                     //  1    MB
  __hip_bfloat16* po   = (__hip_bfloat16*)take((size_t)ROWS * D_INNER * 2);       // 32    MB
  // aliases into the zx region (zx dead after scan_k):
  float*          h0f  = (float*)zx;                                  // live only rmsnorm->dtproj
  float*          h    = (float*)zx;                                  // 32 MB, live after scan
  __hip_bfloat16* gact = (__hip_bfloat16*)((char*)zx + 33554432);     // 44 MB, disjoint from h

  // weight conversions
  cvt_pad_k<<<(PROJ_PAD * D_MODEL + 255) / 256, 256, 0, stream>>>(wi, wbi);
  cvt_k<<<(D_MODEL * D_INNER + 255) / 256, 256, 0, stream>>>(wo, wbo, D_MODEL * D_INNER);
  cvt_k<<<(FFN_DIM * D_MODEL + 255) / 256, 256, 0, stream>>>(wg, wbg, FFN_DIM * D_MODEL);
  cvt_k<<<(FFN_DIM * D_MODEL + 255) / 256, 256, 0, stream>>>(wu, wbu, FFN_DIM * D_MODEL);
  cvt_k<<<(FFN_DIM * D_MODEL + 255) / 256, 256, 0, stream>>>(wd, wbd, FFN_DIM * D_MODEL);

  // mixer
  rmsnorm_k<<<ROWS, 256, 0, stream>>>(x, n1w, h0b, h0f);
  dtproj_k<<<ROWS * 32 / 256, 256, 0, stream>>>(h0f, wi, dtb, dt);   // before zx is clobbered
  gemm_bt<0><<<(ROWS / 128) * (PROJ_PAD / 128), 256, 0, stream>>>(h0b, wbi, zx, nullptr, nullptr,
                                                                  ROWS, PROJ_PAD, D_MODEL);
  bcdt_k<<<ROWS / 8, 256, 0, stream>>>(zx, cw, cb, bcb);
  scan_k<<<BATCH * N_HEADS * 4, 64, 0, stream>>>(zx, bcb, dt, A_log, Dp, cw, cb, po);
  gemm_bt<1><<<(ROWS / 128) * (D_MODEL / 128), 256, 0, stream>>>(po, wbo, h, nullptr, x,
                                                                 ROWS, D_MODEL, D_INNER);
  // FFN
  rmsnorm_k<<<ROWS, 256, 0, stream>>>(h, n2w, h0b, nullptr);
  gemm_bt<2><<<(ROWS / 128) * (FFN_DIM / 128), 256, 0, stream>>>(h0b, wbg, nullptr, gact, nullptr,
                                                                 ROWS, FFN_DIM, D_MODEL);
  gemm_bt<3><<<(ROWS / 128) * (FFN_DIM / 128), 256, 0, stream>>>(h0b, wbu, nullptr, gact, nullptr,
                                                                 ROWS, FFN_DIM, D_MODEL);
  gemm_bt<1><<<(ROWS / 128) * (D_MODEL / 128), 256, 0, stream>>>(gact, wbd, out, nullptr, h,
                                                                 ROWS, D_MODEL, FFN_DIM);
}

// Round 4
// 1216.738 us; speedup vs baseline: 1.3835x; 1.3835x over previous
//
#include <hip/hip_runtime.h>
#include <hip/hip_bf16.h>

#define D_MODEL   1024
#define D_STATE   16
#define D_HEAD    64
#define D_CONV    4
#define FFN_DIM   2816
#define D_INNER   2048
#define N_HEADS   32
#define BATCH     4
#define SEQ       2048
#define ROWS      (BATCH*SEQ)     // 8192
#define PROJ_DIM  4160
#define PROJ_PAD  4224            // 33 * 128
#define CONV_CH   2080            // D_INNER + 2*D_STATE

typedef __bf16 bf16x8 __attribute__((ext_vector_type(8)));
typedef float  f32x4  __attribute__((ext_vector_type(4)));

__device__ __forceinline__ float siluf(float x) { return x / (1.0f + __expf(-x)); }

// ---------------------------------------------------------------- converts
__global__ void cvt_k(const float* __restrict__ src, __hip_bfloat16* __restrict__ dst, int n) {
  int i = blockIdx.x * blockDim.x + threadIdx.x;
  if (i < n) dst[i] = __float2bfloat16(src[i]);
}

// in_proj: [4160][1024] f32 -> [4224][1024] bf16, zero-padded rows
__global__ void cvt_pad_k(const float* __restrict__ src, __hip_bfloat16* __restrict__ dst) {
  int i = blockIdx.x * blockDim.x + threadIdx.x;
  if (i >= PROJ_PAD * D_MODEL) return;
  int row = i >> 10;
  dst[i] = (row < PROJ_DIM) ? __float2bfloat16(src[i]) : __float2bfloat16(0.0f);
}

// ---------------------------------------------------------------- rmsnorm (f32 in -> bf16 out, optional f32 out)
__global__ __launch_bounds__(256) void rmsnorm_k(const float* __restrict__ x,
                                                 const float* __restrict__ w,
                                                 __hip_bfloat16* __restrict__ out,
                                                 float* __restrict__ outf) {
  int row = blockIdx.x;
  int t = threadIdx.x;
  const float* xr = x + (size_t)row * D_MODEL;
  float4 v = ((const float4*)xr)[t];            // 256 threads * 4 = 1024
  float ss = v.x*v.x + v.y*v.y + v.z*v.z + v.w*v.w;
  #pragma unroll
  for (int o = 32; o > 0; o >>= 1) ss += __shfl_xor(ss, o);
  __shared__ float red[4];
  if ((t & 63) == 0) red[t >> 6] = ss;
  __syncthreads();
  ss = red[0] + red[1] + red[2] + red[3];
  float scale = rsqrtf(ss * (1.0f / D_MODEL) + 1e-6f);
  float4 wv = ((const float4*)w)[t];
  float4 r;
  r.x = v.x * scale * wv.x; r.y = v.y * scale * wv.y;
  r.z = v.z * scale * wv.z; r.w = v.w * scale * wv.w;
  __hip_bfloat16* orow = out + (size_t)row * D_MODEL + t * 4;
  orow[0] = __float2bfloat16(r.x);
  orow[1] = __float2bfloat16(r.y);
  orow[2] = __float2bfloat16(r.z);
  orow[3] = __float2bfloat16(r.w);
  if (outf) ((float4*)(outf + (size_t)row * D_MODEL))[t] = r;
}

// ---------------------------------------------------------------- dt projection in pure f32, output transposed [h][r]
__global__ __launch_bounds__(256) void dtproj_k(const float* __restrict__ xn,
                                                const float* __restrict__ wi,
                                                const float* __restrict__ dtb,
                                                float* __restrict__ dtT) {
  int idx = blockIdx.x * 256 + threadIdx.x;     // r*32 + hh
  int hh = idx & 31, r = idx >> 5;
  const float4* xr = (const float4*)(xn + (size_t)r * D_MODEL);
  const float4* wr = (const float4*)(wi + (size_t)(2 * D_INNER + 2 * D_STATE + hh) * D_MODEL);
  float a0 = 0.f, a1 = 0.f, a2 = 0.f, a3 = 0.f;
  #pragma unroll 4
  for (int k = 0; k < D_MODEL / 4; ++k) {
    float4 a = xr[k], b = wr[k];
    a0 = fmaf(a.x, b.x, a0); a1 = fmaf(a.y, b.y, a1);
    a2 = fmaf(a.z, b.z, a2); a3 = fmaf(a.w, b.w, a3);
  }
  float xv = (a0 + a1) + (a2 + a3) + dtb[hh];
  dtT[hh * ROWS + r] = (xv > 20.f) ? xv : log1pf(__expf(xv));
}

// ---------------------------------------------------------------- GEMM  C[M,N] = A[M,K] * Bw[N,K]^T
// EPI: 0 = store f32; 1 = f32 store of (acc + add_src); 2 = bf16 store of silu(acc);
//      3 = bf16 in-place: Cb *= acc
template<int EPI>
__global__ __launch_bounds__(256) void gemm_bt(
    const __hip_bfloat16* __restrict__ A,
    const __hip_bfloat16* __restrict__ Bw,
    float* __restrict__ Cf,
    __hip_bfloat16* __restrict__ Cb,
    const float* __restrict__ add_src,
    int M, int N, int K)
{
  const int tid  = threadIdx.x;
  const int wave = tid >> 6;
  const int lane = tid & 63;
  const int nTilesN = N >> 7;
  const int bm = (blockIdx.x / nTilesN) << 7;
  const int bn = (blockIdx.x % nTilesN) << 7;

  __shared__ __hip_bfloat16 As[128 * 32];
  __shared__ __hip_bfloat16 Bs[128 * 32];

  const int wm = (wave >> 1) << 6;   // 0 or 64
  const int wn = (wave & 1) << 6;    // 0 or 64
  const int r16 = lane & 15;
  const int kg  = lane >> 4;         // 0..3

  f32x4 acc[4][4] = {};

  for (int k0 = 0; k0 < K; k0 += 32) {
    #pragma unroll
    for (int i = 0; i < 2; ++i) {
      int q = tid + 256 * i;
      int row = q >> 2;
      int kc  = (q & 3) << 3;
      const __hip_bfloat16* ga = A  + (size_t)(bm + row) * K + k0 + kc;
      const __hip_bfloat16* gb = Bw + (size_t)(bn + row) * K + k0 + kc;
      __builtin_amdgcn_global_load_lds((const __attribute__((address_space(1))) unsigned int*)ga,
                                       (__attribute__((address_space(3))) unsigned int*)(As + q * 8),
                                       16, 0, 0);
      __builtin_amdgcn_global_load_lds((const __attribute__((address_space(1))) unsigned int*)gb,
                                       (__attribute__((address_space(3))) unsigned int*)(Bs + q * 8),
                                       16, 0, 0);
    }
    __syncthreads();

    bf16x8 af[4], bfr[4];
    #pragma unroll
    for (int i = 0; i < 4; ++i) {
      af[i]  = *(const bf16x8*)(As + (wm + i * 16 + r16) * 32 + kg * 8);
      bfr[i] = *(const bf16x8*)(Bs + (wn + i * 16 + r16) * 32 + kg * 8);
    }
    #pragma unroll
    for (int mi = 0; mi < 4; ++mi)
      #pragma unroll
      for (int ni = 0; ni < 4; ++ni)
        acc[mi][ni] = __builtin_amdgcn_mfma_f32_16x16x32_bf16(af[mi], bfr[ni], acc[mi][ni], 0, 0, 0);
    __syncthreads();
  }

  // C/D layout: col = lane&15, row = (lane>>4)*4 + j
  #pragma unroll
  for (int mi = 0; mi < 4; ++mi) {
    #pragma unroll
    for (int ni = 0; ni < 4; ++ni) {
      #pragma unroll
      for (int j = 0; j < 4; ++j) {
        int r = bm + wm + mi * 16 + kg * 4 + j;
        int c = bn + wn + ni * 16 + r16;
        size_t idx = (size_t)r * N + c;
        float v = acc[mi][ni][j];
        if constexpr (EPI == 0) {
          Cf[idx] = v;
        } else if constexpr (EPI == 1) {
          Cf[idx] = v + add_src[idx];
        } else if constexpr (EPI == 2) {
          Cb[idx] = __float2bfloat16(siluf(v));
        } else if constexpr (EPI == 3) {
          Cb[idx] = __float2bfloat16(v * __bfloat162float(Cb[idx]));
        }
      }
    }
  }
}

// ---------------------------------------------------------------- conv+silu+normalize for the 32 B/C channels
__global__ __launch_bounds__(256) void bcdt_k(const float* __restrict__ zx,
                                              const float* __restrict__ cw,
                                              const float* __restrict__ cb,
                                              float* __restrict__ bc) {
  int t = threadIdx.x;
  int r = blockIdx.x * 8 + (t >> 5);
  int ch = t & 31;
  int l = r & (SEQ - 1);
  int c = D_INNER + ch;                       // conv channel 2048+ch
  float acc = cb[c];
  #pragma unroll
  for (int k = 0; k < 4; ++k) {
    int lp = l - 3 + k;
    if (lp >= 0)
      acc = fmaf(zx[(size_t)(r - 3 + k) * PROJ_PAD + 2 * D_INNER + ch], cw[c * 4 + k], acc);
  }
  acc = siluf(acc);
  float ss = acc * acc;
  ss += __shfl_xor(ss, 1);
  ss += __shfl_xor(ss, 2);
  ss += __shfl_xor(ss, 4);
  ss += __shfl_xor(ss, 8);
  bc[r * 32 + ch] = acc / (sqrtf(ss) + 1e-6f);
}

// ---------------------------------------------------------------- sequential scan, LDS-tiled double-buffered
// block = (b, h, half): 256 blocks x 128 threads (2 waves).
// wave wv handles d_local = half*32 + wv*16 + (lane&15); 4 n-groups of 4 per lane.
#define T_TILE 16
#define N_TILES (SEQ / T_TILE)
__global__ __launch_bounds__(128) void scan_k(
    const float* __restrict__ zx, const float* __restrict__ bcb,
    const float* __restrict__ dtT, const float* __restrict__ A_log,
    const float* __restrict__ Dp, const float* __restrict__ cw,
    const float* __restrict__ cb, __hip_bfloat16* __restrict__ po)
{
  const int blk  = blockIdx.x;
  const int half = blk & 1, h = (blk >> 1) & 31, b = blk >> 6;
  const int tid  = threadIdx.x;
  const int wv   = tid >> 6;
  const int lane = tid & 63;
  const int d16  = lane & 15;
  const int ng   = lane >> 4;
  const int n0   = ng * 4;
  const int dcol = h * 64 + half * 32 + wv * 16 + d16;   // global channel
  const size_t rowbase = (size_t)b * SEQ;

  __shared__ float xz [2][T_TILE][64];   // [0..31]=z cols, [32..63]=x cols (this block's 32 d)
  __shared__ float bct[2][T_TILE][32];   // B16 | C16
  __shared__ float st [2][T_TILE][16];   // S
  __shared__ float dtt[2][T_TILE];
  __shared__ float aexp[16];

  if (tid < 16) aexp[tid] = __expf(A_log[h * 16 + tid]);

  float A4[4];
  #pragma unroll
  for (int j = 0; j < 4; ++j) A4[j] = __expf(A_log[h * 16 + n0 + j]);
  const float Dh = Dp[h];
  const float c0 = cw[dcol * 4 + 0], c1 = cw[dcol * 4 + 1];
  const float c2 = cw[dcol * 4 + 2], c3 = cw[dcol * 4 + 3];
  const float cbv = cb[dcol];

  // --- staging: all via global_load_lds width 16 (dest = base + lane*16) ---
  auto stage = [&](int tile, int buf) {
    const size_t r0 = rowbase + (size_t)tile * T_TILE;
    // xz tile: 16 rows x 256B; each wave: 2 loads of 1KB (4 rows each)
    #pragma unroll
    for (int i = 0; i < 2; ++i) {
      int lr = 8 * i + 4 * wv + (lane >> 4);          // tile-local row
      int c4 = (lane & 15) * 4;                        // f32 col in [0,64)
      // z cols live at [0,2048); u (conv input) cols at [D_INNER, 2*D_INNER)
      int col = (c4 < 32) ? (h * 64 + half * 32 + c4)
                          : (D_INNER + h * 64 + half * 32 + (c4 - 32));
      const float* g = zx + (r0 + lr) * PROJ_PAD + col;
      float* l = &xz[buf][0][0] + (8 * i + 4 * wv) * 64 + (lane & 15) * 4;
      __builtin_amdgcn_global_load_lds((const __attribute__((address_space(1))) unsigned int*)g,
                                       (__attribute__((address_space(3))) unsigned int*)l,
                                       16, 0, 0);
    }
    // bct tile: 16 rows x 128B; each wave: 1 load of 1KB (8 rows)
    {
      int lr = 8 * wv + (lane >> 3);
      const float* g = bcb + (r0 + lr) * 32 + (lane & 7) * 4;
      float* l = &bct[buf][0][0] + 8 * wv * 32 + (lane & 7) * 4;
      __builtin_amdgcn_global_load_lds((const __attribute__((address_space(1))) unsigned int*)g,
                                       (__attribute__((address_space(3))) unsigned int*)l,
                                       16, 0, 0);
    }
  };

  // S-prep for a freshly staged buffer (dtn regs hold this tile's 16 dt values in lanes 0-15 of BOTH waves)
  auto sprep = [&](int buf, float dtn) {
    #pragma unroll
    for (int i = 0; i < 2; ++i) {
      int idx = tid + 128 * i;          // 0..255
      int row = idx >> 4, n = idx & 15;
      float dv = __shfl(dtn, row);
      float a  = aexp[n];
      st[buf][row][n] = 1.0f / fmaf(dv * dv, a, 1.0f);
    }
  };

  // --- prologue: tile 0 ---
  stage(0, 0);
  float dtn = 0.f;
  if (lane < 16) dtn = dtT[h * ROWS + rowbase + lane];
  __syncthreads();                       // staging + dtn arrived
  if (tid < 16) dtt[0][tid] = dtn;
  sprep(0, dtn);
  __syncthreads();

  float w[4] = {0, 0, 0, 0}, ys[4] = {0, 0, 0, 0};
  float xw1 = 0.f, xw2 = 0.f, xw3 = 0.f;  // conv shift registers (persist across tiles)
  int cur = 0;

  for (int t = 0; t < N_TILES; ++t) {
    if (t + 1 < N_TILES) {
      stage(t + 1, cur ^ 1);
      if (lane < 16) dtn = dtT[h * ROWS + rowbase + (size_t)(t + 1) * T_TILE + lane];
    }
    // ---- compute 16 steps from buf[cur]
    #pragma unroll 4
    for (int l = 0; l < T_TILE; ++l) {
      float xl  = xz[cur][l][32 + wv * 16 + d16];
      float zv  = xz[cur][l][wv * 16 + d16];
      float dtv = dtt[cur][l];
      f32x4 Sv = *(const f32x4*)&st [cur][l][n0];
      f32x4 Bv = *(const f32x4*)&bct[cur][l][n0];
      f32x4 Cv = *(const f32x4*)&bct[cur][l][16 + n0];
      float cacc = fmaf(c3, xl, fmaf(c2, xw3, fmaf(c1, xw2, fmaf(c0, xw1, cbv))));
      float uv = siluf(cacc);
      xw1 = xw2; xw2 = xw3; xw3 = xl;
      float du = dtv * uv;
      float o = 0.f;
      #pragma unroll
      for (int j = 0; j < 4; ++j) {
        float tmp = fmaf(-(dtv * A4[j]), ys[j], w[j]);
        tmp = fmaf(du, Bv[j], tmp);
        w[j] = Sv[j] * tmp;
        ys[j] = fmaf(dtv, w[j], ys[j]);
        o = fmaf(ys[j], Cv[j], o);
      }
      o += __shfl_xor(o, 16);
      o += __shfl_xor(o, 32);
      if (ng == 0) {
        float yv = fmaf(Dh, uv, o);
        po[(rowbase + (size_t)t * T_TILE + l) * D_INNER + dcol] =
            __float2bfloat16(yv * siluf(zv));
      }
    }
    __syncthreads();                     // drains vmcnt: buf[cur^1] + dtn ready
    if (t + 1 < N_TILES) {
      if (tid < 16) dtt[cur ^ 1][tid] = dtn;
      sprep(cur ^ 1, dtn);
      __syncthreads();
    }
    cur ^= 1;
  }
}

// ---------------------------------------------------------------- launch
extern "C" void kernel_launch(void* const* d_in, const int* in_sizes, int n_in,
                              void* d_out, int out_size, void* d_ws, size_t ws_size,
                              hipStream_t stream) {
  const float* x     = (const float*)d_in[0];
  const float* n1w   = (const float*)d_in[1];
  const float* wi    = (const float*)d_in[2];
  const float* cw    = (const float*)d_in[3];
  const float* cb    = (const float*)d_in[4];
  const float* A_log = (const float*)d_in[5];
  const float* dtb   = (const float*)d_in[6];
  const float* Dp    = (const float*)d_in[7];
  const float* wo    = (const float*)d_in[8];
  const float* n2w   = (const float*)d_in[9];
  const float* wg    = (const float*)d_in[10];
  const float* wu    = (const float*)d_in[11];
  const float* wd    = (const float*)d_in[12];
  float* out = (float*)d_out;

  char* p = (char*)d_ws;
  auto take = [&](size_t b) { char* q = p; p += (b + 255) & ~(size_t)255; return q; };
  __hip_bfloat16* wbi  = (__hip_bfloat16*)take((size_t)PROJ_PAD * D_MODEL * 2);   //  8.25 MB
  __hip_bfloat16* wbo  = (__hip_bfloat16*)take((size_t)D_MODEL * D_INNER * 2);    //  4    MB
  __hip_bfloat16* wbg  = (__hip_bfloat16*)take((size_t)FFN_DIM * D_MODEL * 2);    //  5.5  MB
  __hip_bfloat16* wbu  = (__hip_bfloat16*)take((size_t)FFN_DIM * D_MODEL * 2);    //  5.5  MB
  __hip_bfloat16* wbd  = (__hip_bfloat16*)take((size_t)D_MODEL * FFN_DIM * 2);    //  5.5  MB
  __hip_bfloat16* h0b  = (__hip_bfloat16*)take((size_t)ROWS * D_MODEL * 2);       // 16    MB
  float*          zx   = (float*)take((size_t)ROWS * PROJ_PAD * 4);               // 132   MB
  float*          bcb  = (float*)take((size_t)ROWS * 32 * 4);                     //  1    MB
  float*          dtT  = (float*)take((size_t)ROWS * 32 * 4);                     //  1    MB  [h][r]
  __hip_bfloat16* po   = (__hip_bfloat16*)take((size_t)ROWS * D_INNER * 2);       // 32    MB
  // aliases into the zx region (zx dead after scan_k):
  float*          h0f  = (float*)zx;                                  // live only rmsnorm->dtproj
  float*          h    = (float*)zx;                                  // 32 MB, live after scan
  __hip_bfloat16* gact = (__hip_bfloat16*)((char*)zx + 33554432);     // 44 MB, disjoint from h

  // weight conversions
  cvt_pad_k<<<(PROJ_PAD * D_MODEL + 255) / 256, 256, 0, stream>>>(wi, wbi);
  cvt_k<<<(D_MODEL * D_INNER + 255) / 256, 256, 0, stream>>>(wo, wbo, D_MODEL * D_INNER);
  cvt_k<<<(FFN_DIM * D_MODEL + 255) / 256, 256, 0, stream>>>(wg, wbg, FFN_DIM * D_MODEL);
  cvt_k<<<(FFN_DIM * D_MODEL + 255) / 256, 256, 0, stream>>>(wu, wbu, FFN_DIM * D_MODEL);
  cvt_k<<<(FFN_DIM * D_MODEL + 255) / 256, 256, 0, stream>>>(wd, wbd, FFN_DIM * D_MODEL);

  // mixer
  rmsnorm_k<<<ROWS, 256, 0, stream>>>(x, n1w, h0b, h0f);
  dtproj_k<<<ROWS * 32 / 256, 256, 0, stream>>>(h0f, wi, dtb, dtT);   // before zx is clobbered
  gemm_bt<0><<<(ROWS / 128) * (PROJ_PAD / 128), 256, 0, stream>>>(h0b, wbi, zx, nullptr, nullptr,
                                                                  ROWS, PROJ_PAD, D_MODEL);
  bcdt_k<<<ROWS / 8, 256, 0, stream>>>(zx, cw, cb, bcb);
  scan_k<<<BATCH * N_HEADS * 2, 128, 0, stream>>>(zx, bcb, dtT, A_log, Dp, cw, cb, po);
  gemm_bt<1><<<(ROWS / 128) * (D_MODEL / 128), 256, 0, stream>>>(po, wbo, h, nullptr, x,
                                                                 ROWS, D_MODEL, D_INNER);
  // FFN
  rmsnorm_k<<<ROWS, 256, 0, stream>>>(h, n2w, h0b, nullptr);
  gemm_bt<2><<<(ROWS / 128) * (FFN_DIM / 128), 256, 0, stream>>>(h0b, wbg, nullptr, gact, nullptr,
                                                                 ROWS, FFN_DIM, D_MODEL);
  gemm_bt<3><<<(ROWS / 128) * (FFN_DIM / 128), 256, 0, stream>>>(h0b, wbu, nullptr, gact, nullptr,
                                                                 ROWS, FFN_DIM, D_MODEL);
  gemm_bt<1><<<(ROWS / 128) * (D_MODEL / 128), 256, 0, stream>>>(gact, wbd, out, nullptr, h,
                                                                 ROWS, D_MODEL, FFN_DIM);
}

// Round 5
// 988.681 us; speedup vs baseline: 1.7026x; 1.2307x over previous
//
#include <hip/hip_runtime.h>
#include <hip/hip_bf16.h>

#define D_MODEL   1024
#define D_STATE   16
#define D_HEAD    64
#define D_CONV    4
#define FFN_DIM   2816
#define D_INNER   2048
#define N_HEADS   32
#define BATCH     4
#define SEQ       2048
#define ROWS      (BATCH*SEQ)     // 8192
#define PROJ_DIM  4160
#define PROJ_PAD  4224            // 33 * 128
#define CONV_CH   2080            // D_INNER + 2*D_STATE

typedef __bf16 bf16x8 __attribute__((ext_vector_type(8)));
typedef float  f32x4  __attribute__((ext_vector_type(4)));

__device__ __forceinline__ float siluf(float x) { return x / (1.0f + __expf(-x)); }

// ---------------------------------------------------------------- converts
__global__ void cvt_k(const float* __restrict__ src, __hip_bfloat16* __restrict__ dst, int n) {
  int i = blockIdx.x * blockDim.x + threadIdx.x;
  if (i < n) dst[i] = __float2bfloat16(src[i]);
}

// in_proj: [4160][1024] f32 -> [4224][1024] bf16, zero-padded rows
__global__ void cvt_pad_k(const float* __restrict__ src, __hip_bfloat16* __restrict__ dst) {
  int i = blockIdx.x * blockDim.x + threadIdx.x;
  if (i >= PROJ_PAD * D_MODEL) return;
  int row = i >> 10;
  dst[i] = (row < PROJ_DIM) ? __float2bfloat16(src[i]) : __float2bfloat16(0.0f);
}

// ---------------------------------------------------------------- rmsnorm (f32 in -> bf16 out, optional f32 out)
__global__ __launch_bounds__(256) void rmsnorm_k(const float* __restrict__ x,
                                                 const float* __restrict__ w,
                                                 __hip_bfloat16* __restrict__ out,
                                                 float* __restrict__ outf) {
  int row = blockIdx.x;
  int t = threadIdx.x;
  const float* xr = x + (size_t)row * D_MODEL;
  float4 v = ((const float4*)xr)[t];            // 256 threads * 4 = 1024
  float ss = v.x*v.x + v.y*v.y + v.z*v.z + v.w*v.w;
  #pragma unroll
  for (int o = 32; o > 0; o >>= 1) ss += __shfl_xor(ss, o);
  __shared__ float red[4];
  if ((t & 63) == 0) red[t >> 6] = ss;
  __syncthreads();
  ss = red[0] + red[1] + red[2] + red[3];
  float scale = rsqrtf(ss * (1.0f / D_MODEL) + 1e-6f);
  float4 wv = ((const float4*)w)[t];
  float4 r;
  r.x = v.x * scale * wv.x; r.y = v.y * scale * wv.y;
  r.z = v.z * scale * wv.z; r.w = v.w * scale * wv.w;
  __hip_bfloat16* orow = out + (size_t)row * D_MODEL + t * 4;
  orow[0] = __float2bfloat16(r.x);
  orow[1] = __float2bfloat16(r.y);
  orow[2] = __float2bfloat16(r.z);
  orow[3] = __float2bfloat16(r.w);
  if (outf) ((float4*)(outf + (size_t)row * D_MODEL))[t] = r;
}

// ---------------------------------------------------------------- dt projection in pure f32, output transposed [h][r]
__global__ __launch_bounds__(256) void dtproj_k(const float* __restrict__ xn,
                                                const float* __restrict__ wi,
                                                const float* __restrict__ dtb,
                                                float* __restrict__ dtT) {
  int idx = blockIdx.x * 256 + threadIdx.x;     // r*32 + hh
  int hh = idx & 31, r = idx >> 5;
  const float4* xr = (const float4*)(xn + (size_t)r * D_MODEL);
  const float4* wr = (const float4*)(wi + (size_t)(2 * D_INNER + 2 * D_STATE + hh) * D_MODEL);
  float a0 = 0.f, a1 = 0.f, a2 = 0.f, a3 = 0.f;
  #pragma unroll 4
  for (int k = 0; k < D_MODEL / 4; ++k) {
    float4 a = xr[k], b = wr[k];
    a0 = fmaf(a.x, b.x, a0); a1 = fmaf(a.y, b.y, a1);
    a2 = fmaf(a.z, b.z, a2); a3 = fmaf(a.w, b.w, a3);
  }
  float xv = (a0 + a1) + (a2 + a3) + dtb[hh];
  dtT[hh * ROWS + r] = (xv > 20.f) ? xv : log1pf(__expf(xv));
}

// ---------------------------------------------------------------- GEMM  C[M,N] = A[M,K] * Bw[N,K]^T
// EPI: 0 = store f32; 1 = f32 store of (acc + add_src); 2 = bf16 store of silu(acc);
//      3 = bf16 in-place: Cb *= acc
template<int EPI>
__global__ __launch_bounds__(256) void gemm_bt(
    const __hip_bfloat16* __restrict__ A,
    const __hip_bfloat16* __restrict__ Bw,
    float* __restrict__ Cf,
    __hip_bfloat16* __restrict__ Cb,
    const float* __restrict__ add_src,
    int M, int N, int K)
{
  const int tid  = threadIdx.x;
  const int wave = tid >> 6;
  const int lane = tid & 63;
  const int nTilesN = N >> 7;
  const int bm = (blockIdx.x / nTilesN) << 7;
  const int bn = (blockIdx.x % nTilesN) << 7;

  __shared__ __hip_bfloat16 As[128 * 32];
  __shared__ __hip_bfloat16 Bs[128 * 32];

  const int wm = (wave >> 1) << 6;   // 0 or 64
  const int wn = (wave & 1) << 6;    // 0 or 64
  const int r16 = lane & 15;
  const int kg  = lane >> 4;         // 0..3

  f32x4 acc[4][4] = {};

  for (int k0 = 0; k0 < K; k0 += 32) {
    #pragma unroll
    for (int i = 0; i < 2; ++i) {
      int q = tid + 256 * i;
      int row = q >> 2;
      int kc  = (q & 3) << 3;
      const __hip_bfloat16* ga = A  + (size_t)(bm + row) * K + k0 + kc;
      const __hip_bfloat16* gb = Bw + (size_t)(bn + row) * K + k0 + kc;
      __builtin_amdgcn_global_load_lds((const __attribute__((address_space(1))) unsigned int*)ga,
                                       (__attribute__((address_space(3))) unsigned int*)(As + q * 8),
                                       16, 0, 0);
      __builtin_amdgcn_global_load_lds((const __attribute__((address_space(1))) unsigned int*)gb,
                                       (__attribute__((address_space(3))) unsigned int*)(Bs + q * 8),
                                       16, 0, 0);
    }
    __syncthreads();

    bf16x8 af[4], bfr[4];
    #pragma unroll
    for (int i = 0; i < 4; ++i) {
      af[i]  = *(const bf16x8*)(As + (wm + i * 16 + r16) * 32 + kg * 8);
      bfr[i] = *(const bf16x8*)(Bs + (wn + i * 16 + r16) * 32 + kg * 8);
    }
    #pragma unroll
    for (int mi = 0; mi < 4; ++mi)
      #pragma unroll
      for (int ni = 0; ni < 4; ++ni)
        acc[mi][ni] = __builtin_amdgcn_mfma_f32_16x16x32_bf16(af[mi], bfr[ni], acc[mi][ni], 0, 0, 0);
    __syncthreads();
  }

  // C/D layout: col = lane&15, row = (lane>>4)*4 + j
  #pragma unroll
  for (int mi = 0; mi < 4; ++mi) {
    #pragma unroll
    for (int ni = 0; ni < 4; ++ni) {
      #pragma unroll
      for (int j = 0; j < 4; ++j) {
        int r = bm + wm + mi * 16 + kg * 4 + j;
        int c = bn + wn + ni * 16 + r16;
        size_t idx = (size_t)r * N + c;
        float v = acc[mi][ni][j];
        if constexpr (EPI == 0) {
          Cf[idx] = v;
        } else if constexpr (EPI == 1) {
          Cf[idx] = v + add_src[idx];
        } else if constexpr (EPI == 2) {
          Cb[idx] = __float2bfloat16(siluf(v));
        } else if constexpr (EPI == 3) {
          Cb[idx] = __float2bfloat16(v * __bfloat162float(Cb[idx]));
        }
      }
    }
  }
}

// ---------------------------------------------------------------- conv+silu+normalize for the 32 B/C channels
__global__ __launch_bounds__(256) void bcdt_k(const float* __restrict__ zx,
                                              const float* __restrict__ cw,
                                              const float* __restrict__ cb,
                                              float* __restrict__ bc) {
  int t = threadIdx.x;
  int r = blockIdx.x * 8 + (t >> 5);
  int ch = t & 31;
  int l = r & (SEQ - 1);
  int c = D_INNER + ch;                       // conv channel 2048+ch
  float acc = cb[c];
  #pragma unroll
  for (int k = 0; k < 4; ++k) {
    int lp = l - 3 + k;
    if (lp >= 0)
      acc = fmaf(zx[(size_t)(r - 3 + k) * PROJ_PAD + 2 * D_INNER + ch], cw[c * 4 + k], acc);
  }
  acc = siluf(acc);
  float ss = acc * acc;
  ss += __shfl_xor(ss, 1);
  ss += __shfl_xor(ss, 2);
  ss += __shfl_xor(ss, 4);
  ss += __shfl_xor(ss, 8);
  bc[r * 32 + ch] = acc / (sqrtf(ss) + 1e-6f);
}

// ---------------------------------------------------------------- sequential scan, LDS-tiled double-buffered
// block = (b, h, half): 256 blocks x 128 threads (2 waves).
// wave wv handles d_local = half*32 + wv*16 + (lane&15); 4 n-groups of 4 per lane.
// Phase 1 (serial): recurrence only, per-lane partial o -> LDS (no shuffles).
// Phase 2 (parallel, per-wave own data): reduce 4 partials + silu(z) + store.
#define T_TILE 16
#define N_TILES (SEQ / T_TILE)
__global__ __launch_bounds__(128) void scan_k(
    const float* __restrict__ zx, const float* __restrict__ bcb,
    const float* __restrict__ dtT, const float* __restrict__ A_log,
    const float* __restrict__ Dp, const float* __restrict__ cw,
    const float* __restrict__ cb, __hip_bfloat16* __restrict__ po)
{
  const int blk  = blockIdx.x;
  const int half = blk & 1, h = (blk >> 1) & 31, b = blk >> 6;
  const int tid  = threadIdx.x;
  const int wv   = tid >> 6;
  const int lane = tid & 63;
  const int d16  = lane & 15;
  const int ng   = lane >> 4;
  const int n0   = ng * 4;
  const int dcol = h * 64 + half * 32 + wv * 16 + d16;   // global channel
  const size_t rowbase = (size_t)b * SEQ;

  __shared__ float xz [2][T_TILE][64];   // [0..31]=z cols, [32..63]=x cols (this block's 32 d)
  __shared__ float bct[2][T_TILE][32];   // B16 | C16
  __shared__ float st [2][T_TILE][16];   // S
  __shared__ float dtt[2][T_TILE];
  __shared__ float aexp[16];
  __shared__ float opart[T_TILE][32][4]; // [l][d_local][ng] partial o

  if (tid < 16) aexp[tid] = __expf(A_log[h * 16 + tid]);

  float A4[4];
  #pragma unroll
  for (int j = 0; j < 4; ++j) A4[j] = __expf(A_log[h * 16 + n0 + j]);
  const float Dh = Dp[h];
  const float c0 = cw[dcol * 4 + 0], c1 = cw[dcol * 4 + 1];
  const float c2 = cw[dcol * 4 + 2], c3 = cw[dcol * 4 + 3];
  const float cbv = cb[dcol];

  // --- staging: all via global_load_lds width 16 (dest = base + lane*16) ---
  auto stage = [&](int tile, int buf) {
    const size_t r0 = rowbase + (size_t)tile * T_TILE;
    // xz tile: 16 rows x 256B; each wave: 2 loads of 1KB (4 rows each)
    #pragma unroll
    for (int i = 0; i < 2; ++i) {
      int lr = 8 * i + 4 * wv + (lane >> 4);          // tile-local row
      int c4 = (lane & 15) * 4;                        // f32 col in [0,64)
      // z cols live at [0,2048); u (conv input) cols at [D_INNER, 2*D_INNER)
      int col = (c4 < 32) ? (h * 64 + half * 32 + c4)
                          : (D_INNER + h * 64 + half * 32 + (c4 - 32));
      const float* g = zx + (r0 + lr) * PROJ_PAD + col;
      float* l = &xz[buf][0][0] + (8 * i + 4 * wv) * 64 + (lane & 15) * 4;
      __builtin_amdgcn_global_load_lds((const __attribute__((address_space(1))) unsigned int*)g,
                                       (__attribute__((address_space(3))) unsigned int*)l,
                                       16, 0, 0);
    }
    // bct tile: 16 rows x 128B; each wave: 1 load of 1KB (8 rows)
    {
      int lr = 8 * wv + (lane >> 3);
      const float* g = bcb + (r0 + lr) * 32 + (lane & 7) * 4;
      float* l = &bct[buf][0][0] + 8 * wv * 32 + (lane & 7) * 4;
      __builtin_amdgcn_global_load_lds((const __attribute__((address_space(1))) unsigned int*)g,
                                       (__attribute__((address_space(3))) unsigned int*)l,
                                       16, 0, 0);
    }
  };

  // S-prep for a freshly staged buffer (dtn regs hold this tile's 16 dt values in lanes 0-15 of BOTH waves)
  auto sprep = [&](int buf, float dtn) {
    #pragma unroll
    for (int i = 0; i < 2; ++i) {
      int idx = tid + 128 * i;          // 0..255
      int row = idx >> 4, n = idx & 15;
      float dv = __shfl(dtn, row);
      float a  = aexp[n];
      st[buf][row][n] = 1.0f / fmaf(dv * dv, a, 1.0f);
    }
  };

  // --- prologue: tile 0 ---
  stage(0, 0);
  float dtn = 0.f;
  if (lane < 16) dtn = dtT[h * ROWS + rowbase + lane];
  __syncthreads();                       // staging + dtn arrived
  if (tid < 16) dtt[0][tid] = dtn;
  sprep(0, dtn);
  __syncthreads();

  float w[4] = {0, 0, 0, 0}, ys[4] = {0, 0, 0, 0};
  float xw1 = 0.f, xw2 = 0.f, xw3 = 0.f;  // conv shift registers (persist across tiles)
  int cur = 0;

  for (int t = 0; t < N_TILES; ++t) {
    if (t + 1 < N_TILES) {
      stage(t + 1, cur ^ 1);
      if (lane < 16) dtn = dtT[h * ROWS + rowbase + (size_t)(t + 1) * T_TILE + lane];
    }
    // ---- phase 1: 16 serial steps, recurrence only, partials to LDS
    #pragma unroll 4
    for (int l = 0; l < T_TILE; ++l) {
      float xl  = xz[cur][l][32 + wv * 16 + d16];
      float dtv = dtt[cur][l];
      f32x4 Sv = *(const f32x4*)&st [cur][l][n0];
      f32x4 Bv = *(const f32x4*)&bct[cur][l][n0];
      f32x4 Cv = *(const f32x4*)&bct[cur][l][16 + n0];
      float cacc = fmaf(c3, xl, fmaf(c2, xw3, fmaf(c1, xw2, fmaf(c0, xw1, cbv))));
      float uv = siluf(cacc);
      xw1 = xw2; xw2 = xw3; xw3 = xl;
      float du = dtv * uv;
      float o = 0.f;
      #pragma unroll
      for (int j = 0; j < 4; ++j) {
        float tmp = fmaf(-(dtv * A4[j]), ys[j], w[j]);
        tmp = fmaf(du, Bv[j], tmp);
        w[j] = Sv[j] * tmp;
        ys[j] = fmaf(dtv, w[j], ys[j]);
        o = fmaf(ys[j], Cv[j], o);
      }
      float ofin = (ng == 0) ? fmaf(Dh, uv, o) : o;
      opart[l][wv * 16 + d16][ng] = ofin;
    }
    // ---- phase 2: per-wave reduce of its own partials + output (no barrier needed)
    #pragma unroll
    for (int i = 0; i < 4; ++i) {
      int l  = (lane >> 4) + 4 * i;
      int dl = wv * 16 + d16;
      f32x4 op = *(const f32x4*)&opart[l][dl][0];
      float zv = xz[cur][l][dl];
      float yv = (op[0] + op[1]) + (op[2] + op[3]);
      po[(rowbase + (size_t)t * T_TILE + l) * D_INNER + (h * 64 + half * 32 + dl)] =
          __float2bfloat16(yv * siluf(zv));
    }
    __syncthreads();                     // drains vmcnt: buf[cur^1] + dtn ready
    if (t + 1 < N_TILES) {
      if (tid < 16) dtt[cur ^ 1][tid] = dtn;
      sprep(cur ^ 1, dtn);
      __syncthreads();
    }
    cur ^= 1;
  }
}

// ---------------------------------------------------------------- launch
extern "C" void kernel_launch(void* const* d_in, const int* in_sizes, int n_in,
                              void* d_out, int out_size, void* d_ws, size_t ws_size,
                              hipStream_t stream) {
  const float* x     = (const float*)d_in[0];
  const float* n1w   = (const float*)d_in[1];
  const float* wi    = (const float*)d_in[2];
  const float* cw    = (const float*)d_in[3];
  const float* cb    = (const float*)d_in[4];
  const float* A_log = (const float*)d_in[5];
  const float* dtb   = (const float*)d_in[6];
  const float* Dp    = (const float*)d_in[7];
  const float* wo    = (const float*)d_in[8];
  const float* n2w   = (const float*)d_in[9];
  const float* wg    = (const float*)d_in[10];
  const float* wu    = (const float*)d_in[11];
  const float* wd    = (const float*)d_in[12];
  float* out = (float*)d_out;

  char* p = (char*)d_ws;
  auto take = [&](size_t b) { char* q = p; p += (b + 255) & ~(size_t)255; return q; };
  __hip_bfloat16* wbi  = (__hip_bfloat16*)take((size_t)PROJ_PAD * D_MODEL * 2);   //  8.25 MB
  __hip_bfloat16* wbo  = (__hip_bfloat16*)take((size_t)D_MODEL * D_INNER * 2);    //  4    MB
  __hip_bfloat16* wbg  = (__hip_bfloat16*)take((size_t)FFN_DIM * D_MODEL * 2);    //  5.5  MB
  __hip_bfloat16* wbu  = (__hip_bfloat16*)take((size_t)FFN_DIM * D_MODEL * 2);    //  5.5  MB
  __hip_bfloat16* wbd  = (__hip_bfloat16*)take((size_t)D_MODEL * FFN_DIM * 2);    //  5.5  MB
  __hip_bfloat16* h0b  = (__hip_bfloat16*)take((size_t)ROWS * D_MODEL * 2);       // 16    MB
  float*          zx   = (float*)take((size_t)ROWS * PROJ_PAD * 4);               // 132   MB
  float*          bcb  = (float*)take((size_t)ROWS * 32 * 4);                     //  1    MB
  float*          dtT  = (float*)take((size_t)ROWS * 32 * 4);                     //  1    MB  [h][r]
  __hip_bfloat16* po   = (__hip_bfloat16*)take((size_t)ROWS * D_INNER * 2);       // 32    MB
  // aliases into the zx region (zx dead after scan_k):
  float*          h0f  = (float*)zx;                                  // live only rmsnorm->dtproj
  float*          h    = (float*)zx;                                  // 32 MB, live after scan
  __hip_bfloat16* gact = (__hip_bfloat16*)((char*)zx + 33554432);     // 44 MB, disjoint from h

  // weight conversions
  cvt_pad_k<<<(PROJ_PAD * D_MODEL + 255) / 256, 256, 0, stream>>>(wi, wbi);
  cvt_k<<<(D_MODEL * D_INNER + 255) / 256, 256, 0, stream>>>(wo, wbo, D_MODEL * D_INNER);
  cvt_k<<<(FFN_DIM * D_MODEL + 255) / 256, 256, 0, stream>>>(wg, wbg, FFN_DIM * D_MODEL);
  cvt_k<<<(FFN_DIM * D_MODEL + 255) / 256, 256, 0, stream>>>(wu, wbu, FFN_DIM * D_MODEL);
  cvt_k<<<(FFN_DIM * D_MODEL + 255) / 256, 256, 0, stream>>>(wd, wbd, FFN_DIM * D_MODEL);

  // mixer
  rmsnorm_k<<<ROWS, 256, 0, stream>>>(x, n1w, h0b, h0f);
  dtproj_k<<<ROWS * 32 / 256, 256, 0, stream>>>(h0f, wi, dtb, dtT);   // before zx is clobbered
  gemm_bt<0><<<(ROWS / 128) * (PROJ_PAD / 128), 256, 0, stream>>>(h0b, wbi, zx, nullptr, nullptr,
                                                                  ROWS, PROJ_PAD, D_MODEL);
  bcdt_k<<<ROWS / 8, 256, 0, stream>>>(zx, cw, cb, bcb);
  scan_k<<<BATCH * N_HEADS * 2, 128, 0, stream>>>(zx, bcb, dtT, A_log, Dp, cw, cb, po);
  gemm_bt<1><<<(ROWS / 128) * (D_MODEL / 128), 256, 0, stream>>>(po, wbo, h, nullptr, x,
                                                                 ROWS, D_MODEL, D_INNER);
  // FFN
  rmsnorm_k<<<ROWS, 256, 0, stream>>>(h, n2w, h0b, nullptr);
  gemm_bt<2><<<(ROWS / 128) * (FFN_DIM / 128), 256, 0, stream>>>(h0b, wbg, nullptr, gact, nullptr,
                                                                 ROWS, FFN_DIM, D_MODEL);
  gemm_bt<3><<<(ROWS / 128) * (FFN_DIM / 128), 256, 0, stream>>>(h0b, wbu, nullptr, gact, nullptr,
                                                                 ROWS, FFN_DIM, D_MODEL);
  gemm_bt<1><<<(ROWS / 128) * (D_MODEL / 128), 256, 0, stream>>>(gact, wbd, out, nullptr, h,
                                                                 ROWS, D_MODEL, FFN_DIM);
}

// Round 6
// 854.992 us; speedup vs baseline: 1.9688x; 1.1564x over previous
//
#include <hip/hip_runtime.h>
#include <hip/hip_bf16.h>

#define D_MODEL   1024
#define D_STATE   16
#define D_HEAD    64
#define D_CONV    4
#define FFN_DIM   2816
#define D_INNER   2048
#define N_HEADS   32
#define BATCH     4
#define SEQ       2048
#define ROWS      (BATCH*SEQ)     // 8192
#define PROJ_DIM  4160
#define PROJ_PAD  4224            // 33 * 128
#define CONV_CH   2080            // D_INNER + 2*D_STATE
#define CH        128             // scan chunk length
#define NCH       (SEQ/CH)        // 16 chunks

typedef __bf16 bf16x8 __attribute__((ext_vector_type(8)));
typedef float  f32x4  __attribute__((ext_vector_type(4)));

__device__ __forceinline__ float siluf(float x) { return x / (1.0f + __expf(-x)); }

// ---------------------------------------------------------------- converts
__global__ void cvt_k(const float* __restrict__ src, __hip_bfloat16* __restrict__ dst, int n) {
  int i = blockIdx.x * blockDim.x + threadIdx.x;
  if (i < n) dst[i] = __float2bfloat16(src[i]);
}

// in_proj: [4160][1024] f32 -> [4224][1024] bf16, zero-padded rows
__global__ void cvt_pad_k(const float* __restrict__ src, __hip_bfloat16* __restrict__ dst) {
  int i = blockIdx.x * blockDim.x + threadIdx.x;
  if (i >= PROJ_PAD * D_MODEL) return;
  int row = i >> 10;
  dst[i] = (row < PROJ_DIM) ? __float2bfloat16(src[i]) : __float2bfloat16(0.0f);
}

// ---------------------------------------------------------------- rmsnorm (f32 in -> bf16 out, optional f32 out)
__global__ __launch_bounds__(256) void rmsnorm_k(const float* __restrict__ x,
                                                 const float* __restrict__ w,
                                                 __hip_bfloat16* __restrict__ out,
                                                 float* __restrict__ outf) {
  int row = blockIdx.x;
  int t = threadIdx.x;
  const float* xr = x + (size_t)row * D_MODEL;
  float4 v = ((const float4*)xr)[t];            // 256 threads * 4 = 1024
  float ss = v.x*v.x + v.y*v.y + v.z*v.z + v.w*v.w;
  #pragma unroll
  for (int o = 32; o > 0; o >>= 1) ss += __shfl_xor(ss, o);
  __shared__ float red[4];
  if ((t & 63) == 0) red[t >> 6] = ss;
  __syncthreads();
  ss = red[0] + red[1] + red[2] + red[3];
  float scale = rsqrtf(ss * (1.0f / D_MODEL) + 1e-6f);
  float4 wv = ((const float4*)w)[t];
  float4 r;
  r.x = v.x * scale * wv.x; r.y = v.y * scale * wv.y;
  r.z = v.z * scale * wv.z; r.w = v.w * scale * wv.w;
  __hip_bfloat16* orow = out + (size_t)row * D_MODEL + t * 4;
  orow[0] = __float2bfloat16(r.x);
  orow[1] = __float2bfloat16(r.y);
  orow[2] = __float2bfloat16(r.z);
  orow[3] = __float2bfloat16(r.w);
  if (outf) ((float4*)(outf + (size_t)row * D_MODEL))[t] = r;
}

// ---------------------------------------------------------------- dt projection in pure f32, output transposed [h][r]
__global__ __launch_bounds__(256) void dtproj_k(const float* __restrict__ xn,
                                                const float* __restrict__ wi,
                                                const float* __restrict__ dtb,
                                                float* __restrict__ dtT) {
  int idx = blockIdx.x * 256 + threadIdx.x;     // r*32 + hh
  int hh = idx & 31, r = idx >> 5;
  const float4* xr = (const float4*)(xn + (size_t)r * D_MODEL);
  const float4* wr = (const float4*)(wi + (size_t)(2 * D_INNER + 2 * D_STATE + hh) * D_MODEL);
  float a0 = 0.f, a1 = 0.f, a2 = 0.f, a3 = 0.f;
  #pragma unroll 4
  for (int k = 0; k < D_MODEL / 4; ++k) {
    float4 a = xr[k], b = wr[k];
    a0 = fmaf(a.x, b.x, a0); a1 = fmaf(a.y, b.y, a1);
    a2 = fmaf(a.z, b.z, a2); a3 = fmaf(a.w, b.w, a3);
  }
  float xv = (a0 + a1) + (a2 + a3) + dtb[hh];
  dtT[hh * ROWS + r] = (xv > 20.f) ? xv : log1pf(__expf(xv));
}

// ---------------------------------------------------------------- GEMM  C[M,N] = A[M,K] * Bw[N,K]^T
// EPI: 0 = store f32; 1 = f32 store of (acc + add_src); 2 = bf16 store of silu(acc);
//      3 = bf16 in-place: Cb *= acc
template<int EPI>
__global__ __launch_bounds__(256) void gemm_bt(
    const __hip_bfloat16* __restrict__ A,
    const __hip_bfloat16* __restrict__ Bw,
    float* __restrict__ Cf,
    __hip_bfloat16* __restrict__ Cb,
    const float* __restrict__ add_src,
    int M, int N, int K)
{
  const int tid  = threadIdx.x;
  const int wave = tid >> 6;
  const int lane = tid & 63;
  const int nTilesN = N >> 7;
  const int bm = (blockIdx.x / nTilesN) << 7;
  const int bn = (blockIdx.x % nTilesN) << 7;

  __shared__ __hip_bfloat16 As[128 * 32];
  __shared__ __hip_bfloat16 Bs[128 * 32];

  const int wm = (wave >> 1) << 6;   // 0 or 64
  const int wn = (wave & 1) << 6;    // 0 or 64
  const int r16 = lane & 15;
  const int kg  = lane >> 4;         // 0..3

  f32x4 acc[4][4] = {};

  for (int k0 = 0; k0 < K; k0 += 32) {
    #pragma unroll
    for (int i = 0; i < 2; ++i) {
      int q = tid + 256 * i;
      int row = q >> 2;
      int kc  = (q & 3) << 3;
      const __hip_bfloat16* ga = A  + (size_t)(bm + row) * K + k0 + kc;
      const __hip_bfloat16* gb = Bw + (size_t)(bn + row) * K + k0 + kc;
      __builtin_amdgcn_global_load_lds((const __attribute__((address_space(1))) unsigned int*)ga,
                                       (__attribute__((address_space(3))) unsigned int*)(As + q * 8),
                                       16, 0, 0);
      __builtin_amdgcn_global_load_lds((const __attribute__((address_space(1))) unsigned int*)gb,
                                       (__attribute__((address_space(3))) unsigned int*)(Bs + q * 8),
                                       16, 0, 0);
    }
    __syncthreads();

    bf16x8 af[4], bfr[4];
    #pragma unroll
    for (int i = 0; i < 4; ++i) {
      af[i]  = *(const bf16x8*)(As + (wm + i * 16 + r16) * 32 + kg * 8);
      bfr[i] = *(const bf16x8*)(Bs + (wn + i * 16 + r16) * 32 + kg * 8);
    }
    #pragma unroll
    for (int mi = 0; mi < 4; ++mi)
      #pragma unroll
      for (int ni = 0; ni < 4; ++ni)
        acc[mi][ni] = __builtin_amdgcn_mfma_f32_16x16x32_bf16(af[mi], bfr[ni], acc[mi][ni], 0, 0, 0);
    __syncthreads();
  }

  // C/D layout: col = lane&15, row = (lane>>4)*4 + j
  #pragma unroll
  for (int mi = 0; mi < 4; ++mi) {
    #pragma unroll
    for (int ni = 0; ni < 4; ++ni) {
      #pragma unroll
      for (int j = 0; j < 4; ++j) {
        int r = bm + wm + mi * 16 + kg * 4 + j;
        int c = bn + wn + ni * 16 + r16;
        size_t idx = (size_t)r * N + c;
        float v = acc[mi][ni][j];
        if constexpr (EPI == 0) {
          Cf[idx] = v;
        } else if constexpr (EPI == 1) {
          Cf[idx] = v + add_src[idx];
        } else if constexpr (EPI == 2) {
          Cb[idx] = __float2bfloat16(siluf(v));
        } else if constexpr (EPI == 3) {
          Cb[idx] = __float2bfloat16(v * __bfloat162float(Cb[idx]));
        }
      }
    }
  }
}

// ---------------------------------------------------------------- conv+silu+normalize for the 32 B/C channels
__global__ __launch_bounds__(256) void bcdt_k(const float* __restrict__ zx,
                                              const float* __restrict__ cw,
                                              const float* __restrict__ cb,
                                              float* __restrict__ bc) {
  int t = threadIdx.x;
  int r = blockIdx.x * 8 + (t >> 5);
  int ch = t & 31;
  int l = r & (SEQ - 1);
  int c = D_INNER + ch;                       // conv channel 2048+ch
  float acc = cb[c];
  #pragma unroll
  for (int k = 0; k < 4; ++k) {
    int lp = l - 3 + k;
    if (lp >= 0)
      acc = fmaf(zx[(size_t)(r - 3 + k) * PROJ_PAD + 2 * D_INNER + ch], cw[c * 4 + k], acc);
  }
  acc = siluf(acc);
  float ss = acc * acc;
  ss += __shfl_xor(ss, 1);
  ss += __shfl_xor(ss, 2);
  ss += __shfl_xor(ss, 4);
  ss += __shfl_xor(ss, 8);
  bc[r * 32 + ch] = acc / (sqrtf(ss) + 1e-6f);
}

// ---------------------------------------------------------------- chunk transfer matrices (2x2 per (b,h,n,chunk))
// M_t = [[S, -dt*A*S],[dt*S, 1-dt^2*A*S]];  P_chunk = prod_{t in chunk} M_t
__global__ __launch_bounds__(256) void pk_k(const float* __restrict__ dtT,
                                            const float* __restrict__ A_log,
                                            float* __restrict__ Pm) {
  int bh = blockIdx.x;                  // b*32+h
  int h = bh & 31;
  int t = threadIdx.x;
  int ch = t >> 4, n = t & 15;
  float a = __expf(A_log[h * 16 + n]);
  const float* dtp = dtT + (size_t)h * ROWS + (size_t)(bh >> 5) * SEQ + ch * CH;
  float p00 = 1.f, p01 = 0.f, p10 = 0.f, p11 = 1.f;
  for (int l = 0; l < CH; ++l) {
    float dt = dtp[l];
    float s  = 1.0f / fmaf(dt * dt, a, 1.0f);
    float m00 = s;
    float m01 = -dt * a * s;
    float m10 = dt * s;
    float m11 = fmaf(-dt * a, m10, 1.0f);
    float q00 = fmaf(m00, p00, m01 * p10);
    float q01 = fmaf(m00, p01, m01 * p11);
    float q10 = fmaf(m10, p00, m11 * p10);
    float q11 = fmaf(m10, p01, m11 * p11);
    p00 = q00; p01 = q01; p10 = q10; p11 = q11;
  }
  float4 v = {p00, p01, p10, p11};
  *(float4*)&Pm[(((size_t)bh * NCH + ch) * 16 + n) * 4] = v;
}

// ---------------------------------------------------------------- propagate chunk-boundary states
// thread = (b,h,d,n); sequential over 16 chunks; sinit[c] = state BEFORE chunk c.
__global__ __launch_bounds__(256) void prop_k(const float* __restrict__ Pm,
                                              const float* __restrict__ pend,
                                              float* __restrict__ sinit) {
  int gid = blockIdx.x * 256 + threadIdx.x;   // ((bh*64+d)*16+n)
  int n  = gid & 15;
  int d  = (gid >> 4) & 63;
  int bh = gid >> 10;
  float s0 = 0.f, s1 = 0.f;
  for (int c = 0; c < NCH; ++c) {
    size_t i2 = (((size_t)bh * NCH + c) * 64 + d) * 16 + n;
    *(float2*)&sinit[i2 * 2] = make_float2(s0, s1);
    float4 P  = *(const float4*)&Pm[(((size_t)bh * NCH + c) * 16 + n) * 4];
    float2 pe = *(const float2*)&pend[i2 * 2];
    float t0 = fmaf(P.x, s0, fmaf(P.y, s1, pe.x));
    float t1 = fmaf(P.z, s0, fmaf(P.w, s1, pe.y));
    s0 = t0; s1 = t1;
  }
}

// ---------------------------------------------------------------- chunked scan, LDS-tiled double-buffered
// block = (b,h,chunk,half): 4096 blocks x 128 threads (2 waves).
// PHASE 1: zero init, recurrence only, write end-of-chunk states to `states`.
// PHASE 3: init from `states` (sinit), full outputs to po.
#define T_TILE 16
#define TPC (CH / T_TILE)          // 8 tiles per chunk
template<int PHASE>
__global__ __launch_bounds__(128) void scan_k(
    const float* __restrict__ zx, const float* __restrict__ bcb,
    const float* __restrict__ dtT, const float* __restrict__ A_log,
    const float* __restrict__ Dp, const float* __restrict__ cw,
    const float* __restrict__ cb, float* __restrict__ states,
    __hip_bfloat16* __restrict__ po)
{
  const int blk  = blockIdx.x;
  const int half = blk & 1;
  const int ch   = (blk >> 1) & 15;
  const int h    = (blk >> 5) & 31;
  const int b    = blk >> 10;
  const int bh   = b * 32 + h;
  const int tid  = threadIdx.x;
  const int wv   = tid >> 6;
  const int lane = tid & 63;
  const int d16  = lane & 15;
  const int ng   = lane >> 4;
  const int n0   = ng * 4;
  const int dl   = half * 32 + wv * 16 + d16;            // d within head [0,64)
  const int dcol = h * 64 + dl;                          // global channel
  const size_t rowbase = (size_t)b * SEQ + (size_t)ch * CH;

  __shared__ float xz [2][T_TILE][64];   // [0..31]=z cols, [32..63]=x cols (this block's 32 d)
  __shared__ float bct[2][T_TILE][32];   // B16 | C16
  __shared__ float st [2][T_TILE][16];   // S
  __shared__ float dtt[2][T_TILE];
  __shared__ float aexp[16];
  __shared__ float opart[T_TILE][32][4]; // [l][d_local][ng] partial o (PHASE 3)

  if (tid < 16) aexp[tid] = __expf(A_log[h * 16 + tid]);

  float A4[4];
  #pragma unroll
  for (int j = 0; j < 4; ++j) A4[j] = __expf(A_log[h * 16 + n0 + j]);
  const float Dh = Dp[h];
  const float c0 = cw[dcol * 4 + 0], c1 = cw[dcol * 4 + 1];
  const float c2 = cw[dcol * 4 + 2], c3 = cw[dcol * 4 + 3];
  const float cbv = cb[dcol];

  // --- staging: all via global_load_lds width 16 (dest = base + lane*16) ---
  auto stage = [&](int tile, int buf) {
    const size_t r0 = rowbase + (size_t)tile * T_TILE;
    #pragma unroll
    for (int i = 0; i < 2; ++i) {
      int lr = 8 * i + 4 * wv + (lane >> 4);          // tile-local row
      int c4 = (lane & 15) * 4;                        // f32 col in [0,64)
      int col = (c4 < 32) ? (h * 64 + half * 32 + c4)
                          : (D_INNER + h * 64 + half * 32 + (c4 - 32));
      const float* g = zx + (r0 + lr) * PROJ_PAD + col;
      float* l = &xz[buf][0][0] + (8 * i + 4 * wv) * 64 + (lane & 15) * 4;
      __builtin_amdgcn_global_load_lds((const __attribute__((address_space(1))) unsigned int*)g,
                                       (__attribute__((address_space(3))) unsigned int*)l,
                                       16, 0, 0);
    }
    {
      int lr = 8 * wv + (lane >> 3);
      const float* g = bcb + (r0 + lr) * 32 + (lane & 7) * 4;
      float* l = &bct[buf][0][0] + 8 * wv * 32 + (lane & 7) * 4;
      __builtin_amdgcn_global_load_lds((const __attribute__((address_space(1))) unsigned int*)g,
                                       (__attribute__((address_space(3))) unsigned int*)l,
                                       16, 0, 0);
    }
  };

  auto sprep = [&](int buf, float dtn) {
    #pragma unroll
    for (int i = 0; i < 2; ++i) {
      int idx = tid + 128 * i;          // 0..255
      int row = idx >> 4, n = idx & 15;
      float dv = __shfl(dtn, row);
      float a  = aexp[n];
      st[buf][row][n] = 1.0f / fmaf(dv * dv, a, 1.0f);
    }
  };

  // --- prologue: tile 0 ---
  stage(0, 0);
  float dtn = 0.f;
  if (lane < 16) dtn = dtT[(size_t)h * ROWS + rowbase + lane];
  __syncthreads();
  if (tid < 16) dtt[0][tid] = dtn;
  sprep(0, dtn);
  __syncthreads();

  // --- state init ---
  float w[4], ys[4];
  if constexpr (PHASE == 1) {
    #pragma unroll
    for (int j = 0; j < 4; ++j) { w[j] = 0.f; ys[j] = 0.f; }
  } else {
    #pragma unroll
    for (int j = 0; j < 4; ++j) {
      size_t i2 = (((size_t)bh * NCH + ch) * 64 + dl) * 16 + (n0 + j);
      float2 s = *(const float2*)&states[i2 * 2];
      w[j] = s.x; ys[j] = s.y;
    }
  }
  // conv halo from previous rows (within same batch element; ch>0 => history exists)
  float xw1 = 0.f, xw2 = 0.f, xw3 = 0.f;
  if (ch > 0) {
    const float* xb = zx + rowbase * PROJ_PAD + D_INNER + dcol;
    xw1 = xb[-3 * PROJ_PAD];
    xw2 = xb[-2 * PROJ_PAD];
    xw3 = xb[-1 * PROJ_PAD];
  }
  int cur = 0;

  for (int t = 0; t < TPC; ++t) {
    if (t + 1 < TPC) {
      stage(t + 1, cur ^ 1);
      if (lane < 16) dtn = dtT[(size_t)h * ROWS + rowbase + (size_t)(t + 1) * T_TILE + lane];
    }
    // ---- phase A: 16 serial steps, recurrence only
    #pragma unroll 4
    for (int l = 0; l < T_TILE; ++l) {
      float xl  = xz[cur][l][32 + wv * 16 + d16];
      float dtv = dtt[cur][l];
      f32x4 Sv = *(const f32x4*)&st [cur][l][n0];
      f32x4 Bv = *(const f32x4*)&bct[cur][l][n0];
      float cacc = fmaf(c3, xl, fmaf(c2, xw3, fmaf(c1, xw2, fmaf(c0, xw1, cbv))));
      float uv = siluf(cacc);
      xw1 = xw2; xw2 = xw3; xw3 = xl;
      float du = dtv * uv;
      if constexpr (PHASE == 3) {
        f32x4 Cv = *(const f32x4*)&bct[cur][l][16 + n0];
        float o = 0.f;
        #pragma unroll
        for (int j = 0; j < 4; ++j) {
          float tmp = fmaf(-(dtv * A4[j]), ys[j], w[j]);
          tmp = fmaf(du, Bv[j], tmp);
          w[j] = Sv[j] * tmp;
          ys[j] = fmaf(dtv, w[j], ys[j]);
          o = fmaf(ys[j], Cv[j], o);
        }
        float ofin = (ng == 0) ? fmaf(Dh, uv, o) : o;
        opart[l][wv * 16 + d16][ng] = ofin;
      } else {
        #pragma unroll
        for (int j = 0; j < 4; ++j) {
          float tmp = fmaf(-(dtv * A4[j]), ys[j], w[j]);
          tmp = fmaf(du, Bv[j], tmp);
          w[j] = Sv[j] * tmp;
          ys[j] = fmaf(dtv, w[j], ys[j]);
        }
      }
    }
    // ---- phase B (PHASE 3 only): per-wave reduce + output
    if constexpr (PHASE == 3) {
      #pragma unroll
      for (int i = 0; i < 4; ++i) {
        int l  = (lane >> 4) + 4 * i;
        int dd = wv * 16 + d16;
        f32x4 op = *(const f32x4*)&opart[l][dd][0];
        float zv = xz[cur][l][dd];
        float yv = (op[0] + op[1]) + (op[2] + op[3]);
        po[(rowbase + (size_t)t * T_TILE + l) * D_INNER + (h * 64 + half * 32 + dd)] =
            __float2bfloat16(yv * siluf(zv));
      }
    }
    __syncthreads();                     // drains vmcnt: buf[cur^1] + dtn ready
    if (t + 1 < TPC) {
      if (tid < 16) dtt[cur ^ 1][tid] = dtn;
      sprep(cur ^ 1, dtn);
      __syncthreads();
    }
    cur ^= 1;
  }

  if constexpr (PHASE == 1) {
    #pragma unroll
    for (int j = 0; j < 4; ++j) {
      size_t i2 = (((size_t)bh * NCH + ch) * 64 + dl) * 16 + (n0 + j);
      *(float2*)&states[i2 * 2] = make_float2(w[j], ys[j]);
    }
  }
}

// ---------------------------------------------------------------- launch
extern "C" void kernel_launch(void* const* d_in, const int* in_sizes, int n_in,
                              void* d_out, int out_size, void* d_ws, size_t ws_size,
                              hipStream_t stream) {
  const float* x     = (const float*)d_in[0];
  const float* n1w   = (const float*)d_in[1];
  const float* wi    = (const float*)d_in[2];
  const float* cw    = (const float*)d_in[3];
  const float* cb    = (const float*)d_in[4];
  const float* A_log = (const float*)d_in[5];
  const float* dtb   = (const float*)d_in[6];
  const float* Dp    = (const float*)d_in[7];
  const float* wo    = (const float*)d_in[8];
  const float* n2w   = (const float*)d_in[9];
  const float* wg    = (const float*)d_in[10];
  const float* wu    = (const float*)d_in[11];
  const float* wd    = (const float*)d_in[12];
  float* out = (float*)d_out;

  char* p = (char*)d_ws;
  auto take = [&](size_t b) { char* q = p; p += (b + 255) & ~(size_t)255; return q; };
  __hip_bfloat16* wbi  = (__hip_bfloat16*)take((size_t)PROJ_PAD * D_MODEL * 2);   //  8.25 MB
  __hip_bfloat16* wbo  = (__hip_bfloat16*)take((size_t)D_MODEL * D_INNER * 2);    //  4    MB
  __hip_bfloat16* wbg  = (__hip_bfloat16*)take((size_t)FFN_DIM * D_MODEL * 2);    //  5.5  MB
  __hip_bfloat16* wbu  = (__hip_bfloat16*)take((size_t)FFN_DIM * D_MODEL * 2);    //  5.5  MB
  __hip_bfloat16* wbd  = (__hip_bfloat16*)take((size_t)D_MODEL * FFN_DIM * 2);    //  5.5  MB
  __hip_bfloat16* h0b  = (__hip_bfloat16*)take((size_t)ROWS * D_MODEL * 2);       // 16    MB
  float*          zx   = (float*)take((size_t)ROWS * PROJ_PAD * 4);               // 132   MB
  float*          bcb  = (float*)take((size_t)ROWS * 32 * 4);                     //  1    MB
  float*          dtT  = (float*)take((size_t)ROWS * 32 * 4);                     //  1    MB  [h][r]
  __hip_bfloat16* po   = (__hip_bfloat16*)take((size_t)ROWS * D_INNER * 2);       // 32    MB
  float*          pend = (float*)take((size_t)128 * NCH * 64 * 16 * 2 * 4);       // 16.8  MB
  float*          sini = (float*)take((size_t)128 * NCH * 64 * 16 * 2 * 4);       // 16.8  MB
  float*          Pm   = (float*)take((size_t)128 * NCH * 16 * 4 * 4);            //  0.5  MB
  // aliases into the zx region (zx dead after scan_k<3>):
  float*          h0f  = (float*)zx;                                  // live only rmsnorm->dtproj
  float*          h    = (float*)zx;                                  // 32 MB, live after scan
  __hip_bfloat16* gact = (__hip_bfloat16*)((char*)zx + 33554432);     // 44 MB, disjoint from h

  // weight conversions
  cvt_pad_k<<<(PROJ_PAD * D_MODEL + 255) / 256, 256, 0, stream>>>(wi, wbi);
  cvt_k<<<(D_MODEL * D_INNER + 255) / 256, 256, 0, stream>>>(wo, wbo, D_MODEL * D_INNER);
  cvt_k<<<(FFN_DIM * D_MODEL + 255) / 256, 256, 0, stream>>>(wg, wbg, FFN_DIM * D_MODEL);
  cvt_k<<<(FFN_DIM * D_MODEL + 255) / 256, 256, 0, stream>>>(wu, wbu, FFN_DIM * D_MODEL);
  cvt_k<<<(FFN_DIM * D_MODEL + 255) / 256, 256, 0, stream>>>(wd, wbd, FFN_DIM * D_MODEL);

  // mixer
  rmsnorm_k<<<ROWS, 256, 0, stream>>>(x, n1w, h0b, h0f);
  dtproj_k<<<ROWS * 32 / 256, 256, 0, stream>>>(h0f, wi, dtb, dtT);   // before zx is clobbered
  gemm_bt<0><<<(ROWS / 128) * (PROJ_PAD / 128), 256, 0, stream>>>(h0b, wbi, zx, nullptr, nullptr,
                                                                  ROWS, PROJ_PAD, D_MODEL);
  bcdt_k<<<ROWS / 8, 256, 0, stream>>>(zx, cw, cb, bcb);
  // chunked scan: transfer matrices, particular pass, boundary propagation, final pass
  pk_k<<<BATCH * N_HEADS, 256, 0, stream>>>(dtT, A_log, Pm);
  scan_k<1><<<BATCH * N_HEADS * NCH * 2, 128, 0, stream>>>(zx, bcb, dtT, A_log, Dp, cw, cb, pend, nullptr);
  prop_k<<<BATCH * N_HEADS * 64 * 16 / 256, 256, 0, stream>>>(Pm, pend, sini);
  scan_k<3><<<BATCH * N_HEADS * NCH * 2, 128, 0, stream>>>(zx, bcb, dtT, A_log, Dp, cw, cb, sini, po);
  gemm_bt<1><<<(ROWS / 128) * (D_MODEL / 128), 256, 0, stream>>>(po, wbo, h, nullptr, x,
                                                                 ROWS, D_MODEL, D_INNER);
  // FFN
  rmsnorm_k<<<ROWS, 256, 0, stream>>>(h, n2w, h0b, nullptr);
  gemm_bt<2><<<(ROWS / 128) * (FFN_DIM / 128), 256, 0, stream>>>(h0b, wbg, nullptr, gact, nullptr,
                                                                 ROWS, FFN_DIM, D_MODEL);
  gemm_bt<3><<<(ROWS / 128) * (FFN_DIM / 128), 256, 0, stream>>>(h0b, wbu, nullptr, gact, nullptr,
                                                                 ROWS, FFN_DIM, D_MODEL);
  gemm_bt<1><<<(ROWS / 128) * (D_MODEL / 128), 256, 0, stream>>>(gact, wbd, out, nullptr, h,
                                                                 ROWS, D_MODEL, FFN_DIM);
}

// Round 7
// 781.239 us; speedup vs baseline: 2.1547x; 1.0944x over previous
//
#include <hip/hip_runtime.h>
#include <hip/hip_bf16.h>

#define D_MODEL   1024
#define D_STATE   16
#define D_HEAD    64
#define D_CONV    4
#define FFN_DIM   2816
#define D_INNER   2048
#define N_HEADS   32
#define BATCH     4
#define SEQ       2048
#define ROWS      (BATCH*SEQ)     // 8192
#define PROJ_DIM  4160
#define PROJ_PAD  4224            // 33 * 128
#define CONV_CH   2080            // D_INNER + 2*D_STATE
#define CH        128             // scan chunk length
#define NCH       (SEQ/CH)        // 16 chunks

typedef __bf16 bf16x8 __attribute__((ext_vector_type(8)));
typedef float  f32x4  __attribute__((ext_vector_type(4)));

__device__ __forceinline__ float siluf(float x) { return x / (1.0f + __expf(-x)); }

// ---------------------------------------------------------------- converts
__global__ void cvt_k(const float* __restrict__ src, __hip_bfloat16* __restrict__ dst, int n) {
  int i = blockIdx.x * blockDim.x + threadIdx.x;
  if (i < n) dst[i] = __float2bfloat16(src[i]);
}

// in_proj: [4160][1024] f32 -> [4224][1024] bf16, zero-padded rows
__global__ void cvt_pad_k(const float* __restrict__ src, __hip_bfloat16* __restrict__ dst) {
  int i = blockIdx.x * blockDim.x + threadIdx.x;
  if (i >= PROJ_PAD * D_MODEL) return;
  int row = i >> 10;
  dst[i] = (row < PROJ_DIM) ? __float2bfloat16(src[i]) : __float2bfloat16(0.0f);
}

// ---------------------------------------------------------------- rmsnorm (f32 in -> bf16 out, optional f32 out)
__global__ __launch_bounds__(256) void rmsnorm_k(const float* __restrict__ x,
                                                 const float* __restrict__ w,
                                                 __hip_bfloat16* __restrict__ out,
                                                 float* __restrict__ outf) {
  int row = blockIdx.x;
  int t = threadIdx.x;
  const float* xr = x + (size_t)row * D_MODEL;
  float4 v = ((const float4*)xr)[t];            // 256 threads * 4 = 1024
  float ss = v.x*v.x + v.y*v.y + v.z*v.z + v.w*v.w;
  #pragma unroll
  for (int o = 32; o > 0; o >>= 1) ss += __shfl_xor(ss, o);
  __shared__ float red[4];
  if ((t & 63) == 0) red[t >> 6] = ss;
  __syncthreads();
  ss = red[0] + red[1] + red[2] + red[3];
  float scale = rsqrtf(ss * (1.0f / D_MODEL) + 1e-6f);
  float4 wv = ((const float4*)w)[t];
  float4 r;
  r.x = v.x * scale * wv.x; r.y = v.y * scale * wv.y;
  r.z = v.z * scale * wv.z; r.w = v.w * scale * wv.w;
  __hip_bfloat16* orow = out + (size_t)row * D_MODEL + t * 4;
  orow[0] = __float2bfloat16(r.x);
  orow[1] = __float2bfloat16(r.y);
  orow[2] = __float2bfloat16(r.z);
  orow[3] = __float2bfloat16(r.w);
  if (outf) ((float4*)(outf + (size_t)row * D_MODEL))[t] = r;
}

// ---------------------------------------------------------------- dt projection, f32, block-per-4-rows
// grid = ROWS/4 blocks x 256 threads. thread: hh = t>>3 (head), seg = t&7 (k-segment of 128).
__global__ __launch_bounds__(256) void dtproj_k(const float* __restrict__ xn,
                                                const float* __restrict__ wi,
                                                const float* __restrict__ dtb,
                                                float* __restrict__ dtT) {
  const int r0 = blockIdx.x * 4;
  const int t  = threadIdx.x;
  const int hh  = t >> 3;
  const int seg = t & 7;

  __shared__ float xs[4][D_MODEL];
  #pragma unroll
  for (int i = 0; i < 4; ++i)
    ((float4*)&xs[i][0])[t] = ((const float4*)(xn + (size_t)(r0 + i) * D_MODEL))[t];
  __syncthreads();

  const float4* w4 = (const float4*)(wi + (size_t)(2 * D_INNER + 2 * D_STATE + hh) * D_MODEL) + seg * 32;
  const float4* x0 = (const float4*)&xs[0][0] + seg * 32;
  const float4* x1 = (const float4*)&xs[1][0] + seg * 32;
  const float4* x2 = (const float4*)&xs[2][0] + seg * 32;
  const float4* x3 = (const float4*)&xs[3][0] + seg * 32;
  float a0 = 0.f, a1 = 0.f, a2 = 0.f, a3 = 0.f;
  #pragma unroll 8
  for (int k = 0; k < 32; ++k) {
    float4 wv = w4[k];
    float4 v0 = x0[k], v1 = x1[k], v2 = x2[k], v3 = x3[k];
    a0 = fmaf(wv.x, v0.x, fmaf(wv.y, v0.y, fmaf(wv.z, v0.z, fmaf(wv.w, v0.w, a0))));
    a1 = fmaf(wv.x, v1.x, fmaf(wv.y, v1.y, fmaf(wv.z, v1.z, fmaf(wv.w, v1.w, a1))));
    a2 = fmaf(wv.x, v2.x, fmaf(wv.y, v2.y, fmaf(wv.z, v2.z, fmaf(wv.w, v2.w, a2))));
    a3 = fmaf(wv.x, v3.x, fmaf(wv.y, v3.y, fmaf(wv.z, v3.z, fmaf(wv.w, v3.w, a3))));
  }
  // reduce the 8 segments (lanes t^1, t^2, t^4 share hh)
  #pragma unroll
  for (int m = 1; m < 8; m <<= 1) {
    a0 += __shfl_xor(a0, m);
    a1 += __shfl_xor(a1, m);
    a2 += __shfl_xor(a2, m);
    a3 += __shfl_xor(a3, m);
  }
  if (seg == 0) {
    float bias = dtb[hh];
    float v[4] = {a0, a1, a2, a3};
    #pragma unroll
    for (int i = 0; i < 4; ++i) {
      float xv = v[i] + bias;
      dtT[(size_t)hh * ROWS + r0 + i] = (xv > 20.f) ? xv : log1pf(__expf(xv));
    }
  }
}

// ---------------------------------------------------------------- GEMM  C[M,N] = A[M,K] * Bw[N,K]^T
// EPI: 0 = store f32; 1 = f32 store of (acc + add_src); 2 = bf16 store of silu(acc);
//      3 = bf16 in-place: Cb *= acc
template<int EPI>
__global__ __launch_bounds__(256) void gemm_bt(
    const __hip_bfloat16* __restrict__ A,
    const __hip_bfloat16* __restrict__ Bw,
    float* __restrict__ Cf,
    __hip_bfloat16* __restrict__ Cb,
    const float* __restrict__ add_src,
    int M, int N, int K)
{
  const int tid  = threadIdx.x;
  const int wave = tid >> 6;
  const int lane = tid & 63;
  const int nTilesN = N >> 7;
  const int bm = (blockIdx.x / nTilesN) << 7;
  const int bn = (blockIdx.x % nTilesN) << 7;

  __shared__ __hip_bfloat16 As[128 * 32];
  __shared__ __hip_bfloat16 Bs[128 * 32];

  const int wm = (wave >> 1) << 6;   // 0 or 64
  const int wn = (wave & 1) << 6;    // 0 or 64
  const int r16 = lane & 15;
  const int kg  = lane >> 4;         // 0..3

  f32x4 acc[4][4] = {};

  for (int k0 = 0; k0 < K; k0 += 32) {
    #pragma unroll
    for (int i = 0; i < 2; ++i) {
      int q = tid + 256 * i;
      int row = q >> 2;
      int kc  = (q & 3) << 3;
      const __hip_bfloat16* ga = A  + (size_t)(bm + row) * K + k0 + kc;
      const __hip_bfloat16* gb = Bw + (size_t)(bn + row) * K + k0 + kc;
      __builtin_amdgcn_global_load_lds((const __attribute__((address_space(1))) unsigned int*)ga,
                                       (__attribute__((address_space(3))) unsigned int*)(As + q * 8),
                                       16, 0, 0);
      __builtin_amdgcn_global_load_lds((const __attribute__((address_space(1))) unsigned int*)gb,
                                       (__attribute__((address_space(3))) unsigned int*)(Bs + q * 8),
                                       16, 0, 0);
    }
    __syncthreads();

    bf16x8 af[4], bfr[4];
    #pragma unroll
    for (int i = 0; i < 4; ++i) {
      af[i]  = *(const bf16x8*)(As + (wm + i * 16 + r16) * 32 + kg * 8);
      bfr[i] = *(const bf16x8*)(Bs + (wn + i * 16 + r16) * 32 + kg * 8);
    }
    #pragma unroll
    for (int mi = 0; mi < 4; ++mi)
      #pragma unroll
      for (int ni = 0; ni < 4; ++ni)
        acc[mi][ni] = __builtin_amdgcn_mfma_f32_16x16x32_bf16(af[mi], bfr[ni], acc[mi][ni], 0, 0, 0);
    __syncthreads();
  }

  // C/D layout: col = lane&15, row = (lane>>4)*4 + j
  #pragma unroll
  for (int mi = 0; mi < 4; ++mi) {
    #pragma unroll
    for (int ni = 0; ni < 4; ++ni) {
      #pragma unroll
      for (int j = 0; j < 4; ++j) {
        int r = bm + wm + mi * 16 + kg * 4 + j;
        int c = bn + wn + ni * 16 + r16;
        size_t idx = (size_t)r * N + c;
        float v = acc[mi][ni][j];
        if constexpr (EPI == 0) {
          Cf[idx] = v;
        } else if constexpr (EPI == 1) {
          Cf[idx] = v + add_src[idx];
        } else if constexpr (EPI == 2) {
          Cb[idx] = __float2bfloat16(siluf(v));
        } else if constexpr (EPI == 3) {
          Cb[idx] = __float2bfloat16(v * __bfloat162float(Cb[idx]));
        }
      }
    }
  }
}

// ---------------------------------------------------------------- conv+silu+normalize for the 32 B/C channels
__global__ __launch_bounds__(256) void bcdt_k(const float* __restrict__ zx,
                                              const float* __restrict__ cw,
                                              const float* __restrict__ cb,
                                              float* __restrict__ bc) {
  int t = threadIdx.x;
  int r = blockIdx.x * 8 + (t >> 5);
  int ch = t & 31;
  int l = r & (SEQ - 1);
  int c = D_INNER + ch;                       // conv channel 2048+ch
  float acc = cb[c];
  #pragma unroll
  for (int k = 0; k < 4; ++k) {
    int lp = l - 3 + k;
    if (lp >= 0)
      acc = fmaf(zx[(size_t)(r - 3 + k) * PROJ_PAD + 2 * D_INNER + ch], cw[c * 4 + k], acc);
  }
  acc = siluf(acc);
  float ss = acc * acc;
  ss += __shfl_xor(ss, 1);
  ss += __shfl_xor(ss, 2);
  ss += __shfl_xor(ss, 4);
  ss += __shfl_xor(ss, 8);
  bc[r * 32 + ch] = acc / (sqrtf(ss) + 1e-6f);
}

// ---------------------------------------------------------------- chunk transfer matrices (2x2 per (b,h,n,chunk))
// M_t = [[S, -dt*A*S],[dt*S, 1-dt^2*A*S]];  P_chunk = prod_{t in chunk} M_t
__global__ __launch_bounds__(256) void pk_k(const float* __restrict__ dtT,
                                            const float* __restrict__ A_log,
                                            float* __restrict__ Pm) {
  int bh = blockIdx.x;                  // b*32+h
  int h = bh & 31;
  int t = threadIdx.x;
  int ch = t >> 4, n = t & 15;
  float a = __expf(A_log[h * 16 + n]);
  const float* dtp = dtT + (size_t)h * ROWS + (size_t)(bh >> 5) * SEQ + ch * CH;
  float p00 = 1.f, p01 = 0.f, p10 = 0.f, p11 = 1.f;
  for (int l = 0; l < CH; ++l) {
    float dt = dtp[l];
    float s  = 1.0f / fmaf(dt * dt, a, 1.0f);
    float m00 = s;
    float m01 = -dt * a * s;
    float m10 = dt * s;
    float m11 = fmaf(-dt * a, m10, 1.0f);
    float q00 = fmaf(m00, p00, m01 * p10);
    float q01 = fmaf(m00, p01, m01 * p11);
    float q10 = fmaf(m10, p00, m11 * p10);
    float q11 = fmaf(m10, p01, m11 * p11);
    p00 = q00; p01 = q01; p10 = q10; p11 = q11;
  }
  float4 v = {p00, p01, p10, p11};
  *(float4*)&Pm[(((size_t)bh * NCH + ch) * 16 + n) * 4] = v;
}

// ---------------------------------------------------------------- propagate chunk-boundary states
// thread = (b,h,d,n); sequential over 16 chunks; sinit[c] = state BEFORE chunk c.
__global__ __launch_bounds__(256) void prop_k(const float* __restrict__ Pm,
                                              const float* __restrict__ pend,
                                              float* __restrict__ sinit) {
  int gid = blockIdx.x * 256 + threadIdx.x;   // ((bh*64+d)*16+n)
  int n  = gid & 15;
  int d  = (gid >> 4) & 63;
  int bh = gid >> 10;
  float s0 = 0.f, s1 = 0.f;
  for (int c = 0; c < NCH; ++c) {
    size_t i2 = (((size_t)bh * NCH + c) * 64 + d) * 16 + n;
    *(float2*)&sinit[i2 * 2] = make_float2(s0, s1);
    float4 P  = *(const float4*)&Pm[(((size_t)bh * NCH + c) * 16 + n) * 4];
    float2 pe = *(const float2*)&pend[i2 * 2];
    float t0 = fmaf(P.x, s0, fmaf(P.y, s1, pe.x));
    float t1 = fmaf(P.z, s0, fmaf(P.w, s1, pe.y));
    s0 = t0; s1 = t1;
  }
}

// ---------------------------------------------------------------- chunked scan, LDS-tiled double-buffered
// block = (b,h,chunk,half): 4096 blocks x 128 threads (2 waves).
// PHASE 1: zero init, recurrence only, write end-of-chunk states to `states`.
// PHASE 3: init from `states` (sinit), full outputs to po.
#define T_TILE 16
#define TPC (CH / T_TILE)          // 8 tiles per chunk
template<int PHASE>
__global__ __launch_bounds__(128) void scan_k(
    const float* __restrict__ zx, const float* __restrict__ bcb,
    const float* __restrict__ dtT, const float* __restrict__ A_log,
    const float* __restrict__ Dp, const float* __restrict__ cw,
    const float* __restrict__ cb, float* __restrict__ states,
    __hip_bfloat16* __restrict__ po)
{
  const int blk  = blockIdx.x;
  const int half = blk & 1;
  const int ch   = (blk >> 1) & 15;
  const int h    = (blk >> 5) & 31;
  const int b    = blk >> 10;
  const int bh   = b * 32 + h;
  const int tid  = threadIdx.x;
  const int wv   = tid >> 6;
  const int lane = tid & 63;
  const int d16  = lane & 15;
  const int ng   = lane >> 4;
  const int n0   = ng * 4;
  const int dl   = half * 32 + wv * 16 + d16;            // d within head [0,64)
  const int dcol = h * 64 + dl;                          // global channel
  const size_t rowbase = (size_t)b * SEQ + (size_t)ch * CH;

  __shared__ float xz [2][T_TILE][64];   // [0..31]=z cols, [32..63]=x cols (this block's 32 d)
  __shared__ float bct[2][T_TILE][32];   // B16 | C16
  __shared__ float st [2][T_TILE][16];   // S
  __shared__ float dtt[2][T_TILE];
  __shared__ float aexp[16];
  __shared__ float opart[T_TILE][32][4]; // [l][d_local][ng] partial o (PHASE 3)

  if (tid < 16) aexp[tid] = __expf(A_log[h * 16 + tid]);

  float A4[4];
  #pragma unroll
  for (int j = 0; j < 4; ++j) A4[j] = __expf(A_log[h * 16 + n0 + j]);
  const float Dh = Dp[h];
  const float c0 = cw[dcol * 4 + 0], c1 = cw[dcol * 4 + 1];
  const float c2 = cw[dcol * 4 + 2], c3 = cw[dcol * 4 + 3];
  const float cbv = cb[dcol];

  // --- staging: all via global_load_lds width 16 (dest = base + lane*16) ---
  auto stage = [&](int tile, int buf) {
    const size_t r0 = rowbase + (size_t)tile * T_TILE;
    #pragma unroll
    for (int i = 0; i < 2; ++i) {
      int lr = 8 * i + 4 * wv + (lane >> 4);          // tile-local row
      int c4 = (lane & 15) * 4;                        // f32 col in [0,64)
      int col = (c4 < 32) ? (h * 64 + half * 32 + c4)
                          : (D_INNER + h * 64 + half * 32 + (c4 - 32));
      const float* g = zx + (r0 + lr) * PROJ_PAD + col;
      float* l = &xz[buf][0][0] + (8 * i + 4 * wv) * 64 + (lane & 15) * 4;
      __builtin_amdgcn_global_load_lds((const __attribute__((address_space(1))) unsigned int*)g,
                                       (__attribute__((address_space(3))) unsigned int*)l,
                                       16, 0, 0);
    }
    {
      int lr = 8 * wv + (lane >> 3);
      const float* g = bcb + (r0 + lr) * 32 + (lane & 7) * 4;
      float* l = &bct[buf][0][0] + 8 * wv * 32 + (lane & 7) * 4;
      __builtin_amdgcn_global_load_lds((const __attribute__((address_space(1))) unsigned int*)g,
                                       (__attribute__((address_space(3))) unsigned int*)l,
                                       16, 0, 0);
    }
  };

  auto sprep = [&](int buf, float dtn) {
    #pragma unroll
    for (int i = 0; i < 2; ++i) {
      int idx = tid + 128 * i;          // 0..255
      int row = idx >> 4, n = idx & 15;
      float dv = __shfl(dtn, row);
      float a  = aexp[n];
      st[buf][row][n] = 1.0f / fmaf(dv * dv, a, 1.0f);
    }
  };

  // --- prologue: tile 0 ---
  stage(0, 0);
  float dtn = 0.f;
  if (lane < 16) dtn = dtT[(size_t)h * ROWS + rowbase + lane];
  __syncthreads();
  if (tid < 16) dtt[0][tid] = dtn;
  sprep(0, dtn);
  __syncthreads();

  // --- state init ---
  float w[4], ys[4];
  if constexpr (PHASE == 1) {
    #pragma unroll
    for (int j = 0; j < 4; ++j) { w[j] = 0.f; ys[j] = 0.f; }
  } else {
    #pragma unroll
    for (int j = 0; j < 4; ++j) {
      size_t i2 = (((size_t)bh * NCH + ch) * 64 + dl) * 16 + (n0 + j);
      float2 s = *(const float2*)&states[i2 * 2];
      w[j] = s.x; ys[j] = s.y;
    }
  }
  // conv halo from previous rows (within same batch element; ch>0 => history exists)
  float xw1 = 0.f, xw2 = 0.f, xw3 = 0.f;
  if (ch > 0) {
    const float* xb = zx + rowbase * PROJ_PAD + D_INNER + dcol;
    xw1 = xb[-3 * PROJ_PAD];
    xw2 = xb[-2 * PROJ_PAD];
    xw3 = xb[-1 * PROJ_PAD];
  }
  int cur = 0;

  for (int t = 0; t < TPC; ++t) {
    if (t + 1 < TPC) {
      stage(t + 1, cur ^ 1);
      if (lane < 16) dtn = dtT[(size_t)h * ROWS + rowbase + (size_t)(t + 1) * T_TILE + lane];
    }
    // ---- phase A: 16 serial steps, recurrence only
    #pragma unroll 4
    for (int l = 0; l < T_TILE; ++l) {
      float xl  = xz[cur][l][32 + wv * 16 + d16];
      float dtv = dtt[cur][l];
      f32x4 Sv = *(const f32x4*)&st [cur][l][n0];
      f32x4 Bv = *(const f32x4*)&bct[cur][l][n0];
      float cacc = fmaf(c3, xl, fmaf(c2, xw3, fmaf(c1, xw2, fmaf(c0, xw1, cbv))));
      float uv = siluf(cacc);
      xw1 = xw2; xw2 = xw3; xw3 = xl;
      float du = dtv * uv;
      if constexpr (PHASE == 3) {
        f32x4 Cv = *(const f32x4*)&bct[cur][l][16 + n0];
        float o = 0.f;
        #pragma unroll
        for (int j = 0; j < 4; ++j) {
          float tmp = fmaf(-(dtv * A4[j]), ys[j], w[j]);
          tmp = fmaf(du, Bv[j], tmp);
          w[j] = Sv[j] * tmp;
          ys[j] = fmaf(dtv, w[j], ys[j]);
          o = fmaf(ys[j], Cv[j], o);
        }
        float ofin = (ng == 0) ? fmaf(Dh, uv, o) : o;
        opart[l][wv * 16 + d16][ng] = ofin;
      } else {
        #pragma unroll
        for (int j = 0; j < 4; ++j) {
          float tmp = fmaf(-(dtv * A4[j]), ys[j], w[j]);
          tmp = fmaf(du, Bv[j], tmp);
          w[j] = Sv[j] * tmp;
          ys[j] = fmaf(dtv, w[j], ys[j]);
        }
      }
    }
    // ---- phase B (PHASE 3 only): per-wave reduce + output
    if constexpr (PHASE == 3) {
      #pragma unroll
      for (int i = 0; i < 4; ++i) {
        int l  = (lane >> 4) + 4 * i;
        int dd = wv * 16 + d16;
        f32x4 op = *(const f32x4*)&opart[l][dd][0];
        float zv = xz[cur][l][dd];
        float yv = (op[0] + op[1]) + (op[2] + op[3]);
        po[(rowbase + (size_t)t * T_TILE + l) * D_INNER + (h * 64 + half * 32 + dd)] =
            __float2bfloat16(yv * siluf(zv));
      }
    }
    __syncthreads();                     // drains vmcnt: buf[cur^1] + dtn ready
    if (t + 1 < TPC) {
      if (tid < 16) dtt[cur ^ 1][tid] = dtn;
      sprep(cur ^ 1, dtn);
      __syncthreads();
    }
    cur ^= 1;
  }

  if constexpr (PHASE == 1) {
    #pragma unroll
    for (int j = 0; j < 4; ++j) {
      size_t i2 = (((size_t)bh * NCH + ch) * 64 + dl) * 16 + (n0 + j);
      *(float2*)&states[i2 * 2] = make_float2(w[j], ys[j]);
    }
  }
}

// ---------------------------------------------------------------- launch
extern "C" void kernel_launch(void* const* d_in, const int* in_sizes, int n_in,
                              void* d_out, int out_size, void* d_ws, size_t ws_size,
                              hipStream_t stream) {
  const float* x     = (const float*)d_in[0];
  const float* n1w   = (const float*)d_in[1];
  const float* wi    = (const float*)d_in[2];
  const float* cw    = (const float*)d_in[3];
  const float* cb    = (const float*)d_in[4];
  const float* A_log = (const float*)d_in[5];
  const float* dtb   = (const float*)d_in[6];
  const float* Dp    = (const float*)d_in[7];
  const float* wo    = (const float*)d_in[8];
  const float* n2w   = (const float*)d_in[9];
  const float* wg    = (const float*)d_in[10];
  const float* wu    = (const float*)d_in[11];
  const float* wd    = (const float*)d_in[12];
  float* out = (float*)d_out;

  char* p = (char*)d_ws;
  auto take = [&](size_t b) { char* q = p; p += (b + 255) & ~(size_t)255; return q; };
  __hip_bfloat16* wbi  = (__hip_bfloat16*)take((size_t)PROJ_PAD * D_MODEL * 2);   //  8.25 MB
  __hip_bfloat16* wbo  = (__hip_bfloat16*)take((size_t)D_MODEL * D_INNER * 2);    //  4    MB
  __hip_bfloat16* wbg  = (__hip_bfloat16*)take((size_t)FFN_DIM * D_MODEL * 2);    //  5.5  MB
  __hip_bfloat16* wbu  = (__hip_bfloat16*)take((size_t)FFN_DIM * D_MODEL * 2);    //  5.5  MB
  __hip_bfloat16* wbd  = (__hip_bfloat16*)take((size_t)D_MODEL * FFN_DIM * 2);    //  5.5  MB
  __hip_bfloat16* h0b  = (__hip_bfloat16*)take((size_t)ROWS * D_MODEL * 2);       // 16    MB
  float*          zx   = (float*)take((size_t)ROWS * PROJ_PAD * 4);               // 132   MB
  float*          bcb  = (float*)take((size_t)ROWS * 32 * 4);                     //  1    MB
  float*          dtT  = (float*)take((size_t)ROWS * 32 * 4);                     //  1    MB  [h][r]
  __hip_bfloat16* po   = (__hip_bfloat16*)take((size_t)ROWS * D_INNER * 2);       // 32    MB
  float*          pend = (float*)take((size_t)128 * NCH * 64 * 16 * 2 * 4);       // 16.8  MB
  float*          sini = (float*)take((size_t)128 * NCH * 64 * 16 * 2 * 4);       // 16.8  MB
  float*          Pm   = (float*)take((size_t)128 * NCH * 16 * 4 * 4);            //  0.5  MB
  // aliases into the zx region (zx dead after scan_k<3>):
  float*          h0f  = (float*)zx;                                  // live only rmsnorm->dtproj
  float*          h    = (float*)zx;                                  // 32 MB, live after scan
  __hip_bfloat16* gact = (__hip_bfloat16*)((char*)zx + 33554432);     // 44 MB, disjoint from h

  // weight conversions
  cvt_pad_k<<<(PROJ_PAD * D_MODEL + 255) / 256, 256, 0, stream>>>(wi, wbi);
  cvt_k<<<(D_MODEL * D_INNER + 255) / 256, 256, 0, stream>>>(wo, wbo, D_MODEL * D_INNER);
  cvt_k<<<(FFN_DIM * D_MODEL + 255) / 256, 256, 0, stream>>>(wg, wbg, FFN_DIM * D_MODEL);
  cvt_k<<<(FFN_DIM * D_MODEL + 255) / 256, 256, 0, stream>>>(wu, wbu, FFN_DIM * D_MODEL);
  cvt_k<<<(FFN_DIM * D_MODEL + 255) / 256, 256, 0, stream>>>(wd, wbd, FFN_DIM * D_MODEL);

  // mixer
  rmsnorm_k<<<ROWS, 256, 0, stream>>>(x, n1w, h0b, h0f);
  dtproj_k<<<ROWS / 4, 256, 0, stream>>>(h0f, wi, dtb, dtT);   // before zx is clobbered
  gemm_bt<0><<<(ROWS / 128) * (PROJ_PAD / 128), 256, 0, stream>>>(h0b, wbi, zx, nullptr, nullptr,
                                                                  ROWS, PROJ_PAD, D_MODEL);
  bcdt_k<<<ROWS / 8, 256, 0, stream>>>(zx, cw, cb, bcb);
  // chunked scan: transfer matrices, particular pass, boundary propagation, final pass
  pk_k<<<BATCH * N_HEADS, 256, 0, stream>>>(dtT, A_log, Pm);
  scan_k<1><<<BATCH * N_HEADS * NCH * 2, 128, 0, stream>>>(zx, bcb, dtT, A_log, Dp, cw, cb, pend, nullptr);
  prop_k<<<BATCH * N_HEADS * 64 * 16 / 256, 256, 0, stream>>>(Pm, pend, sini);
  scan_k<3><<<BATCH * N_HEADS * NCH * 2, 128, 0, stream>>>(zx, bcb, dtT, A_log, Dp, cw, cb, sini, po);
  gemm_bt<1><<<(ROWS / 128) * (D_MODEL / 128), 256, 0, stream>>>(po, wbo, h, nullptr, x,
                                                                 ROWS, D_MODEL, D_INNER);
  // FFN
  rmsnorm_k<<<ROWS, 256, 0, stream>>>(h, n2w, h0b, nullptr);
  gemm_bt<2><<<(ROWS / 128) * (FFN_DIM / 128), 256, 0, stream>>>(h0b, wbg, nullptr, gact, nullptr,
                                                                 ROWS, FFN_DIM, D_MODEL);
  gemm_bt<3><<<(ROWS / 128) * (FFN_DIM / 128), 256, 0, stream>>>(h0b, wbu, nullptr, gact, nullptr,
                                                                 ROWS, FFN_DIM, D_MODEL);
  gemm_bt<1><<<(ROWS / 128) * (D_MODEL / 128), 256, 0, stream>>>(gact, wbd, out, nullptr, h,
                                                                 ROWS, D_MODEL, FFN_DIM);
}

// Round 8
// 754.957 us; speedup vs baseline: 2.2297x; 1.0348x over previous
//
#include <hip/hip_runtime.h>
#include <hip/hip_bf16.h>

#define D_MODEL   1024
#define D_STATE   16
#define D_HEAD    64
#define D_CONV    4
#define FFN_DIM   2816
#define D_INNER   2048
#define N_HEADS   32
#define BATCH     4
#define SEQ       2048
#define ROWS      (BATCH*SEQ)     // 8192
#define PROJ_DIM  4160
#define PROJ_PAD  4352            // 17 * 256
#define CONV_CH   2080
#define CH        128             // scan chunk length
#define NCH       (SEQ/CH)        // 16 chunks

typedef __bf16 bf16x8 __attribute__((ext_vector_type(8)));
typedef float  f32x4  __attribute__((ext_vector_type(4)));

__device__ __forceinline__ float siluf(float x) { return x / (1.0f + __expf(-x)); }

#define SBAR() do { asm volatile("" ::: "memory"); __builtin_amdgcn_s_barrier(); asm volatile("" ::: "memory"); } while (0)
#define LGKM0() asm volatile("s_waitcnt lgkmcnt(0)" ::: "memory")
#define VMCNT4() asm volatile("s_waitcnt vmcnt(4)" ::: "memory")
#define VMCNT2() asm volatile("s_waitcnt vmcnt(2)" ::: "memory")
#define VMCNT0() asm volatile("s_waitcnt vmcnt(0)" ::: "memory")

// ---------------------------------------------------------------- converts
__global__ void cvt_k(const float* __restrict__ src, __hip_bfloat16* __restrict__ dst, int n) {
  int i = blockIdx.x * blockDim.x + threadIdx.x;
  if (i < n) dst[i] = __float2bfloat16(src[i]);
}

__global__ void cvt_pad_k(const float* __restrict__ src, __hip_bfloat16* __restrict__ dst) {
  int i = blockIdx.x * blockDim.x + threadIdx.x;
  if (i >= PROJ_PAD * D_MODEL) return;
  int row = i >> 10;
  dst[i] = (row < PROJ_DIM) ? __float2bfloat16(src[i]) : __float2bfloat16(0.0f);
}

// ---------------------------------------------------------------- rmsnorm
__global__ __launch_bounds__(256) void rmsnorm_k(const float* __restrict__ x,
                                                 const float* __restrict__ w,
                                                 __hip_bfloat16* __restrict__ out,
                                                 float* __restrict__ outf) {
  int row = blockIdx.x;
  int t = threadIdx.x;
  const float* xr = x + (size_t)row * D_MODEL;
  float4 v = ((const float4*)xr)[t];
  float ss = v.x*v.x + v.y*v.y + v.z*v.z + v.w*v.w;
  #pragma unroll
  for (int o = 32; o > 0; o >>= 1) ss += __shfl_xor(ss, o);
  __shared__ float red[4];
  if ((t & 63) == 0) red[t >> 6] = ss;
  __syncthreads();
  ss = red[0] + red[1] + red[2] + red[3];
  float scale = rsqrtf(ss * (1.0f / D_MODEL) + 1e-6f);
  float4 wv = ((const float4*)w)[t];
  float4 r;
  r.x = v.x * scale * wv.x; r.y = v.y * scale * wv.y;
  r.z = v.z * scale * wv.z; r.w = v.w * scale * wv.w;
  __hip_bfloat16* orow = out + (size_t)row * D_MODEL + t * 4;
  orow[0] = __float2bfloat16(r.x);
  orow[1] = __float2bfloat16(r.y);
  orow[2] = __float2bfloat16(r.z);
  orow[3] = __float2bfloat16(r.w);
  if (outf) ((float4*)(outf + (size_t)row * D_MODEL))[t] = r;
}

// ---------------------------------------------------------------- dt projection (f32, block-per-4-rows)
__global__ __launch_bounds__(256) void dtproj_k(const float* __restrict__ xn,
                                                const float* __restrict__ wi,
                                                const float* __restrict__ dtb,
                                                float* __restrict__ dtT) {
  const int r0 = blockIdx.x * 4;
  const int t  = threadIdx.x;
  const int hh  = t >> 3;
  const int seg = t & 7;

  __shared__ float xs[4][D_MODEL];
  #pragma unroll
  for (int i = 0; i < 4; ++i)
    ((float4*)&xs[i][0])[t] = ((const float4*)(xn + (size_t)(r0 + i) * D_MODEL))[t];
  __syncthreads();

  const float4* w4 = (const float4*)(wi + (size_t)(2 * D_INNER + 2 * D_STATE + hh) * D_MODEL) + seg * 32;
  const float4* x0 = (const float4*)&xs[0][0] + seg * 32;
  const float4* x1 = (const float4*)&xs[1][0] + seg * 32;
  const float4* x2 = (const float4*)&xs[2][0] + seg * 32;
  const float4* x3 = (const float4*)&xs[3][0] + seg * 32;
  float a0 = 0.f, a1 = 0.f, a2 = 0.f, a3 = 0.f;
  #pragma unroll 8
  for (int k = 0; k < 32; ++k) {
    float4 wv = w4[k];
    float4 v0 = x0[k], v1 = x1[k], v2 = x2[k], v3 = x3[k];
    a0 = fmaf(wv.x, v0.x, fmaf(wv.y, v0.y, fmaf(wv.z, v0.z, fmaf(wv.w, v0.w, a0))));
    a1 = fmaf(wv.x, v1.x, fmaf(wv.y, v1.y, fmaf(wv.z, v1.z, fmaf(wv.w, v1.w, a1))));
    a2 = fmaf(wv.x, v2.x, fmaf(wv.y, v2.y, fmaf(wv.z, v2.z, fmaf(wv.w, v2.w, a2))));
    a3 = fmaf(wv.x, v3.x, fmaf(wv.y, v3.y, fmaf(wv.z, v3.z, fmaf(wv.w, v3.w, a3))));
  }
  #pragma unroll
  for (int m = 1; m < 8; m <<= 1) {
    a0 += __shfl_xor(a0, m);
    a1 += __shfl_xor(a1, m);
    a2 += __shfl_xor(a2, m);
    a3 += __shfl_xor(a3, m);
  }
  if (seg == 0) {
    float bias = dtb[hh];
    float v[4] = {a0, a1, a2, a3};
    #pragma unroll
    for (int i = 0; i < 4; ++i) {
      float xv = v[i] + bias;
      dtT[(size_t)hh * ROWS + r0 + i] = (xv > 20.f) ? xv : log1pf(__expf(xv));
    }
  }
}

// ---------------------------------------------------------------- 256x256 8-phase GEMM  C = A[M,K] * Bw[N,K]^T
// 512 threads = 8 waves (2M x 4N). BK=64. LDS 128KiB dynamic, double-buffered,
// st_16x32 subtiled layout with byte ^= ((byte>>9)&1)<<5 swizzle.
// EPI: 0 f32 store; 1 f32 store + add_src; 2 bf16 silu; 3 bf16 in-place multiply.
template<int EPI>
__global__ __launch_bounds__(512, 2) void gemm8(
    const __hip_bfloat16* __restrict__ A,
    const __hip_bfloat16* __restrict__ Bw,
    float* __restrict__ Cf,
    __hip_bfloat16* __restrict__ Cb,
    const float* __restrict__ add_src,
    int M, int N, int K)
{
  extern __shared__ char lds[];          // 131072 bytes
  const int nwg = (M >> 8) * (N >> 8);   // caller guarantees nwg % 8 == 0
  int bid = blockIdx.x;
  bid = (bid & 7) * (nwg >> 3) + (bid >> 3);   // XCD swizzle (bijective: nwg%8==0)
  const int ntn = N >> 8;
  const int bm = (bid / ntn) << 8;
  const int bn = (bid % ntn) << 8;

  const int tid  = threadIdx.x;
  const int wid  = tid >> 6;
  const int lane = tid & 63;
  const int wm = wid >> 2;          // 0..1
  const int wn = wid & 3;           // 0..3
  const int r16 = lane & 15;
  const int kg  = lane >> 4;

  // swizzled ds_read per-lane base within a 1024B subtile
  const int rb = ((r16 << 6) + (kg << 4)) ^ ((r16 & 8) << 2);

  // staging geometry: thread covers dest bytes [tid*16, tid*16+16) of an 8KB 64-row chunk.
  // Invert the st_16x32 swizzle to get the logical (row, col) this slot must hold.
  const int s_sub = tid >> 6;                  // subtile 0..7
  const int s_w   = (tid & 63) << 4;
  const int s_wp  = s_w ^ ((((s_w) >> 9) & 1) << 5);
  const int s_row = ((s_sub >> 1) << 4) + (s_wp >> 6);        // 0..63 in chunk
  const int s_col = ((s_sub & 1) << 5) + ((s_wp >> 1) & 31);  // 0..63 (bf16 elems)

  auto stage = [&](int buf, int mat, int half, int c, int kt) {
    const __hip_bfloat16* src = (mat == 0)
        ? A  + (size_t)(bm + half * 128 + c * 64 + s_row) * K + kt * 64 + s_col
        : Bw + (size_t)(bn + half * 128 + c * 64 + s_row) * K + kt * 64 + s_col;
    char* dst = lds + buf * 65536 + mat * 32768 + half * 16384 + c * 8192 + tid * 16;
    __builtin_amdgcn_global_load_lds((const __attribute__((address_space(1))) unsigned int*)src,
                                     (__attribute__((address_space(3))) unsigned int*)dst,
                                     16, 0, 0);
  };

  f32x4 acc[8][4] = {};
  bf16x8 af[4][2], bfr[4][2];

  const int NT = K >> 6;
  // prologue: fully stage K-tile 0 into buf 0
  stage(0,0,0,0,0); stage(0,0,0,1,0); stage(0,0,1,0,0); stage(0,0,1,1,0);
  stage(0,1,0,0,0); stage(0,1,0,1,0); stage(0,1,1,0,0); stage(0,1,1,1,0);
  __syncthreads();

  for (int kt = 0; kt < NT; ++kt) {
    const int buf = kt & 1, nbuf = buf ^ 1;
    const bool st = (kt + 1 < NT);
    const char* Ab = lds + buf * 65536 + wm * 16384;
    const char* Bb = lds + buf * 65536 + 32768 + (wn >> 1) * 16384 + (wn & 1) * 8192;

    // ---- phase 1: quadrant (miH=0, ni 0-1)
    #pragma unroll
    for (int mi2 = 0; mi2 < 4; ++mi2)
      #pragma unroll
      for (int kk = 0; kk < 2; ++kk)
        af[mi2][kk] = *(const bf16x8*)(Ab + (mi2 * 2 + kk) * 1024 + rb);
    #pragma unroll
    for (int ni = 0; ni < 2; ++ni)
      #pragma unroll
      for (int kk = 0; kk < 2; ++kk)
        bfr[ni][kk] = *(const bf16x8*)(Bb + (ni * 2 + kk) * 1024 + rb);
    if (st) { stage(nbuf,1,0,0,kt+1); stage(nbuf,1,0,1,kt+1); }
    SBAR(); LGKM0();
    __builtin_amdgcn_s_setprio(1);
    #pragma unroll
    for (int mi2 = 0; mi2 < 4; ++mi2)
      #pragma unroll
      for (int ni = 0; ni < 2; ++ni)
        #pragma unroll
        for (int kk = 0; kk < 2; ++kk)
          acc[mi2][ni] = __builtin_amdgcn_mfma_f32_16x16x32_bf16(af[mi2][kk], bfr[ni][kk], acc[mi2][ni], 0, 0, 0);
    __builtin_amdgcn_s_setprio(0);
    SBAR();

    // ---- phase 2: quadrant (miH=0, ni 2-3)
    #pragma unroll
    for (int ni = 2; ni < 4; ++ni)
      #pragma unroll
      for (int kk = 0; kk < 2; ++kk)
        bfr[ni][kk] = *(const bf16x8*)(Bb + (ni * 2 + kk) * 1024 + rb);
    if (st) { stage(nbuf,1,1,0,kt+1); stage(nbuf,1,1,1,kt+1); }
    SBAR(); LGKM0();
    __builtin_amdgcn_s_setprio(1);
    #pragma unroll
    for (int mi2 = 0; mi2 < 4; ++mi2)
      #pragma unroll
      for (int ni = 2; ni < 4; ++ni)
        #pragma unroll
        for (int kk = 0; kk < 2; ++kk)
          acc[mi2][ni] = __builtin_amdgcn_mfma_f32_16x16x32_bf16(af[mi2][kk], bfr[ni][kk], acc[mi2][ni], 0, 0, 0);
    __builtin_amdgcn_s_setprio(0);
    if (st) { VMCNT4(); } else { VMCNT0(); }   // fence prev-kt A-c1 chunks before phase 3
    SBAR();

    // ---- phase 3: quadrant (miH=1, ni 0-1)
    #pragma unroll
    for (int mi2 = 0; mi2 < 4; ++mi2)
      #pragma unroll
      for (int kk = 0; kk < 2; ++kk)
        af[mi2][kk] = *(const bf16x8*)(Ab + ((4 + mi2) * 2 + kk) * 1024 + rb);
    if (st) { stage(nbuf,0,0,0,kt+1); stage(nbuf,0,1,0,kt+1); }
    SBAR(); LGKM0();
    __builtin_amdgcn_s_setprio(1);
    #pragma unroll
    for (int mi2 = 0; mi2 < 4; ++mi2)
      #pragma unroll
      for (int ni = 0; ni < 2; ++ni)
        #pragma unroll
        for (int kk = 0; kk < 2; ++kk)
          acc[4 + mi2][ni] = __builtin_amdgcn_mfma_f32_16x16x32_bf16(af[mi2][kk], bfr[ni][kk], acc[4 + mi2][ni], 0, 0, 0);
    __builtin_amdgcn_s_setprio(0);
    SBAR();

    // ---- phase 4: quadrant (miH=1, ni 2-3)
    if (st) { stage(nbuf,0,0,1,kt+1); stage(nbuf,0,1,1,kt+1); }
    SBAR(); LGKM0();
    __builtin_amdgcn_s_setprio(1);
    #pragma unroll
    for (int mi2 = 0; mi2 < 4; ++mi2)
      #pragma unroll
      for (int ni = 2; ni < 4; ++ni)
        #pragma unroll
        for (int kk = 0; kk < 2; ++kk)
          acc[4 + mi2][ni] = __builtin_amdgcn_mfma_f32_16x16x32_bf16(af[mi2][kk], bfr[ni][kk], acc[4 + mi2][ni], 0, 0, 0);
    __builtin_amdgcn_s_setprio(0);
    VMCNT2();                                  // keep only newest A-c1 pair in flight
    SBAR();
  }

  // epilogue: C/D layout col = lane&15, row = (lane>>4)*4 + j
  #pragma unroll
  for (int mi = 0; mi < 8; ++mi) {
    #pragma unroll
    for (int ni = 0; ni < 4; ++ni) {
      #pragma unroll
      for (int j = 0; j < 4; ++j) {
        int r = bm + wm * 128 + mi * 16 + kg * 4 + j;
        int c = bn + wn * 64 + ni * 16 + r16;
        size_t idx = (size_t)r * N + c;
        float v = acc[mi][ni][j];
        if constexpr (EPI == 0) {
          Cf[idx] = v;
        } else if constexpr (EPI == 1) {
          Cf[idx] = v + add_src[idx];
        } else if constexpr (EPI == 2) {
          Cb[idx] = __float2bfloat16(siluf(v));
        } else if constexpr (EPI == 3) {
          Cb[idx] = __float2bfloat16(v * __bfloat162float(Cb[idx]));
        }
      }
    }
  }
}

// ---------------------------------------------------------------- conv+silu+normalize for the 32 B/C channels
__global__ __launch_bounds__(256) void bcdt_k(const float* __restrict__ zx,
                                              const float* __restrict__ cw,
                                              const float* __restrict__ cb,
                                              float* __restrict__ bc) {
  int t = threadIdx.x;
  int r = blockIdx.x * 8 + (t >> 5);
  int ch = t & 31;
  int l = r & (SEQ - 1);
  int c = D_INNER + ch;
  float acc = cb[c];
  #pragma unroll
  for (int k = 0; k < 4; ++k) {
    int lp = l - 3 + k;
    if (lp >= 0)
      acc = fmaf(zx[(size_t)(r - 3 + k) * PROJ_PAD + 2 * D_INNER + ch], cw[c * 4 + k], acc);
  }
  acc = siluf(acc);
  float ss = acc * acc;
  ss += __shfl_xor(ss, 1);
  ss += __shfl_xor(ss, 2);
  ss += __shfl_xor(ss, 4);
  ss += __shfl_xor(ss, 8);
  bc[r * 32 + ch] = acc / (sqrtf(ss) + 1e-6f);
}

// ---------------------------------------------------------------- chunk transfer matrices
__global__ __launch_bounds__(256) void pk_k(const float* __restrict__ dtT,
                                            const float* __restrict__ A_log,
                                            float* __restrict__ Pm) {
  int bh = blockIdx.x;
  int h = bh & 31;
  int t = threadIdx.x;
  int ch = t >> 4, n = t & 15;
  float a = __expf(A_log[h * 16 + n]);
  const float* dtp = dtT + (size_t)h * ROWS + (size_t)(bh >> 5) * SEQ + ch * CH;
  float p00 = 1.f, p01 = 0.f, p10 = 0.f, p11 = 1.f;
  for (int l = 0; l < CH; ++l) {
    float dt = dtp[l];
    float s  = 1.0f / fmaf(dt * dt, a, 1.0f);
    float m00 = s;
    float m01 = -dt * a * s;
    float m10 = dt * s;
    float m11 = fmaf(-dt * a, m10, 1.0f);
    float q00 = fmaf(m00, p00, m01 * p10);
    float q01 = fmaf(m00, p01, m01 * p11);
    float q10 = fmaf(m10, p00, m11 * p10);
    float q11 = fmaf(m10, p01, m11 * p11);
    p00 = q00; p01 = q01; p10 = q10; p11 = q11;
  }
  float4 v = {p00, p01, p10, p11};
  *(float4*)&Pm[(((size_t)bh * NCH + ch) * 16 + n) * 4] = v;
}

// ---------------------------------------------------------------- propagate chunk-boundary states
__global__ __launch_bounds__(256) void prop_k(const float* __restrict__ Pm,
                                              const float* __restrict__ pend,
                                              float* __restrict__ sinit) {
  int gid = blockIdx.x * 256 + threadIdx.x;
  int n  = gid & 15;
  int d  = (gid >> 4) & 63;
  int bh = gid >> 10;
  float s0 = 0.f, s1 = 0.f;
  for (int c = 0; c < NCH; ++c) {
    size_t i2 = (((size_t)bh * NCH + c) * 64 + d) * 16 + n;
    *(float2*)&sinit[i2 * 2] = make_float2(s0, s1);
    float4 P  = *(const float4*)&Pm[(((size_t)bh * NCH + c) * 16 + n) * 4];
    float2 pe = *(const float2*)&pend[i2 * 2];
    float t0 = fmaf(P.x, s0, fmaf(P.y, s1, pe.x));
    float t1 = fmaf(P.z, s0, fmaf(P.w, s1, pe.y));
    s0 = t0; s1 = t1;
  }
}

// ---------------------------------------------------------------- chunked scan
#define T_TILE 16
#define TPC (CH / T_TILE)
template<int PHASE>
__global__ __launch_bounds__(128) void scan_k(
    const float* __restrict__ zx, const float* __restrict__ bcb,
    const float* __restrict__ dtT, const float* __restrict__ A_log,
    const float* __restrict__ Dp, const float* __restrict__ cw,
    const float* __restrict__ cb, float* __restrict__ states,
    __hip_bfloat16* __restrict__ po)
{
  const int blk  = blockIdx.x;
  const int half = blk & 1;
  const int ch   = (blk >> 1) & 15;
  const int h    = (blk >> 5) & 31;
  const int b    = blk >> 10;
  const int bh   = b * 32 + h;
  const int tid  = threadIdx.x;
  const int wv   = tid >> 6;
  const int lane = tid & 63;
  const int d16  = lane & 15;
  const int ng   = lane >> 4;
  const int n0   = ng * 4;
  const int dl   = half * 32 + wv * 16 + d16;
  const int dcol = h * 64 + dl;
  const size_t rowbase = (size_t)b * SEQ + (size_t)ch * CH;

  __shared__ float xz [2][T_TILE][64];
  __shared__ float bct[2][T_TILE][32];
  __shared__ float st [2][T_TILE][16];
  __shared__ float dtt[2][T_TILE];
  __shared__ float aexp[16];
  __shared__ float opart[T_TILE][32][4];

  if (tid < 16) aexp[tid] = __expf(A_log[h * 16 + tid]);

  float A4[4];
  #pragma unroll
  for (int j = 0; j < 4; ++j) A4[j] = __expf(A_log[h * 16 + n0 + j]);
  const float Dh = Dp[h];
  const float c0 = cw[dcol * 4 + 0], c1 = cw[dcol * 4 + 1];
  const float c2 = cw[dcol * 4 + 2], c3 = cw[dcol * 4 + 3];
  const float cbv = cb[dcol];

  auto stage = [&](int tile, int buf) {
    const size_t r0 = rowbase + (size_t)tile * T_TILE;
    #pragma unroll
    for (int i = 0; i < 2; ++i) {
      int lr = 8 * i + 4 * wv + (lane >> 4);
      int c4 = (lane & 15) * 4;
      int col = (c4 < 32) ? (h * 64 + half * 32 + c4)
                          : (D_INNER + h * 64 + half * 32 + (c4 - 32));
      const float* g = zx + (r0 + lr) * PROJ_PAD + col;
      float* l = &xz[buf][0][0] + (8 * i + 4 * wv) * 64 + (lane & 15) * 4;
      __builtin_amdgcn_global_load_lds((const __attribute__((address_space(1))) unsigned int*)g,
                                       (__attribute__((address_space(3))) unsigned int*)l,
                                       16, 0, 0);
    }
    {
      int lr = 8 * wv + (lane >> 3);
      const float* g = bcb + (r0 + lr) * 32 + (lane & 7) * 4;
      float* l = &bct[buf][0][0] + 8 * wv * 32 + (lane & 7) * 4;
      __builtin_amdgcn_global_load_lds((const __attribute__((address_space(1))) unsigned int*)g,
                                       (__attribute__((address_space(3))) unsigned int*)l,
                                       16, 0, 0);
    }
  };

  auto sprep = [&](int buf, float dtn) {
    #pragma unroll
    for (int i = 0; i < 2; ++i) {
      int idx = tid + 128 * i;
      int row = idx >> 4, n = idx & 15;
      float dv = __shfl(dtn, row);
      float a  = aexp[n];
      st[buf][row][n] = 1.0f / fmaf(dv * dv, a, 1.0f);
    }
  };

  stage(0, 0);
  float dtn = 0.f;
  if (lane < 16) dtn = dtT[(size_t)h * ROWS + rowbase + lane];
  __syncthreads();
  if (tid < 16) dtt[0][tid] = dtn;
  sprep(0, dtn);
  __syncthreads();

  float w[4], ys[4];
  if constexpr (PHASE == 1) {
    #pragma unroll
    for (int j = 0; j < 4; ++j) { w[j] = 0.f; ys[j] = 0.f; }
  } else {
    #pragma unroll
    for (int j = 0; j < 4; ++j) {
      size_t i2 = (((size_t)bh * NCH + ch) * 64 + dl) * 16 + (n0 + j);
      float2 s = *(const float2*)&states[i2 * 2];
      w[j] = s.x; ys[j] = s.y;
    }
  }
  float xw1 = 0.f, xw2 = 0.f, xw3 = 0.f;
  if (ch > 0) {
    const float* xb = zx + rowbase * PROJ_PAD + D_INNER + dcol;
    xw1 = xb[-3 * PROJ_PAD];
    xw2 = xb[-2 * PROJ_PAD];
    xw3 = xb[-1 * PROJ_PAD];
  }
  int cur = 0;

  for (int t = 0; t < TPC; ++t) {
    if (t + 1 < TPC) {
      stage(t + 1, cur ^ 1);
      if (lane < 16) dtn = dtT[(size_t)h * ROWS + rowbase + (size_t)(t + 1) * T_TILE + lane];
    }
    #pragma unroll 4
    for (int l = 0; l < T_TILE; ++l) {
      float xl  = xz[cur][l][32 + wv * 16 + d16];
      float dtv = dtt[cur][l];
      f32x4 Sv = *(const f32x4*)&st [cur][l][n0];
      f32x4 Bv = *(const f32x4*)&bct[cur][l][n0];
      float cacc = fmaf(c3, xl, fmaf(c2, xw3, fmaf(c1, xw2, fmaf(c0, xw1, cbv))));
      float uv = siluf(cacc);
      xw1 = xw2; xw2 = xw3; xw3 = xl;
      float du = dtv * uv;
      if constexpr (PHASE == 3) {
        f32x4 Cv = *(const f32x4*)&bct[cur][l][16 + n0];
        float o = 0.f;
        #pragma unroll
        for (int j = 0; j < 4; ++j) {
          float tmp = fmaf(-(dtv * A4[j]), ys[j], w[j]);
          tmp = fmaf(du, Bv[j], tmp);
          w[j] = Sv[j] * tmp;
          ys[j] = fmaf(dtv, w[j], ys[j]);
          o = fmaf(ys[j], Cv[j], o);
        }
        float ofin = (ng == 0) ? fmaf(Dh, uv, o) : o;
        opart[l][wv * 16 + d16][ng] = ofin;
      } else {
        #pragma unroll
        for (int j = 0; j < 4; ++j) {
          float tmp = fmaf(-(dtv * A4[j]), ys[j], w[j]);
          tmp = fmaf(du, Bv[j], tmp);
          w[j] = Sv[j] * tmp;
          ys[j] = fmaf(dtv, w[j], ys[j]);
        }
      }
    }
    if constexpr (PHASE == 3) {
      #pragma unroll
      for (int i = 0; i < 4; ++i) {
        int l  = (lane >> 4) + 4 * i;
        int dd = wv * 16 + d16;
        f32x4 op = *(const f32x4*)&opart[l][dd][0];
        float zv = xz[cur][l][dd];
        float yv = (op[0] + op[1]) + (op[2] + op[3]);
        po[(rowbase + (size_t)t * T_TILE + l) * D_INNER + (h * 64 + half * 32 + dd)] =
            __float2bfloat16(yv * siluf(zv));
      }
    }
    __syncthreads();
    if (t + 1 < TPC) {
      if (tid < 16) dtt[cur ^ 1][tid] = dtn;
      sprep(cur ^ 1, dtn);
      __syncthreads();
    }
    cur ^= 1;
  }

  if constexpr (PHASE == 1) {
    #pragma unroll
    for (int j = 0; j < 4; ++j) {
      size_t i2 = (((size_t)bh * NCH + ch) * 64 + dl) * 16 + (n0 + j);
      *(float2*)&states[i2 * 2] = make_float2(w[j], ys[j]);
    }
  }
}

// ---------------------------------------------------------------- launch
extern "C" void kernel_launch(void* const* d_in, const int* in_sizes, int n_in,
                              void* d_out, int out_size, void* d_ws, size_t ws_size,
                              hipStream_t stream) {
  const float* x     = (const float*)d_in[0];
  const float* n1w   = (const float*)d_in[1];
  const float* wi    = (const float*)d_in[2];
  const float* cw    = (const float*)d_in[3];
  const float* cb    = (const float*)d_in[4];
  const float* A_log = (const float*)d_in[5];
  const float* dtb   = (const float*)d_in[6];
  const float* Dp    = (const float*)d_in[7];
  const float* wo    = (const float*)d_in[8];
  const float* n2w   = (const float*)d_in[9];
  const float* wg    = (const float*)d_in[10];
  const float* wu    = (const float*)d_in[11];
  const float* wd    = (const float*)d_in[12];
  float* out = (float*)d_out;

  char* p = (char*)d_ws;
  auto take = [&](size_t b) { char* q = p; p += (b + 255) & ~(size_t)255; return q; };
  __hip_bfloat16* wbi  = (__hip_bfloat16*)take((size_t)PROJ_PAD * D_MODEL * 2);   //  8.9 MB
  __hip_bfloat16* wbo  = (__hip_bfloat16*)take((size_t)D_MODEL * D_INNER * 2);
  __hip_bfloat16* wbg  = (__hip_bfloat16*)take((size_t)FFN_DIM * D_MODEL * 2);
  __hip_bfloat16* wbu  = (__hip_bfloat16*)take((size_t)FFN_DIM * D_MODEL * 2);
  __hip_bfloat16* wbd  = (__hip_bfloat16*)take((size_t)D_MODEL * FFN_DIM * 2);
  __hip_bfloat16* h0b  = (__hip_bfloat16*)take((size_t)ROWS * D_MODEL * 2);       // 16 MB
  float*          zx   = (float*)take((size_t)ROWS * PROJ_PAD * 4);               // 142.6 MB
  float*          bcb  = (float*)take((size_t)ROWS * 32 * 4);
  float*          dtT  = (float*)take((size_t)ROWS * 32 * 4);
  __hip_bfloat16* po   = (__hip_bfloat16*)take((size_t)ROWS * D_INNER * 2);       // 32 MB
  float*          pend = (float*)take((size_t)128 * NCH * 64 * 16 * 2 * 4);       // 16.8 MB
  float*          sini = (float*)take((size_t)128 * NCH * 64 * 16 * 2 * 4);       // 16.8 MB
  float*          Pm   = (float*)take((size_t)128 * NCH * 16 * 4 * 4);
  float*          h0f  = (float*)zx;
  float*          h    = (float*)zx;
  __hip_bfloat16* gact = (__hip_bfloat16*)((char*)zx + 33554432);

  // raise dynamic-LDS cap for the 8-phase GEMMs (host-side, idempotent, capture-safe)
  hipFuncSetAttribute(reinterpret_cast<const void*>(&gemm8<0>), hipFuncAttributeMaxDynamicSharedMemorySize, 131072);
  hipFuncSetAttribute(reinterpret_cast<const void*>(&gemm8<1>), hipFuncAttributeMaxDynamicSharedMemorySize, 131072);
  hipFuncSetAttribute(reinterpret_cast<const void*>(&gemm8<2>), hipFuncAttributeMaxDynamicSharedMemorySize, 131072);
  hipFuncSetAttribute(reinterpret_cast<const void*>(&gemm8<3>), hipFuncAttributeMaxDynamicSharedMemorySize, 131072);

  // weight conversions
  cvt_pad_k<<<(PROJ_PAD * D_MODEL + 255) / 256, 256, 0, stream>>>(wi, wbi);
  cvt_k<<<(D_MODEL * D_INNER + 255) / 256, 256, 0, stream>>>(wo, wbo, D_MODEL * D_INNER);
  cvt_k<<<(FFN_DIM * D_MODEL + 255) / 256, 256, 0, stream>>>(wg, wbg, FFN_DIM * D_MODEL);
  cvt_k<<<(FFN_DIM * D_MODEL + 255) / 256, 256, 0, stream>>>(wu, wbu, FFN_DIM * D_MODEL);
  cvt_k<<<(FFN_DIM * D_MODEL + 255) / 256, 256, 0, stream>>>(wd, wbd, FFN_DIM * D_MODEL);

  // mixer
  rmsnorm_k<<<ROWS, 256, 0, stream>>>(x, n1w, h0b, h0f);
  dtproj_k<<<ROWS / 4, 256, 0, stream>>>(h0f, wi, dtb, dtT);
  gemm8<0><<<(ROWS / 256) * (PROJ_PAD / 256), 512, 131072, stream>>>(h0b, wbi, zx, nullptr, nullptr,
                                                                     ROWS, PROJ_PAD, D_MODEL);
  bcdt_k<<<ROWS / 8, 256, 0, stream>>>(zx, cw, cb, bcb);
  pk_k<<<BATCH * N_HEADS, 256, 0, stream>>>(dtT, A_log, Pm);
  scan_k<1><<<BATCH * N_HEADS * NCH * 2, 128, 0, stream>>>(zx, bcb, dtT, A_log, Dp, cw, cb, pend, nullptr);
  prop_k<<<BATCH * N_HEADS * 64 * 16 / 256, 256, 0, stream>>>(Pm, pend, sini);
  scan_k<3><<<BATCH * N_HEADS * NCH * 2, 128, 0, stream>>>(zx, bcb, dtT, A_log, Dp, cw, cb, sini, po);
  gemm8<1><<<(ROWS / 256) * (D_MODEL / 256), 512, 131072, stream>>>(po, wbo, h, nullptr, x,
                                                                    ROWS, D_MODEL, D_INNER);
  // FFN
  rmsnorm_k<<<ROWS, 256, 0, stream>>>(h, n2w, h0b, nullptr);
  gemm8<2><<<(ROWS / 256) * (FFN_DIM / 256), 512, 131072, stream>>>(h0b, wbg, nullptr, gact, nullptr,
                                                                    ROWS, FFN_DIM, D_MODEL);
  gemm8<3><<<(ROWS / 256) * (FFN_DIM / 256), 512, 131072, stream>>>(h0b, wbu, nullptr, gact, nullptr,
                                                                    ROWS, FFN_DIM, D_MODEL);
  gemm8<1><<<(ROWS / 256) * (D_MODEL / 256), 512, 131072, stream>>>(gact, wbd, out, nullptr, h,
                                                                    ROWS, D_MODEL, FFN_DIM);
}

// Round 9
// 711.538 us; speedup vs baseline: 2.3658x; 1.0610x over previous
//
#include <hip/hip_runtime.h>
#include <hip/hip_bf16.h>

#define D_MODEL   1024
#define D_STATE   16
#define D_HEAD    64
#define D_CONV    4
#define FFN_DIM   2816
#define D_INNER   2048
#define N_HEADS   32
#define BATCH     4
#define SEQ       2048
#define ROWS      (BATCH*SEQ)     // 8192
#define PROJ_DIM  4160
#define PROJ_PAD  4352            // 17 * 256
#define CONV_CH   2080
#define CH        128             // scan chunk length
#define NCH       (SEQ/CH)        // 16 chunks

typedef __bf16 bf16x8 __attribute__((ext_vector_type(8)));
typedef float  f32x4  __attribute__((ext_vector_type(4)));

__device__ __forceinline__ float siluf(float x) { return x / (1.0f + __expf(-x)); }

#define SBAR() do { asm volatile("" ::: "memory"); __builtin_amdgcn_s_barrier(); asm volatile("" ::: "memory"); } while (0)
#define LGKM0() asm volatile("s_waitcnt lgkmcnt(0)" ::: "memory")
#define VMCNT4() asm volatile("s_waitcnt vmcnt(4)" ::: "memory")
#define VMCNT2() asm volatile("s_waitcnt vmcnt(2)" ::: "memory")
#define VMCNT0() asm volatile("s_waitcnt vmcnt(0)" ::: "memory")

// ---------------------------------------------------------------- converts
__global__ void cvt_k(const float* __restrict__ src, __hip_bfloat16* __restrict__ dst, int n) {
  int i = blockIdx.x * blockDim.x + threadIdx.x;
  if (i < n) dst[i] = __float2bfloat16(src[i]);
}

__global__ void cvt_pad_k(const float* __restrict__ src, __hip_bfloat16* __restrict__ dst) {
  int i = blockIdx.x * blockDim.x + threadIdx.x;
  if (i >= PROJ_PAD * D_MODEL) return;
  int row = i >> 10;
  dst[i] = (row < PROJ_DIM) ? __float2bfloat16(src[i]) : __float2bfloat16(0.0f);
}

// ---------------------------------------------------------------- rmsnorm
__global__ __launch_bounds__(256) void rmsnorm_k(const float* __restrict__ x,
                                                 const float* __restrict__ w,
                                                 __hip_bfloat16* __restrict__ out,
                                                 float* __restrict__ outf) {
  int row = blockIdx.x;
  int t = threadIdx.x;
  const float* xr = x + (size_t)row * D_MODEL;
  float4 v = ((const float4*)xr)[t];
  float ss = v.x*v.x + v.y*v.y + v.z*v.z + v.w*v.w;
  #pragma unroll
  for (int o = 32; o > 0; o >>= 1) ss += __shfl_xor(ss, o);
  __shared__ float red[4];
  if ((t & 63) == 0) red[t >> 6] = ss;
  __syncthreads();
  ss = red[0] + red[1] + red[2] + red[3];
  float scale = rsqrtf(ss * (1.0f / D_MODEL) + 1e-6f);
  float4 wv = ((const float4*)w)[t];
  float4 r;
  r.x = v.x * scale * wv.x; r.y = v.y * scale * wv.y;
  r.z = v.z * scale * wv.z; r.w = v.w * scale * wv.w;
  __hip_bfloat16* orow = out + (size_t)row * D_MODEL + t * 4;
  orow[0] = __float2bfloat16(r.x);
  orow[1] = __float2bfloat16(r.y);
  orow[2] = __float2bfloat16(r.z);
  orow[3] = __float2bfloat16(r.w);
  if (outf) ((float4*)(outf + (size_t)row * D_MODEL))[t] = r;
}

// ---------------------------------------------------------------- dt projection (f32, block-per-4-rows)
__global__ __launch_bounds__(256) void dtproj_k(const float* __restrict__ xn,
                                                const float* __restrict__ wi,
                                                const float* __restrict__ dtb,
                                                float* __restrict__ dtT) {
  const int r0 = blockIdx.x * 4;
  const int t  = threadIdx.x;
  const int hh  = t >> 3;
  const int seg = t & 7;

  __shared__ float xs[4][D_MODEL];
  #pragma unroll
  for (int i = 0; i < 4; ++i)
    ((float4*)&xs[i][0])[t] = ((const float4*)(xn + (size_t)(r0 + i) * D_MODEL))[t];
  __syncthreads();

  const float4* w4 = (const float4*)(wi + (size_t)(2 * D_INNER + 2 * D_STATE + hh) * D_MODEL) + seg * 32;
  const float4* x0 = (const float4*)&xs[0][0] + seg * 32;
  const float4* x1 = (const float4*)&xs[1][0] + seg * 32;
  const float4* x2 = (const float4*)&xs[2][0] + seg * 32;
  const float4* x3 = (const float4*)&xs[3][0] + seg * 32;
  float a0 = 0.f, a1 = 0.f, a2 = 0.f, a3 = 0.f;
  #pragma unroll 8
  for (int k = 0; k < 32; ++k) {
    float4 wv = w4[k];
    float4 v0 = x0[k], v1 = x1[k], v2 = x2[k], v3 = x3[k];
    a0 = fmaf(wv.x, v0.x, fmaf(wv.y, v0.y, fmaf(wv.z, v0.z, fmaf(wv.w, v0.w, a0))));
    a1 = fmaf(wv.x, v1.x, fmaf(wv.y, v1.y, fmaf(wv.z, v1.z, fmaf(wv.w, v1.w, a1))));
    a2 = fmaf(wv.x, v2.x, fmaf(wv.y, v2.y, fmaf(wv.z, v2.z, fmaf(wv.w, v2.w, a2))));
    a3 = fmaf(wv.x, v3.x, fmaf(wv.y, v3.y, fmaf(wv.z, v3.z, fmaf(wv.w, v3.w, a3))));
  }
  #pragma unroll
  for (int m = 1; m < 8; m <<= 1) {
    a0 += __shfl_xor(a0, m);
    a1 += __shfl_xor(a1, m);
    a2 += __shfl_xor(a2, m);
    a3 += __shfl_xor(a3, m);
  }
  if (seg == 0) {
    float bias = dtb[hh];
    float v[4] = {a0, a1, a2, a3};
    #pragma unroll
    for (int i = 0; i < 4; ++i) {
      float xv = v[i] + bias;
      dtT[(size_t)hh * ROWS + r0 + i] = (xv > 20.f) ? xv : log1pf(__expf(xv));
    }
  }
}

// ---------------------------------------------------------------- 256x256 8-phase GEMM
template<int EPI>
__global__ __launch_bounds__(512, 2) void gemm8(
    const __hip_bfloat16* __restrict__ A,
    const __hip_bfloat16* __restrict__ Bw,
    float* __restrict__ Cf,
    __hip_bfloat16* __restrict__ Cb,
    const float* __restrict__ add_src,
    int M, int N, int K)
{
  extern __shared__ char lds[];
  const int nwg = (M >> 8) * (N >> 8);
  int bid = blockIdx.x;
  bid = (bid & 7) * (nwg >> 3) + (bid >> 3);
  const int ntn = N >> 8;
  const int bm = (bid / ntn) << 8;
  const int bn = (bid % ntn) << 8;

  const int tid  = threadIdx.x;
  const int wid  = tid >> 6;
  const int lane = tid & 63;
  const int wm = wid >> 2;
  const int wn = wid & 3;
  const int r16 = lane & 15;
  const int kg  = lane >> 4;

  const int rb = ((r16 << 6) + (kg << 4)) ^ ((r16 & 8) << 2);

  const int s_sub = tid >> 6;
  const int s_w   = (tid & 63) << 4;
  const int s_wp  = s_w ^ ((((s_w) >> 9) & 1) << 5);
  const int s_row = ((s_sub >> 1) << 4) + (s_wp >> 6);
  const int s_col = ((s_sub & 1) << 5) + ((s_wp >> 1) & 31);

  auto stage = [&](int buf, int mat, int half, int c, int kt) {
    const __hip_bfloat16* src = (mat == 0)
        ? A  + (size_t)(bm + half * 128 + c * 64 + s_row) * K + kt * 64 + s_col
        : Bw + (size_t)(bn + half * 128 + c * 64 + s_row) * K + kt * 64 + s_col;
    char* dst = lds + buf * 65536 + mat * 32768 + half * 16384 + c * 8192 + tid * 16;
    __builtin_amdgcn_global_load_lds((const __attribute__((address_space(1))) unsigned int*)src,
                                     (__attribute__((address_space(3))) unsigned int*)dst,
                                     16, 0, 0);
  };

  f32x4 acc[8][4] = {};
  bf16x8 af[4][2], bfr[4][2];

  const int NT = K >> 6;
  stage(0,0,0,0,0); stage(0,0,0,1,0); stage(0,0,1,0,0); stage(0,0,1,1,0);
  stage(0,1,0,0,0); stage(0,1,0,1,0); stage(0,1,1,0,0); stage(0,1,1,1,0);
  __syncthreads();

  for (int kt = 0; kt < NT; ++kt) {
    const int buf = kt & 1, nbuf = buf ^ 1;
    const bool st = (kt + 1 < NT);
    const char* Ab = lds + buf * 65536 + wm * 16384;
    const char* Bb = lds + buf * 65536 + 32768 + (wn >> 1) * 16384 + (wn & 1) * 8192;

    #pragma unroll
    for (int mi2 = 0; mi2 < 4; ++mi2)
      #pragma unroll
      for (int kk = 0; kk < 2; ++kk)
        af[mi2][kk] = *(const bf16x8*)(Ab + (mi2 * 2 + kk) * 1024 + rb);
    #pragma unroll
    for (int ni = 0; ni < 2; ++ni)
      #pragma unroll
      for (int kk = 0; kk < 2; ++kk)
        bfr[ni][kk] = *(const bf16x8*)(Bb + (ni * 2 + kk) * 1024 + rb);
    if (st) { stage(nbuf,1,0,0,kt+1); stage(nbuf,1,0,1,kt+1); }
    SBAR(); LGKM0();
    __builtin_amdgcn_s_setprio(1);
    #pragma unroll
    for (int mi2 = 0; mi2 < 4; ++mi2)
      #pragma unroll
      for (int ni = 0; ni < 2; ++ni)
        #pragma unroll
        for (int kk = 0; kk < 2; ++kk)
          acc[mi2][ni] = __builtin_amdgcn_mfma_f32_16x16x32_bf16(af[mi2][kk], bfr[ni][kk], acc[mi2][ni], 0, 0, 0);
    __builtin_amdgcn_s_setprio(0);
    SBAR();

    #pragma unroll
    for (int ni = 2; ni < 4; ++ni)
      #pragma unroll
      for (int kk = 0; kk < 2; ++kk)
        bfr[ni][kk] = *(const bf16x8*)(Bb + (ni * 2 + kk) * 1024 + rb);
    if (st) { stage(nbuf,1,1,0,kt+1); stage(nbuf,1,1,1,kt+1); }
    SBAR(); LGKM0();
    __builtin_amdgcn_s_setprio(1);
    #pragma unroll
    for (int mi2 = 0; mi2 < 4; ++mi2)
      #pragma unroll
      for (int ni = 2; ni < 4; ++ni)
        #pragma unroll
        for (int kk = 0; kk < 2; ++kk)
          acc[mi2][ni] = __builtin_amdgcn_mfma_f32_16x16x32_bf16(af[mi2][kk], bfr[ni][kk], acc[mi2][ni], 0, 0, 0);
    __builtin_amdgcn_s_setprio(0);
    if (st) { VMCNT4(); } else { VMCNT0(); }
    SBAR();

    #pragma unroll
    for (int mi2 = 0; mi2 < 4; ++mi2)
      #pragma unroll
      for (int kk = 0; kk < 2; ++kk)
        af[mi2][kk] = *(const bf16x8*)(Ab + ((4 + mi2) * 2 + kk) * 1024 + rb);
    if (st) { stage(nbuf,0,0,0,kt+1); stage(nbuf,0,1,0,kt+1); }
    SBAR(); LGKM0();
    __builtin_amdgcn_s_setprio(1);
    #pragma unroll
    for (int mi2 = 0; mi2 < 4; ++mi2)
      #pragma unroll
      for (int ni = 0; ni < 2; ++ni)
        #pragma unroll
        for (int kk = 0; kk < 2; ++kk)
          acc[4 + mi2][ni] = __builtin_amdgcn_mfma_f32_16x16x32_bf16(af[mi2][kk], bfr[ni][kk], acc[4 + mi2][ni], 0, 0, 0);
    __builtin_amdgcn_s_setprio(0);
    SBAR();

    if (st) { stage(nbuf,0,0,1,kt+1); stage(nbuf,0,1,1,kt+1); }
    SBAR(); LGKM0();
    __builtin_amdgcn_s_setprio(1);
    #pragma unroll
    for (int mi2 = 0; mi2 < 4; ++mi2)
      #pragma unroll
      for (int ni = 2; ni < 4; ++ni)
        #pragma unroll
        for (int kk = 0; kk < 2; ++kk)
          acc[4 + mi2][ni] = __builtin_amdgcn_mfma_f32_16x16x32_bf16(af[mi2][kk], bfr[ni][kk], acc[4 + mi2][ni], 0, 0, 0);
    __builtin_amdgcn_s_setprio(0);
    VMCNT2();
    SBAR();
  }

  #pragma unroll
  for (int mi = 0; mi < 8; ++mi) {
    #pragma unroll
    for (int ni = 0; ni < 4; ++ni) {
      #pragma unroll
      for (int j = 0; j < 4; ++j) {
        int r = bm + wm * 128 + mi * 16 + kg * 4 + j;
        int c = bn + wn * 64 + ni * 16 + r16;
        size_t idx = (size_t)r * N + c;
        float v = acc[mi][ni][j];
        if constexpr (EPI == 0) {
          Cf[idx] = v;
        } else if constexpr (EPI == 1) {
          Cf[idx] = v + add_src[idx];
        } else if constexpr (EPI == 2) {
          Cb[idx] = __float2bfloat16(siluf(v));
        } else if constexpr (EPI == 3) {
          Cb[idx] = __float2bfloat16(v * __bfloat162float(Cb[idx]));
        }
      }
    }
  }
}

// ---------------------------------------------------------------- 256x128 8-phase GEMM (full grid at N=1024)
// 8 waves (2M x 4N), per-wave 128x32 output. A: 32KB/buf (4 chunks), B: 16KB/buf (2 chunks).
template<int EPI>
__global__ __launch_bounds__(512, 2) void gemm8B(
    const __hip_bfloat16* __restrict__ A,
    const __hip_bfloat16* __restrict__ Bw,
    float* __restrict__ Cf,
    __hip_bfloat16* __restrict__ Cb,
    const float* __restrict__ add_src,
    int M, int N, int K)
{
  extern __shared__ char lds[];
  const int nwg = (M >> 8) * (N >> 7);
  int bid = blockIdx.x;
  bid = (bid & 7) * (nwg >> 3) + (bid >> 3);
  const int ntn = N >> 7;
  const int bm = (bid / ntn) << 8;
  const int bn = (bid % ntn) << 7;

  const int tid  = threadIdx.x;
  const int wid  = tid >> 6;
  const int lane = tid & 63;
  const int wm = wid >> 2;          // 0..1 -> 128 rows
  const int wn = wid & 3;           // 0..3 -> 32 cols
  const int r16 = lane & 15;
  const int kg  = lane >> 4;

  const int rb = ((r16 << 6) + (kg << 4)) ^ ((r16 & 8) << 2);

  const int s_sub = tid >> 6;
  const int s_w   = (tid & 63) << 4;
  const int s_wp  = s_w ^ ((((s_w) >> 9) & 1) << 5);
  const int s_row = ((s_sub >> 1) << 4) + (s_wp >> 6);
  const int s_col = ((s_sub & 1) << 5) + ((s_wp >> 1) & 31);

  auto stageA = [&](int buf, int half, int c, int kt) {
    const __hip_bfloat16* src = A + (size_t)(bm + half * 128 + c * 64 + s_row) * K + kt * 64 + s_col;
    char* dst = lds + buf * 65536 + half * 16384 + c * 8192 + tid * 16;
    __builtin_amdgcn_global_load_lds((const __attribute__((address_space(1))) unsigned int*)src,
                                     (__attribute__((address_space(3))) unsigned int*)dst,
                                     16, 0, 0);
  };
  auto stageB = [&](int buf, int c, int kt) {
    const __hip_bfloat16* src = Bw + (size_t)(bn + c * 64 + s_row) * K + kt * 64 + s_col;
    char* dst = lds + buf * 65536 + 32768 + c * 8192 + tid * 16;
    __builtin_amdgcn_global_load_lds((const __attribute__((address_space(1))) unsigned int*)src,
                                     (__attribute__((address_space(3))) unsigned int*)dst,
                                     16, 0, 0);
  };

  f32x4 acc[8][2] = {};
  bf16x8 af[4][2], bfr[2][2];

  const int NT = K >> 6;
  // prologue: 6 chunks of K-tile 0 (order: B0,B1,A00,A10,A01,A11)
  stageB(0,0,0); stageB(0,1,0);
  stageA(0,0,0,0); stageA(0,1,0,0); stageA(0,0,1,0); stageA(0,1,1,0);
  __syncthreads();

  for (int kt = 0; kt < NT; ++kt) {
    const int buf = kt & 1, nbuf = buf ^ 1;
    const bool st = (kt + 1 < NT);
    const char* Ab = lds + buf * 65536 + wm * 16384;
    // wave wn covers B rows wn*32..+31: chunk wn>>1, subtile pair (wn&1)*2
    const char* Bb = lds + buf * 65536 + 32768 + (wn >> 1) * 8192 + (wn & 1) * 4096;

    // ---- phase 1: A chunk c0 (rows wm*128..+63) x all 32 cols
    #pragma unroll
    for (int mi2 = 0; mi2 < 4; ++mi2)
      #pragma unroll
      for (int kk = 0; kk < 2; ++kk)
        af[mi2][kk] = *(const bf16x8*)(Ab + (mi2 * 2 + kk) * 1024 + rb);
    #pragma unroll
    for (int ni = 0; ni < 2; ++ni)
      #pragma unroll
      for (int kk = 0; kk < 2; ++kk)
        bfr[ni][kk] = *(const bf16x8*)(Bb + (ni * 2 + kk) * 1024 + rb);
    if (st) { stageB(nbuf,0,kt+1); stageB(nbuf,1,kt+1); stageA(nbuf,0,0,kt+1); stageA(nbuf,1,0,kt+1); }
    SBAR(); LGKM0();
    __builtin_amdgcn_s_setprio(1);
    #pragma unroll
    for (int mi2 = 0; mi2 < 4; ++mi2)
      #pragma unroll
      for (int ni = 0; ni < 2; ++ni)
        #pragma unroll
        for (int kk = 0; kk < 2; ++kk)
          acc[mi2][ni] = __builtin_amdgcn_mfma_f32_16x16x32_bf16(af[mi2][kk], bfr[ni][kk], acc[mi2][ni], 0, 0, 0);
    __builtin_amdgcn_s_setprio(0);
    if (st) { VMCNT4(); } else { VMCNT0(); }   // retire prev-kt A-c1 pair before phase 2 reads
    SBAR();

    // ---- phase 2: A chunk c1 (rows wm*128+64..+127)
    #pragma unroll
    for (int mi2 = 0; mi2 < 4; ++mi2)
      #pragma unroll
      for (int kk = 0; kk < 2; ++kk)
        af[mi2][kk] = *(const bf16x8*)(Ab + ((4 + mi2) * 2 + kk) * 1024 + rb);
    if (st) { stageA(nbuf,0,1,kt+1); stageA(nbuf,1,1,kt+1); }
    SBAR(); LGKM0();
    __builtin_amdgcn_s_setprio(1);
    #pragma unroll
    for (int mi2 = 0; mi2 < 4; ++mi2)
      #pragma unroll
      for (int ni = 0; ni < 2; ++ni)
        #pragma unroll
        for (int kk = 0; kk < 2; ++kk)
          acc[4 + mi2][ni] = __builtin_amdgcn_mfma_f32_16x16x32_bf16(af[mi2][kk], bfr[ni][kk], acc[4 + mi2][ni], 0, 0, 0);
    __builtin_amdgcn_s_setprio(0);
    VMCNT2();                                  // retire this kt's 4 p1-stages; keep A-c1 pair in flight
    SBAR();
  }

  #pragma unroll
  for (int mi = 0; mi < 8; ++mi) {
    #pragma unroll
    for (int ni = 0; ni < 2; ++ni) {
      #pragma unroll
      for (int j = 0; j < 4; ++j) {
        int r = bm + wm * 128 + mi * 16 + kg * 4 + j;
        int c = bn + wn * 32 + ni * 16 + r16;
        size_t idx = (size_t)r * N + c;
        float v = acc[mi][ni][j];
        if constexpr (EPI == 0) {
          Cf[idx] = v;
        } else if constexpr (EPI == 1) {
          Cf[idx] = v + add_src[idx];
        } else if constexpr (EPI == 2) {
          Cb[idx] = __float2bfloat16(siluf(v));
        } else if constexpr (EPI == 3) {
          Cb[idx] = __float2bfloat16(v * __bfloat162float(Cb[idx]));
        }
      }
    }
  }
}

// ---------------------------------------------------------------- conv+silu+normalize for the 32 B/C channels
__global__ __launch_bounds__(256) void bcdt_k(const float* __restrict__ zx,
                                              const float* __restrict__ cw,
                                              const float* __restrict__ cb,
                                              float* __restrict__ bc) {
  int t = threadIdx.x;
  int r = blockIdx.x * 8 + (t >> 5);
  int ch = t & 31;
  int l = r & (SEQ - 1);
  int c = D_INNER + ch;
  float acc = cb[c];
  #pragma unroll
  for (int k = 0; k < 4; ++k) {
    int lp = l - 3 + k;
    if (lp >= 0)
      acc = fmaf(zx[(size_t)(r - 3 + k) * PROJ_PAD + 2 * D_INNER + ch], cw[c * 4 + k], acc);
  }
  acc = siluf(acc);
  float ss = acc * acc;
  ss += __shfl_xor(ss, 1);
  ss += __shfl_xor(ss, 2);
  ss += __shfl_xor(ss, 4);
  ss += __shfl_xor(ss, 8);
  bc[r * 32 + ch] = acc / (sqrtf(ss) + 1e-6f);
}

// ---------------------------------------------------------------- chunk transfer matrices
__global__ __launch_bounds__(256) void pk_k(const float* __restrict__ dtT,
                                            const float* __restrict__ A_log,
                                            float* __restrict__ Pm) {
  int bh = blockIdx.x;
  int h = bh & 31;
  int t = threadIdx.x;
  int ch = t >> 4, n = t & 15;
  float a = __expf(A_log[h * 16 + n]);
  const float* dtp = dtT + (size_t)h * ROWS + (size_t)(bh >> 5) * SEQ + ch * CH;
  float p00 = 1.f, p01 = 0.f, p10 = 0.f, p11 = 1.f;
  for (int l = 0; l < CH; ++l) {
    float dt = dtp[l];
    float s  = 1.0f / fmaf(dt * dt, a, 1.0f);
    float m00 = s;
    float m01 = -dt * a * s;
    float m10 = dt * s;
    float m11 = fmaf(-dt * a, m10, 1.0f);
    float q00 = fmaf(m00, p00, m01 * p10);
    float q01 = fmaf(m00, p01, m01 * p11);
    float q10 = fmaf(m10, p00, m11 * p10);
    float q11 = fmaf(m10, p01, m11 * p11);
    p00 = q00; p01 = q01; p10 = q10; p11 = q11;
  }
  float4 v = {p00, p01, p10, p11};
  *(float4*)&Pm[(((size_t)bh * NCH + ch) * 16 + n) * 4] = v;
}

// ---------------------------------------------------------------- propagate chunk-boundary states
__global__ __launch_bounds__(256) void prop_k(const float* __restrict__ Pm,
                                              const float* __restrict__ pend,
                                              float* __restrict__ sinit) {
  int gid = blockIdx.x * 256 + threadIdx.x;
  int n  = gid & 15;
  int d  = (gid >> 4) & 63;
  int bh = gid >> 10;
  float s0 = 0.f, s1 = 0.f;
  for (int c = 0; c < NCH; ++c) {
    size_t i2 = (((size_t)bh * NCH + c) * 64 + d) * 16 + n;
    *(float2*)&sinit[i2 * 2] = make_float2(s0, s1);
    float4 P  = *(const float4*)&Pm[(((size_t)bh * NCH + c) * 16 + n) * 4];
    float2 pe = *(const float2*)&pend[i2 * 2];
    float t0 = fmaf(P.x, s0, fmaf(P.y, s1, pe.x));
    float t1 = fmaf(P.z, s0, fmaf(P.w, s1, pe.y));
    s0 = t0; s1 = t1;
  }
}

// ---------------------------------------------------------------- chunked scan
#define T_TILE 16
#define TPC (CH / T_TILE)
template<int PHASE>
__global__ __launch_bounds__(128) void scan_k(
    const float* __restrict__ zx, const float* __restrict__ bcb,
    const float* __restrict__ dtT, const float* __restrict__ A_log,
    const float* __restrict__ Dp, const float* __restrict__ cw,
    const float* __restrict__ cb, float* __restrict__ states,
    __hip_bfloat16* __restrict__ po)
{
  const int blk  = blockIdx.x;
  const int half = blk & 1;
  const int ch   = (blk >> 1) & 15;
  const int h    = (blk >> 5) & 31;
  const int b    = blk >> 10;
  const int bh   = b * 32 + h;
  const int tid  = threadIdx.x;
  const int wv   = tid >> 6;
  const int lane = tid & 63;
  const int d16  = lane & 15;
  const int ng   = lane >> 4;
  const int n0   = ng * 4;
  const int dl   = half * 32 + wv * 16 + d16;
  const int dcol = h * 64 + dl;
  const size_t rowbase = (size_t)b * SEQ + (size_t)ch * CH;

  __shared__ float xz [2][T_TILE][64];
  __shared__ float bct[2][T_TILE][32];
  __shared__ float st [2][T_TILE][32];   // [n]=S, [16+n]=dt*A
  __shared__ float dtt[2][T_TILE];
  __shared__ float aexp[16];
  __shared__ float opart[T_TILE][32][4];

  if (tid < 16) aexp[tid] = __expf(A_log[h * 16 + tid]);

  const float Dh = Dp[h];
  const float c0 = cw[dcol * 4 + 0], c1 = cw[dcol * 4 + 1];
  const float c2 = cw[dcol * 4 + 2], c3 = cw[dcol * 4 + 3];
  const float cbv = cb[dcol];

  auto stage = [&](int tile, int buf) {
    const size_t r0 = rowbase + (size_t)tile * T_TILE;
    #pragma unroll
    for (int i = 0; i < 2; ++i) {
      int lr = 8 * i + 4 * wv + (lane >> 4);
      int c4 = (lane & 15) * 4;
      int col = (c4 < 32) ? (h * 64 + half * 32 + c4)
                          : (D_INNER + h * 64 + half * 32 + (c4 - 32));
      const float* g = zx + (r0 + lr) * PROJ_PAD + col;
      float* l = &xz[buf][0][0] + (8 * i + 4 * wv) * 64 + (lane & 15) * 4;
      __builtin_amdgcn_global_load_lds((const __attribute__((address_space(1))) unsigned int*)g,
                                       (__attribute__((address_space(3))) unsigned int*)l,
                                       16, 0, 0);
    }
    {
      int lr = 8 * wv + (lane >> 3);
      const float* g = bcb + (r0 + lr) * 32 + (lane & 7) * 4;
      float* l = &bct[buf][0][0] + 8 * wv * 32 + (lane & 7) * 4;
      __builtin_amdgcn_global_load_lds((const __attribute__((address_space(1))) unsigned int*)g,
                                       (__attribute__((address_space(3))) unsigned int*)l,
                                       16, 0, 0);
    }
  };

  auto sprep = [&](int buf, float dtn) {
    #pragma unroll
    for (int i = 0; i < 2; ++i) {
      int idx = tid + 128 * i;
      int row = idx >> 4, n = idx & 15;
      float dv = __shfl(dtn, row);
      float a  = aexp[n];
      st[buf][row][n]      = 1.0f / fmaf(dv * dv, a, 1.0f);
      st[buf][row][16 + n] = dv * a;
    }
  };

  stage(0, 0);
  float dtn = 0.f;
  if (lane < 16) dtn = dtT[(size_t)h * ROWS + rowbase + lane];
  __syncthreads();
  if (tid < 16) dtt[0][tid] = dtn;
  sprep(0, dtn);
  __syncthreads();

  float w[4], ys[4];
  if constexpr (PHASE == 1) {
    #pragma unroll
    for (int j = 0; j < 4; ++j) { w[j] = 0.f; ys[j] = 0.f; }
  } else {
    #pragma unroll
    for (int j = 0; j < 4; ++j) {
      size_t i2 = (((size_t)bh * NCH + ch) * 64 + dl) * 16 + (n0 + j);
      float2 s = *(const float2*)&states[i2 * 2];
      w[j] = s.x; ys[j] = s.y;
    }
  }
  float xw1 = 0.f, xw2 = 0.f, xw3 = 0.f;
  if (ch > 0) {
    const float* xb = zx + rowbase * PROJ_PAD + D_INNER + dcol;
    xw1 = xb[-3 * PROJ_PAD];
    xw2 = xb[-2 * PROJ_PAD];
    xw3 = xb[-1 * PROJ_PAD];
  }
  int cur = 0;

  for (int t = 0; t < TPC; ++t) {
    if (t + 1 < TPC) {
      stage(t + 1, cur ^ 1);
      if (lane < 16) dtn = dtT[(size_t)h * ROWS + rowbase + (size_t)(t + 1) * T_TILE + lane];
    }
    #pragma unroll 4
    for (int l = 0; l < T_TILE; ++l) {
      float xl  = xz[cur][l][32 + wv * 16 + d16];
      float dtv = dtt[cur][l];
      f32x4 Sv = *(const f32x4*)&st [cur][l][n0];
      f32x4 Av = *(const f32x4*)&st [cur][l][16 + n0];
      f32x4 Bv = *(const f32x4*)&bct[cur][l][n0];
      float cacc = fmaf(c3, xl, fmaf(c2, xw3, fmaf(c1, xw2, fmaf(c0, xw1, cbv))));
      float uv = siluf(cacc);
      xw1 = xw2; xw2 = xw3; xw3 = xl;
      float du = dtv * uv;
      if constexpr (PHASE == 3) {
        f32x4 Cv = *(const f32x4*)&bct[cur][l][16 + n0];
        float o = 0.f;
        #pragma unroll
        for (int j = 0; j < 4; ++j) {
          float tmp = fmaf(-Av[j], ys[j], w[j]);
          tmp = fmaf(du, Bv[j], tmp);
          w[j] = Sv[j] * tmp;
          ys[j] = fmaf(dtv, w[j], ys[j]);
          o = fmaf(ys[j], Cv[j], o);
        }
        float ofin = (ng == 0) ? fmaf(Dh, uv, o) : o;
        opart[l][wv * 16 + d16][ng] = ofin;
      } else {
        #pragma unroll
        for (int j = 0; j < 4; ++j) {
          float tmp = fmaf(-Av[j], ys[j], w[j]);
          tmp = fmaf(du, Bv[j], tmp);
          w[j] = Sv[j] * tmp;
          ys[j] = fmaf(dtv, w[j], ys[j]);
        }
      }
    }
    if constexpr (PHASE == 3) {
      #pragma unroll
      for (int i = 0; i < 4; ++i) {
        int l  = (lane >> 4) + 4 * i;
        int dd = wv * 16 + d16;
        f32x4 op = *(const f32x4*)&opart[l][dd][0];
        float zv = xz[cur][l][dd];
        float yv = (op[0] + op[1]) + (op[2] + op[3]);
        po[(rowbase + (size_t)t * T_TILE + l) * D_INNER + (h * 64 + half * 32 + dd)] =
            __float2bfloat16(yv * siluf(zv));
      }
    }
    __syncthreads();
    if (t + 1 < TPC) {
      if (tid < 16) dtt[cur ^ 1][tid] = dtn;
      sprep(cur ^ 1, dtn);
      __syncthreads();
    }
    cur ^= 1;
  }

  if constexpr (PHASE == 1) {
    #pragma unroll
    for (int j = 0; j < 4; ++j) {
      size_t i2 = (((size_t)bh * NCH + ch) * 64 + dl) * 16 + (n0 + j);
      *(float2*)&states[i2 * 2] = make_float2(w[j], ys[j]);
    }
  }
}

// ---------------------------------------------------------------- launch
extern "C" void kernel_launch(void* const* d_in, const int* in_sizes, int n_in,
                              void* d_out, int out_size, void* d_ws, size_t ws_size,
                              hipStream_t stream) {
  const float* x     = (const float*)d_in[0];
  const float* n1w   = (const float*)d_in[1];
  const float* wi    = (const float*)d_in[2];
  const float* cw    = (const float*)d_in[3];
  const float* cb    = (const float*)d_in[4];
  const float* A_log = (const float*)d_in[5];
  const float* dtb   = (const float*)d_in[6];
  const float* Dp    = (const float*)d_in[7];
  const float* wo    = (const float*)d_in[8];
  const float* n2w   = (const float*)d_in[9];
  const float* wg    = (const float*)d_in[10];
  const float* wu    = (const float*)d_in[11];
  const float* wd    = (const float*)d_in[12];
  float* out = (float*)d_out;

  char* p = (char*)d_ws;
  auto take = [&](size_t b) { char* q = p; p += (b + 255) & ~(size_t)255; return q; };
  __hip_bfloat16* wbi  = (__hip_bfloat16*)take((size_t)PROJ_PAD * D_MODEL * 2);
  __hip_bfloat16* wbo  = (__hip_bfloat16*)take((size_t)D_MODEL * D_INNER * 2);
  __hip_bfloat16* wbg  = (__hip_bfloat16*)take((size_t)FFN_DIM * D_MODEL * 2);
  __hip_bfloat16* wbu  = (__hip_bfloat16*)take((size_t)FFN_DIM * D_MODEL * 2);
  __hip_bfloat16* wbd  = (__hip_bfloat16*)take((size_t)D_MODEL * FFN_DIM * 2);
  __hip_bfloat16* h0b  = (__hip_bfloat16*)take((size_t)ROWS * D_MODEL * 2);
  float*          zx   = (float*)take((size_t)ROWS * PROJ_PAD * 4);
  float*          bcb  = (float*)take((size_t)ROWS * 32 * 4);
  float*          dtT  = (float*)take((size_t)ROWS * 32 * 4);
  __hip_bfloat16* po   = (__hip_bfloat16*)take((size_t)ROWS * D_INNER * 2);
  float*          pend = (float*)take((size_t)128 * NCH * 64 * 16 * 2 * 4);
  float*          sini = (float*)take((size_t)128 * NCH * 64 * 16 * 2 * 4);
  float*          Pm   = (float*)take((size_t)128 * NCH * 16 * 4 * 4);
  float*          h0f  = (float*)zx;
  float*          h    = (float*)zx;
  __hip_bfloat16* gact = (__hip_bfloat16*)((char*)zx + 33554432);

  hipFuncSetAttribute(reinterpret_cast<const void*>(&gemm8<0>),  hipFuncAttributeMaxDynamicSharedMemorySize, 131072);
  hipFuncSetAttribute(reinterpret_cast<const void*>(&gemm8<2>),  hipFuncAttributeMaxDynamicSharedMemorySize, 131072);
  hipFuncSetAttribute(reinterpret_cast<const void*>(&gemm8<3>),  hipFuncAttributeMaxDynamicSharedMemorySize, 131072);
  hipFuncSetAttribute(reinterpret_cast<const void*>(&gemm8B<1>), hipFuncAttributeMaxDynamicSharedMemorySize, 131072);

  // weight conversions
  cvt_pad_k<<<(PROJ_PAD * D_MODEL + 255) / 256, 256, 0, stream>>>(wi, wbi);
  cvt_k<<<(D_MODEL * D_INNER + 255) / 256, 256, 0, stream>>>(wo, wbo, D_MODEL * D_INNER);
  cvt_k<<<(FFN_DIM * D_MODEL + 255) / 256, 256, 0, stream>>>(wg, wbg, FFN_DIM * D_MODEL);
  cvt_k<<<(FFN_DIM * D_MODEL + 255) / 256, 256, 0, stream>>>(wu, wbu, FFN_DIM * D_MODEL);
  cvt_k<<<(FFN_DIM * D_MODEL + 255) / 256, 256, 0, stream>>>(wd, wbd, FFN_DIM * D_MODEL);

  // mixer
  rmsnorm_k<<<ROWS, 256, 0, stream>>>(x, n1w, h0b, h0f);
  dtproj_k<<<ROWS / 4, 256, 0, stream>>>(h0f, wi, dtb, dtT);
  gemm8<0><<<(ROWS / 256) * (PROJ_PAD / 256), 512, 131072, stream>>>(h0b, wbi, zx, nullptr, nullptr,
                                                                     ROWS, PROJ_PAD, D_MODEL);
  bcdt_k<<<ROWS / 8, 256, 0, stream>>>(zx, cw, cb, bcb);
  pk_k<<<BATCH * N_HEADS, 256, 0, stream>>>(dtT, A_log, Pm);
  scan_k<1><<<BATCH * N_HEADS * NCH * 2, 128, 0, stream>>>(zx, bcb, dtT, A_log, Dp, cw, cb, pend, nullptr);
  prop_k<<<BATCH * N_HEADS * 64 * 16 / 256, 256, 0, stream>>>(Pm, pend, sini);
  scan_k<3><<<BATCH * N_HEADS * NCH * 2, 128, 0, stream>>>(zx, bcb, dtT, A_log, Dp, cw, cb, sini, po);
  gemm8B<1><<<(ROWS / 256) * (D_MODEL / 128), 512, 131072, stream>>>(po, wbo, h, nullptr, x,
                                                                     ROWS, D_MODEL, D_INNER);
  // FFN
  rmsnorm_k<<<ROWS, 256, 0, stream>>>(h, n2w, h0b, nullptr);
  gemm8<2><<<(ROWS / 256) * (FFN_DIM / 256), 512, 131072, stream>>>(h0b, wbg, nullptr, gact, nullptr,
                                                                    ROWS, FFN_DIM, D_MODEL);
  gemm8<3><<<(ROWS / 256) * (FFN_DIM / 256), 512, 131072, stream>>>(h0b, wbu, nullptr, gact, nullptr,
                                                                    ROWS, FFN_DIM, D_MODEL);
  gemm8B<1><<<(ROWS / 256) * (D_MODEL / 128), 512, 131072, stream>>>(gact, wbd, out, nullptr, h,
                                                                     ROWS, D_MODEL, FFN_DIM);
}

// Round 10
// 704.105 us; speedup vs baseline: 2.3907x; 1.0106x over previous
//
#include <hip/hip_runtime.h>
#include <hip/hip_bf16.h>

#define D_MODEL   1024
#define D_STATE   16
#define D_HEAD    64
#define D_CONV    4
#define FFN_DIM   2816
#define D_INNER   2048
#define N_HEADS   32
#define BATCH     4
#define SEQ       2048
#define ROWS      (BATCH*SEQ)     // 8192
#define PROJ_DIM  4160
#define PROJ_PAD  4352            // 17 * 256
#define CONV_CH   2080
#define CH        128             // scan chunk length
#define NCH       (SEQ/CH)        // 16 chunks

typedef __bf16 bf16x8 __attribute__((ext_vector_type(8)));
typedef float  f32x4  __attribute__((ext_vector_type(4)));
typedef float  f32x2  __attribute__((ext_vector_type(2)));

__device__ __forceinline__ float siluf(float x) { return x / (1.0f + __expf(-x)); }

#define SBAR() do { asm volatile("" ::: "memory"); __builtin_amdgcn_s_barrier(); asm volatile("" ::: "memory"); } while (0)
#define LGKM0() asm volatile("s_waitcnt lgkmcnt(0)" ::: "memory")
#define VMCNT4() asm volatile("s_waitcnt vmcnt(4)" ::: "memory")
#define VMCNT2() asm volatile("s_waitcnt vmcnt(2)" ::: "memory")
#define VMCNT0() asm volatile("s_waitcnt vmcnt(0)" ::: "memory")

// ---------------------------------------------------------------- converts
__global__ void cvt_k(const float* __restrict__ src, __hip_bfloat16* __restrict__ dst, int n) {
  int i = blockIdx.x * blockDim.x + threadIdx.x;
  if (i < n) dst[i] = __float2bfloat16(src[i]);
}

__global__ void cvt_pad_k(const float* __restrict__ src, __hip_bfloat16* __restrict__ dst) {
  int i = blockIdx.x * blockDim.x + threadIdx.x;
  if (i >= PROJ_PAD * D_MODEL) return;
  int row = i >> 10;
  dst[i] = (row < PROJ_DIM) ? __float2bfloat16(src[i]) : __float2bfloat16(0.0f);
}

// ---------------------------------------------------------------- rmsnorm
__global__ __launch_bounds__(256) void rmsnorm_k(const float* __restrict__ x,
                                                 const float* __restrict__ w,
                                                 __hip_bfloat16* __restrict__ out,
                                                 float* __restrict__ outf) {
  int row = blockIdx.x;
  int t = threadIdx.x;
  const float* xr = x + (size_t)row * D_MODEL;
  float4 v = ((const float4*)xr)[t];
  float ss = v.x*v.x + v.y*v.y + v.z*v.z + v.w*v.w;
  #pragma unroll
  for (int o = 32; o > 0; o >>= 1) ss += __shfl_xor(ss, o);
  __shared__ float red[4];
  if ((t & 63) == 0) red[t >> 6] = ss;
  __syncthreads();
  ss = red[0] + red[1] + red[2] + red[3];
  float scale = rsqrtf(ss * (1.0f / D_MODEL) + 1e-6f);
  float4 wv = ((const float4*)w)[t];
  float4 r;
  r.x = v.x * scale * wv.x; r.y = v.y * scale * wv.y;
  r.z = v.z * scale * wv.z; r.w = v.w * scale * wv.w;
  __hip_bfloat16* orow = out + (size_t)row * D_MODEL + t * 4;
  orow[0] = __float2bfloat16(r.x);
  orow[1] = __float2bfloat16(r.y);
  orow[2] = __float2bfloat16(r.z);
  orow[3] = __float2bfloat16(r.w);
  if (outf) ((float4*)(outf + (size_t)row * D_MODEL))[t] = r;
}

// ---------------------------------------------------------------- dt projection (f32, block-per-4-rows)
__global__ __launch_bounds__(256) void dtproj_k(const float* __restrict__ xn,
                                                const float* __restrict__ wi,
                                                const float* __restrict__ dtb,
                                                float* __restrict__ dtT) {
  const int r0 = blockIdx.x * 4;
  const int t  = threadIdx.x;
  const int hh  = t >> 3;
  const int seg = t & 7;

  __shared__ float xs[4][D_MODEL];
  #pragma unroll
  for (int i = 0; i < 4; ++i)
    ((float4*)&xs[i][0])[t] = ((const float4*)(xn + (size_t)(r0 + i) * D_MODEL))[t];
  __syncthreads();

  const float4* w4 = (const float4*)(wi + (size_t)(2 * D_INNER + 2 * D_STATE + hh) * D_MODEL) + seg * 32;
  const float4* x0 = (const float4*)&xs[0][0] + seg * 32;
  const float4* x1 = (const float4*)&xs[1][0] + seg * 32;
  const float4* x2 = (const float4*)&xs[2][0] + seg * 32;
  const float4* x3 = (const float4*)&xs[3][0] + seg * 32;
  float a0 = 0.f, a1 = 0.f, a2 = 0.f, a3 = 0.f;
  #pragma unroll 8
  for (int k = 0; k < 32; ++k) {
    float4 wv = w4[k];
    float4 v0 = x0[k], v1 = x1[k], v2 = x2[k], v3 = x3[k];
    a0 = fmaf(wv.x, v0.x, fmaf(wv.y, v0.y, fmaf(wv.z, v0.z, fmaf(wv.w, v0.w, a0))));
    a1 = fmaf(wv.x, v1.x, fmaf(wv.y, v1.y, fmaf(wv.z, v1.z, fmaf(wv.w, v1.w, a1))));
    a2 = fmaf(wv.x, v2.x, fmaf(wv.y, v2.y, fmaf(wv.z, v2.z, fmaf(wv.w, v2.w, a2))));
    a3 = fmaf(wv.x, v3.x, fmaf(wv.y, v3.y, fmaf(wv.z, v3.z, fmaf(wv.w, v3.w, a3))));
  }
  #pragma unroll
  for (int m = 1; m < 8; m <<= 1) {
    a0 += __shfl_xor(a0, m);
    a1 += __shfl_xor(a1, m);
    a2 += __shfl_xor(a2, m);
    a3 += __shfl_xor(a3, m);
  }
  if (seg == 0) {
    float bias = dtb[hh];
    float v[4] = {a0, a1, a2, a3};
    #pragma unroll
    for (int i = 0; i < 4; ++i) {
      float xv = v[i] + bias;
      dtT[(size_t)hh * ROWS + r0 + i] = (xv > 20.f) ? xv : log1pf(__expf(xv));
    }
  }
}

// ---------------------------------------------------------------- 256x256 8-phase GEMM
template<int EPI>
__global__ __launch_bounds__(512, 2) void gemm8(
    const __hip_bfloat16* __restrict__ A,
    const __hip_bfloat16* __restrict__ Bw,
    float* __restrict__ Cf,
    __hip_bfloat16* __restrict__ Cb,
    const float* __restrict__ add_src,
    int M, int N, int K)
{
  extern __shared__ char lds[];
  const int nwg = (M >> 8) * (N >> 8);
  int bid = blockIdx.x;
  bid = (bid & 7) * (nwg >> 3) + (bid >> 3);
  const int ntn = N >> 8;
  const int bm = (bid / ntn) << 8;
  const int bn = (bid % ntn) << 8;

  const int tid  = threadIdx.x;
  const int wid  = tid >> 6;
  const int lane = tid & 63;
  const int wm = wid >> 2;
  const int wn = wid & 3;
  const int r16 = lane & 15;
  const int kg  = lane >> 4;

  const int rb = ((r16 << 6) + (kg << 4)) ^ ((r16 & 8) << 2);

  const int s_sub = tid >> 6;
  const int s_w   = (tid & 63) << 4;
  const int s_wp  = s_w ^ ((((s_w) >> 9) & 1) << 5);
  const int s_row = ((s_sub >> 1) << 4) + (s_wp >> 6);
  const int s_col = ((s_sub & 1) << 5) + ((s_wp >> 1) & 31);

  auto stage = [&](int buf, int mat, int half, int c, int kt) {
    const __hip_bfloat16* src = (mat == 0)
        ? A  + (size_t)(bm + half * 128 + c * 64 + s_row) * K + kt * 64 + s_col
        : Bw + (size_t)(bn + half * 128 + c * 64 + s_row) * K + kt * 64 + s_col;
    char* dst = lds + buf * 65536 + mat * 32768 + half * 16384 + c * 8192 + tid * 16;
    __builtin_amdgcn_global_load_lds((const __attribute__((address_space(1))) unsigned int*)src,
                                     (__attribute__((address_space(3))) unsigned int*)dst,
                                     16, 0, 0);
  };

  f32x4 acc[8][4] = {};
  bf16x8 af[4][2], bfr[4][2];

  const int NT = K >> 6;
  stage(0,0,0,0,0); stage(0,0,0,1,0); stage(0,0,1,0,0); stage(0,0,1,1,0);
  stage(0,1,0,0,0); stage(0,1,0,1,0); stage(0,1,1,0,0); stage(0,1,1,1,0);
  __syncthreads();

  for (int kt = 0; kt < NT; ++kt) {
    const int buf = kt & 1, nbuf = buf ^ 1;
    const bool st = (kt + 1 < NT);
    const char* Ab = lds + buf * 65536 + wm * 16384;
    const char* Bb = lds + buf * 65536 + 32768 + (wn >> 1) * 16384 + (wn & 1) * 8192;

    #pragma unroll
    for (int mi2 = 0; mi2 < 4; ++mi2)
      #pragma unroll
      for (int kk = 0; kk < 2; ++kk)
        af[mi2][kk] = *(const bf16x8*)(Ab + (mi2 * 2 + kk) * 1024 + rb);
    #pragma unroll
    for (int ni = 0; ni < 2; ++ni)
      #pragma unroll
      for (int kk = 0; kk < 2; ++kk)
        bfr[ni][kk] = *(const bf16x8*)(Bb + (ni * 2 + kk) * 1024 + rb);
    if (st) { stage(nbuf,1,0,0,kt+1); stage(nbuf,1,0,1,kt+1); }
    SBAR(); LGKM0();
    __builtin_amdgcn_s_setprio(1);
    #pragma unroll
    for (int mi2 = 0; mi2 < 4; ++mi2)
      #pragma unroll
      for (int ni = 0; ni < 2; ++ni)
        #pragma unroll
        for (int kk = 0; kk < 2; ++kk)
          acc[mi2][ni] = __builtin_amdgcn_mfma_f32_16x16x32_bf16(af[mi2][kk], bfr[ni][kk], acc[mi2][ni], 0, 0, 0);
    __builtin_amdgcn_s_setprio(0);
    SBAR();

    #pragma unroll
    for (int ni = 2; ni < 4; ++ni)
      #pragma unroll
      for (int kk = 0; kk < 2; ++kk)
        bfr[ni][kk] = *(const bf16x8*)(Bb + (ni * 2 + kk) * 1024 + rb);
    if (st) { stage(nbuf,1,1,0,kt+1); stage(nbuf,1,1,1,kt+1); }
    SBAR(); LGKM0();
    __builtin_amdgcn_s_setprio(1);
    #pragma unroll
    for (int mi2 = 0; mi2 < 4; ++mi2)
      #pragma unroll
      for (int ni = 2; ni < 4; ++ni)
        #pragma unroll
        for (int kk = 0; kk < 2; ++kk)
          acc[mi2][ni] = __builtin_amdgcn_mfma_f32_16x16x32_bf16(af[mi2][kk], bfr[ni][kk], acc[mi2][ni], 0, 0, 0);
    __builtin_amdgcn_s_setprio(0);
    if (st) { VMCNT4(); } else { VMCNT0(); }
    SBAR();

    #pragma unroll
    for (int mi2 = 0; mi2 < 4; ++mi2)
      #pragma unroll
      for (int kk = 0; kk < 2; ++kk)
        af[mi2][kk] = *(const bf16x8*)(Ab + ((4 + mi2) * 2 + kk) * 1024 + rb);
    if (st) { stage(nbuf,0,0,0,kt+1); stage(nbuf,0,1,0,kt+1); }
    SBAR(); LGKM0();
    __builtin_amdgcn_s_setprio(1);
    #pragma unroll
    for (int mi2 = 0; mi2 < 4; ++mi2)
      #pragma unroll
      for (int ni = 0; ni < 2; ++ni)
        #pragma unroll
        for (int kk = 0; kk < 2; ++kk)
          acc[4 + mi2][ni] = __builtin_amdgcn_mfma_f32_16x16x32_bf16(af[mi2][kk], bfr[ni][kk], acc[4 + mi2][ni], 0, 0, 0);
    __builtin_amdgcn_s_setprio(0);
    SBAR();

    if (st) { stage(nbuf,0,0,1,kt+1); stage(nbuf,0,1,1,kt+1); }
    SBAR(); LGKM0();
    __builtin_amdgcn_s_setprio(1);
    #pragma unroll
    for (int mi2 = 0; mi2 < 4; ++mi2)
      #pragma unroll
      for (int ni = 2; ni < 4; ++ni)
        #pragma unroll
        for (int kk = 0; kk < 2; ++kk)
          acc[4 + mi2][ni] = __builtin_amdgcn_mfma_f32_16x16x32_bf16(af[mi2][kk], bfr[ni][kk], acc[4 + mi2][ni], 0, 0, 0);
    __builtin_amdgcn_s_setprio(0);
    VMCNT2();
    SBAR();
  }

  #pragma unroll
  for (int mi = 0; mi < 8; ++mi) {
    #pragma unroll
    for (int ni = 0; ni < 4; ++ni) {
      #pragma unroll
      for (int j = 0; j < 4; ++j) {
        int r = bm + wm * 128 + mi * 16 + kg * 4 + j;
        int c = bn + wn * 64 + ni * 16 + r16;
        size_t idx = (size_t)r * N + c;
        float v = acc[mi][ni][j];
        if constexpr (EPI == 0) {
          Cf[idx] = v;
        } else if constexpr (EPI == 1) {
          Cf[idx] = v + add_src[idx];
        } else if constexpr (EPI == 2) {
          Cb[idx] = __float2bfloat16(siluf(v));
        } else if constexpr (EPI == 3) {
          Cb[idx] = __float2bfloat16(v * __bfloat162float(Cb[idx]));
        }
      }
    }
  }
}

// ---------------------------------------------------------------- 256x128 8-phase GEMM (full grid at N=1024)
template<int EPI>
__global__ __launch_bounds__(512, 2) void gemm8B(
    const __hip_bfloat16* __restrict__ A,
    const __hip_bfloat16* __restrict__ Bw,
    float* __restrict__ Cf,
    __hip_bfloat16* __restrict__ Cb,
    const float* __restrict__ add_src,
    int M, int N, int K)
{
  extern __shared__ char lds[];
  const int nwg = (M >> 8) * (N >> 7);
  int bid = blockIdx.x;
  bid = (bid & 7) * (nwg >> 3) + (bid >> 3);
  const int ntn = N >> 7;
  const int bm = (bid / ntn) << 8;
  const int bn = (bid % ntn) << 7;

  const int tid  = threadIdx.x;
  const int wid  = tid >> 6;
  const int lane = tid & 63;
  const int wm = wid >> 2;
  const int wn = wid & 3;
  const int r16 = lane & 15;
  const int kg  = lane >> 4;

  const int rb = ((r16 << 6) + (kg << 4)) ^ ((r16 & 8) << 2);

  const int s_sub = tid >> 6;
  const int s_w   = (tid & 63) << 4;
  const int s_wp  = s_w ^ ((((s_w) >> 9) & 1) << 5);
  const int s_row = ((s_sub >> 1) << 4) + (s_wp >> 6);
  const int s_col = ((s_sub & 1) << 5) + ((s_wp >> 1) & 31);

  auto stageA = [&](int buf, int half, int c, int kt) {
    const __hip_bfloat16* src = A + (size_t)(bm + half * 128 + c * 64 + s_row) * K + kt * 64 + s_col;
    char* dst = lds + buf * 65536 + half * 16384 + c * 8192 + tid * 16;
    __builtin_amdgcn_global_load_lds((const __attribute__((address_space(1))) unsigned int*)src,
                                     (__attribute__((address_space(3))) unsigned int*)dst,
                                     16, 0, 0);
  };
  auto stageB = [&](int buf, int c, int kt) {
    const __hip_bfloat16* src = Bw + (size_t)(bn + c * 64 + s_row) * K + kt * 64 + s_col;
    char* dst = lds + buf * 65536 + 32768 + c * 8192 + tid * 16;
    __builtin_amdgcn_global_load_lds((const __attribute__((address_space(1))) unsigned int*)src,
                                     (__attribute__((address_space(3))) unsigned int*)dst,
                                     16, 0, 0);
  };

  f32x4 acc[8][2] = {};
  bf16x8 af[4][2], bfr[2][2];

  const int NT = K >> 6;
  stageB(0,0,0); stageB(0,1,0);
  stageA(0,0,0,0); stageA(0,1,0,0); stageA(0,0,1,0); stageA(0,1,1,0);
  __syncthreads();

  for (int kt = 0; kt < NT; ++kt) {
    const int buf = kt & 1, nbuf = buf ^ 1;
    const bool st = (kt + 1 < NT);
    const char* Ab = lds + buf * 65536 + wm * 16384;
    const char* Bb = lds + buf * 65536 + 32768 + (wn >> 1) * 8192 + (wn & 1) * 4096;

    #pragma unroll
    for (int mi2 = 0; mi2 < 4; ++mi2)
      #pragma unroll
      for (int kk = 0; kk < 2; ++kk)
        af[mi2][kk] = *(const bf16x8*)(Ab + (mi2 * 2 + kk) * 1024 + rb);
    #pragma unroll
    for (int ni = 0; ni < 2; ++ni)
      #pragma unroll
      for (int kk = 0; kk < 2; ++kk)
        bfr[ni][kk] = *(const bf16x8*)(Bb + (ni * 2 + kk) * 1024 + rb);
    if (st) { stageB(nbuf,0,kt+1); stageB(nbuf,1,kt+1); stageA(nbuf,0,0,kt+1); stageA(nbuf,1,0,kt+1); }
    SBAR(); LGKM0();
    __builtin_amdgcn_s_setprio(1);
    #pragma unroll
    for (int mi2 = 0; mi2 < 4; ++mi2)
      #pragma unroll
      for (int ni = 0; ni < 2; ++ni)
        #pragma unroll
        for (int kk = 0; kk < 2; ++kk)
          acc[mi2][ni] = __builtin_amdgcn_mfma_f32_16x16x32_bf16(af[mi2][kk], bfr[ni][kk], acc[mi2][ni], 0, 0, 0);
    __builtin_amdgcn_s_setprio(0);
    if (st) { VMCNT4(); } else { VMCNT0(); }
    SBAR();

    #pragma unroll
    for (int mi2 = 0; mi2 < 4; ++mi2)
      #pragma unroll
      for (int kk = 0; kk < 2; ++kk)
        af[mi2][kk] = *(const bf16x8*)(Ab + ((4 + mi2) * 2 + kk) * 1024 + rb);
    if (st) { stageA(nbuf,0,1,kt+1); stageA(nbuf,1,1,kt+1); }
    SBAR(); LGKM0();
    __builtin_amdgcn_s_setprio(1);
    #pragma unroll
    for (int mi2 = 0; mi2 < 4; ++mi2)
      #pragma unroll
      for (int ni = 0; ni < 2; ++ni)
        #pragma unroll
        for (int kk = 0; kk < 2; ++kk)
          acc[4 + mi2][ni] = __builtin_amdgcn_mfma_f32_16x16x32_bf16(af[mi2][kk], bfr[ni][kk], acc[4 + mi2][ni], 0, 0, 0);
    __builtin_amdgcn_s_setprio(0);
    VMCNT2();
    SBAR();
  }

  #pragma unroll
  for (int mi = 0; mi < 8; ++mi) {
    #pragma unroll
    for (int ni = 0; ni < 2; ++ni) {
      #pragma unroll
      for (int j = 0; j < 4; ++j) {
        int r = bm + wm * 128 + mi * 16 + kg * 4 + j;
        int c = bn + wn * 32 + ni * 16 + r16;
        size_t idx = (size_t)r * N + c;
        float v = acc[mi][ni][j];
        if constexpr (EPI == 0) {
          Cf[idx] = v;
        } else if constexpr (EPI == 1) {
          Cf[idx] = v + add_src[idx];
        } else if constexpr (EPI == 2) {
          Cb[idx] = __float2bfloat16(siluf(v));
        } else if constexpr (EPI == 3) {
          Cb[idx] = __float2bfloat16(v * __bfloat162float(Cb[idx]));
        }
      }
    }
  }
}

// ---------------------------------------------------------------- u = silu(depthwise conv(x)), bf16 into po buffer
// thread covers 4 consecutive channels; grid = ROWS*512/256
__global__ __launch_bounds__(256) void duconv_k(const float* __restrict__ zx,
                                                const float* __restrict__ cw,
                                                const float* __restrict__ cb,
                                                __hip_bfloat16* __restrict__ u_po) {
  int idx = blockIdx.x * 256 + threadIdx.x;
  int q = idx & 511;
  int r = idx >> 9;
  int d0 = q << 2;
  int l = r & (SEQ - 1);
  float4 cb4 = ((const float4*)cb)[q];
  float tw[4][4];
  #pragma unroll
  for (int i = 0; i < 4; ++i) {
    float4 t = ((const float4*)cw)[d0 + i];
    tw[i][0] = t.x; tw[i][1] = t.y; tw[i][2] = t.z; tw[i][3] = t.w;
  }
  float a[4] = {cb4.x, cb4.y, cb4.z, cb4.w};
  #pragma unroll
  for (int k = 0; k < 4; ++k) {
    if (l - 3 + k >= 0) {
      float4 xv = *(const float4*)(zx + (size_t)(r - 3 + k) * PROJ_PAD + D_INNER + d0);
      a[0] = fmaf(xv.x, tw[0][k], a[0]);
      a[1] = fmaf(xv.y, tw[1][k], a[1]);
      a[2] = fmaf(xv.z, tw[2][k], a[2]);
      a[3] = fmaf(xv.w, tw[3][k], a[3]);
    }
  }
  union { ushort4 u4; __hip_bfloat16 b[4]; } pk;
  #pragma unroll
  for (int i = 0; i < 4; ++i) pk.b[i] = __float2bfloat16(siluf(a[i]));
  *(ushort4*)(u_po + (size_t)r * D_INNER + d0) = pk.u4;
}

// ---------------------------------------------------------------- conv+silu+normalize for the 32 B/C channels
__global__ __launch_bounds__(256) void bcdt_k(const float* __restrict__ zx,
                                              const float* __restrict__ cw,
                                              const float* __restrict__ cb,
                                              float* __restrict__ bc) {
  int t = threadIdx.x;
  int r = blockIdx.x * 8 + (t >> 5);
  int ch = t & 31;
  int l = r & (SEQ - 1);
  int c = D_INNER + ch;
  float acc = cb[c];
  #pragma unroll
  for (int k = 0; k < 4; ++k) {
    int lp = l - 3 + k;
    if (lp >= 0)
      acc = fmaf(zx[(size_t)(r - 3 + k) * PROJ_PAD + 2 * D_INNER + ch], cw[c * 4 + k], acc);
  }
  acc = siluf(acc);
  float ss = acc * acc;
  ss += __shfl_xor(ss, 1);
  ss += __shfl_xor(ss, 2);
  ss += __shfl_xor(ss, 4);
  ss += __shfl_xor(ss, 8);
  bc[r * 32 + ch] = acc / (sqrtf(ss) + 1e-6f);
}

// ---------------------------------------------------------------- chunk transfer matrices
__global__ __launch_bounds__(256) void pk_k(const float* __restrict__ dtT,
                                            const float* __restrict__ A_log,
                                            float* __restrict__ Pm) {
  int bh = blockIdx.x;
  int h = bh & 31;
  int t = threadIdx.x;
  int ch = t >> 4, n = t & 15;
  float a = __expf(A_log[h * 16 + n]);
  const float* dtp = dtT + (size_t)h * ROWS + (size_t)(bh >> 5) * SEQ + ch * CH;
  float p00 = 1.f, p01 = 0.f, p10 = 0.f, p11 = 1.f;
  for (int l = 0; l < CH; ++l) {
    float dt = dtp[l];
    float s  = 1.0f / fmaf(dt * dt, a, 1.0f);
    float m00 = s;
    float m01 = -dt * a * s;
    float m10 = dt * s;
    float m11 = fmaf(-dt * a, m10, 1.0f);
    float q00 = fmaf(m00, p00, m01 * p10);
    float q01 = fmaf(m00, p01, m01 * p11);
    float q10 = fmaf(m10, p00, m11 * p10);
    float q11 = fmaf(m10, p01, m11 * p11);
    p00 = q00; p01 = q01; p10 = q10; p11 = q11;
  }
  float4 v = {p00, p01, p10, p11};
  *(float4*)&Pm[(((size_t)bh * NCH + ch) * 16 + n) * 4] = v;
}

// ---------------------------------------------------------------- propagate chunk-boundary states
__global__ __launch_bounds__(256) void prop_k(const float* __restrict__ Pm,
                                              const float* __restrict__ pend,
                                              float* __restrict__ sinit) {
  int gid = blockIdx.x * 256 + threadIdx.x;
  int n  = gid & 15;
  int d  = (gid >> 4) & 63;
  int bh = gid >> 10;
  float s0 = 0.f, s1 = 0.f;
  for (int c = 0; c < NCH; ++c) {
    size_t i2 = (((size_t)bh * NCH + c) * 64 + d) * 16 + n;
    *(float2*)&sinit[i2 * 2] = make_float2(s0, s1);
    float4 P  = *(const float4*)&Pm[(((size_t)bh * NCH + c) * 16 + n) * 4];
    float2 pe = *(const float2*)&pend[i2 * 2];
    float t0 = fmaf(P.x, s0, fmaf(P.y, s1, pe.x));
    float t1 = fmaf(P.z, s0, fmaf(P.w, s1, pe.y));
    s0 = t0; s1 = t1;
  }
}

// ---------------------------------------------------------------- chunked scan (u precomputed, f32x2 packed recurrence)
#define T_TILE 16
#define TPC (CH / T_TILE)
template<int PHASE>
__global__ __launch_bounds__(128) void scan_k(
    const float* __restrict__ zx, const float* __restrict__ bcb,
    const float* __restrict__ dtT, const float* __restrict__ A_log,
    const float* __restrict__ Dp, float* __restrict__ states,
    __hip_bfloat16* u_po)
{
  const int blk  = blockIdx.x;
  const int half = blk & 1;
  const int ch   = (blk >> 1) & 15;
  const int h    = (blk >> 5) & 31;
  const int b    = blk >> 10;
  const int bh   = b * 32 + h;
  const int tid  = threadIdx.x;
  const int wv   = tid >> 6;
  const int lane = tid & 63;
  const int d16  = lane & 15;
  const int ng   = lane >> 4;
  const int n0   = ng * 4;
  const int dwv  = wv * 16 + d16;            // d within block's 32
  const int dl   = half * 32 + dwv;          // d within head
  const int dbase = h * 64 + half * 32;      // global channel base of this block
  const size_t rowbase = (size_t)b * SEQ + (size_t)ch * CH;

  __shared__ __hip_bfloat16 dut[2][T_TILE][32];
  __shared__ float Btl[2][T_TILE][16];
  __shared__ float Ctl[PHASE == 3 ? 2 : 1][T_TILE][16];
  __shared__ float zt [PHASE == 3 ? 2 : 1][T_TILE][32];
  __shared__ float st [2][T_TILE][16];
  __shared__ float dtt[2][T_TILE];
  __shared__ float aexp[16];
  __shared__ float opart[PHASE == 3 ? T_TILE : 1][32][4];

  if (tid < 16) aexp[tid] = __expf(A_log[h * 16 + tid]);

  f32x2 A2[2];
  #pragma unroll
  for (int k = 0; k < 2; ++k) {
    A2[k][0] = __expf(A_log[h * 16 + n0 + 2 * k]);
    A2[k][1] = __expf(A_log[h * 16 + n0 + 2 * k + 1]);
  }
  const float Dh = Dp[h];

  auto stage = [&](int tile, int buf) {
    const size_t r0 = rowbase + (size_t)tile * T_TILE;
    if constexpr (PHASE == 3) {
      {   // z half-tile per wave (8 rows x 128B)
        int row = wv * 8 + (lane >> 3);
        const float* g = zx + (r0 + row) * PROJ_PAD + dbase + (lane & 7) * 4;
        float* l_ = &zt[buf][0][0] + wv * 256 + lane * 4;
        __builtin_amdgcn_global_load_lds((const __attribute__((address_space(1))) unsigned int*)g,
                                         (__attribute__((address_space(3))) unsigned int*)l_, 16, 0, 0);
      }
      if (wv == 0) {   // u tile (16 rows x 64B)
        const __hip_bfloat16* g = u_po + (r0 + (lane >> 2)) * D_INNER + dbase + (lane & 3) * 8;
        __hip_bfloat16* l_ = &dut[buf][0][0] + lane * 8;
        __builtin_amdgcn_global_load_lds((const __attribute__((address_space(1))) unsigned int*)g,
                                         (__attribute__((address_space(3))) unsigned int*)l_, 16, 0, 0);
      } else {          // B tile + C tile (16 rows x 64B each)
        const float* gB = bcb + (r0 + (lane >> 2)) * 32 + (lane & 3) * 4;
        float* lB = &Btl[buf][0][0] + lane * 4;
        __builtin_amdgcn_global_load_lds((const __attribute__((address_space(1))) unsigned int*)gB,
                                         (__attribute__((address_space(3))) unsigned int*)lB, 16, 0, 0);
        const float* gC = bcb + (r0 + (lane >> 2)) * 32 + 16 + (lane & 3) * 4;
        float* lC = &Ctl[buf][0][0] + lane * 4;
        __builtin_amdgcn_global_load_lds((const __attribute__((address_space(1))) unsigned int*)gC,
                                         (__attribute__((address_space(3))) unsigned int*)lC, 16, 0, 0);
      }
    } else {
      if (wv == 0) {
        const __hip_bfloat16* g = u_po + (r0 + (lane >> 2)) * D_INNER + dbase + (lane & 3) * 8;
        __hip_bfloat16* l_ = &dut[buf][0][0] + lane * 8;
        __builtin_amdgcn_global_load_lds((const __attribute__((address_space(1))) unsigned int*)g,
                                         (__attribute__((address_space(3))) unsigned int*)l_, 16, 0, 0);
      } else {
        const float* gB = bcb + (r0 + (lane >> 2)) * 32 + (lane & 3) * 4;
        float* lB = &Btl[buf][0][0] + lane * 4;
        __builtin_amdgcn_global_load_lds((const __attribute__((address_space(1))) unsigned int*)gB,
                                         (__attribute__((address_space(3))) unsigned int*)lB, 16, 0, 0);
      }
    }
  };

  auto sprep = [&](int buf, float dtn) {
    #pragma unroll
    for (int i = 0; i < 2; ++i) {
      int idx = tid + 128 * i;
      int row = idx >> 4, n = idx & 15;
      float dv = __shfl(dtn, row);
      float a  = aexp[n];
      st[buf][row][n] = 1.0f / fmaf(dv * dv, a, 1.0f);
    }
  };

  stage(0, 0);
  float dtn = 0.f;
  if (lane < 16) dtn = dtT[(size_t)h * ROWS + rowbase + lane];
  __syncthreads();
  if (tid < 16) dtt[0][tid] = dtn;
  sprep(0, dtn);
  __syncthreads();

  f32x2 w2[2], ys2[2];
  if constexpr (PHASE == 1) {
    #pragma unroll
    for (int k = 0; k < 2; ++k) { w2[k] = (f32x2){0.f, 0.f}; ys2[k] = (f32x2){0.f, 0.f}; }
  } else {
    #pragma unroll
    for (int k = 0; k < 2; ++k)
      #pragma unroll
      for (int j = 0; j < 2; ++j) {
        size_t i2 = (((size_t)bh * NCH + ch) * 64 + dl) * 16 + (n0 + 2 * k + j);
        float2 s = *(const float2*)&states[i2 * 2];
        w2[k][j] = s.x; ys2[k][j] = s.y;
      }
  }
  int cur = 0;

  for (int t = 0; t < TPC; ++t) {
    if (t + 1 < TPC) {
      stage(t + 1, cur ^ 1);
      if (lane < 16) dtn = dtT[(size_t)h * ROWS + rowbase + (size_t)(t + 1) * T_TILE + lane];
    }
    #pragma unroll 4
    for (int l = 0; l < T_TILE; ++l) {
      float uv  = __bfloat162float(dut[cur][l][dwv]);
      float dtv = dtt[cur][l];
      f32x4 Sv4 = *(const f32x4*)&st [cur][l][n0];
      f32x4 Bv4 = *(const f32x4*)&Btl[cur][l][n0];
      float du = dtv * uv;
      f32x2 S2[2] = { {Sv4[0], Sv4[1]}, {Sv4[2], Sv4[3]} };
      f32x2 B2[2] = { {Bv4[0], Bv4[1]}, {Bv4[2], Bv4[3]} };
      if constexpr (PHASE == 3) {
        f32x4 Cv4 = *(const f32x4*)&Ctl[cur][l][n0];
        f32x2 C2[2] = { {Cv4[0], Cv4[1]}, {Cv4[2], Cv4[3]} };
        f32x2 o2 = {0.f, 0.f};
        #pragma unroll
        for (int k = 0; k < 2; ++k) {
          f32x2 dtA = dtv * A2[k];
          f32x2 tmp = w2[k] - dtA * ys2[k];
          tmp = tmp + du * B2[k];
          w2[k] = S2[k] * tmp;
          ys2[k] = ys2[k] + dtv * w2[k];
          o2 = o2 + ys2[k] * C2[k];
        }
        float o = o2[0] + o2[1];
        float ofin = (ng == 0) ? fmaf(Dh, uv, o) : o;
        opart[l][dwv][ng] = ofin;
      } else {
        #pragma unroll
        for (int k = 0; k < 2; ++k) {
          f32x2 dtA = dtv * A2[k];
          f32x2 tmp = w2[k] - dtA * ys2[k];
          tmp = tmp + du * B2[k];
          w2[k] = S2[k] * tmp;
          ys2[k] = ys2[k] + dtv * w2[k];
        }
      }
    }
    if constexpr (PHASE == 3) {
      #pragma unroll
      for (int i = 0; i < 4; ++i) {
        int l  = (lane >> 4) + 4 * i;
        int dd = wv * 16 + d16;
        f32x4 op = *(const f32x4*)&opart[l][dd][0];
        float zv = zt[cur][l][dd];
        float yv = (op[0] + op[1]) + (op[2] + op[3]);
        u_po[(rowbase + (size_t)t * T_TILE + l) * D_INNER + dbase + dd] =
            __float2bfloat16(yv * siluf(zv));
      }
    }
    __syncthreads();
    if (t + 1 < TPC) {
      if (tid < 16) dtt[cur ^ 1][tid] = dtn;
      sprep(cur ^ 1, dtn);
      __syncthreads();
    }
    cur ^= 1;
  }

  if constexpr (PHASE == 1) {
    #pragma unroll
    for (int k = 0; k < 2; ++k)
      #pragma unroll
      for (int j = 0; j < 2; ++j) {
        size_t i2 = (((size_t)bh * NCH + ch) * 64 + dl) * 16 + (n0 + 2 * k + j);
        *(float2*)&states[i2 * 2] = make_float2(w2[k][j], ys2[k][j]);
      }
  }
}

// ---------------------------------------------------------------- launch
extern "C" void kernel_launch(void* const* d_in, const int* in_sizes, int n_in,
                              void* d_out, int out_size, void* d_ws, size_t ws_size,
                              hipStream_t stream) {
  const float* x     = (const float*)d_in[0];
  const float* n1w   = (const float*)d_in[1];
  const float* wi    = (const float*)d_in[2];
  const float* cw    = (const float*)d_in[3];
  const float* cb    = (const float*)d_in[4];
  const float* A_log = (const float*)d_in[5];
  const float* dtb   = (const float*)d_in[6];
  const float* Dp    = (const float*)d_in[7];
  const float* wo    = (const float*)d_in[8];
  const float* n2w   = (const float*)d_in[9];
  const float* wg    = (const float*)d_in[10];
  const float* wu    = (const float*)d_in[11];
  const float* wd    = (const float*)d_in[12];
  float* out = (float*)d_out;

  char* p = (char*)d_ws;
  auto take = [&](size_t b) { char* q = p; p += (b + 255) & ~(size_t)255; return q; };
  __hip_bfloat16* wbi  = (__hip_bfloat16*)take((size_t)PROJ_PAD * D_MODEL * 2);
  __hip_bfloat16* wbo  = (__hip_bfloat16*)take((size_t)D_MODEL * D_INNER * 2);
  __hip_bfloat16* wbg  = (__hip_bfloat16*)take((size_t)FFN_DIM * D_MODEL * 2);
  __hip_bfloat16* wbu  = (__hip_bfloat16*)take((size_t)FFN_DIM * D_MODEL * 2);
  __hip_bfloat16* wbd  = (__hip_bfloat16*)take((size_t)D_MODEL * FFN_DIM * 2);
  __hip_bfloat16* h0b  = (__hip_bfloat16*)take((size_t)ROWS * D_MODEL * 2);
  float*          zx   = (float*)take((size_t)ROWS * PROJ_PAD * 4);
  float*          bcb  = (float*)take((size_t)ROWS * 32 * 4);
  float*          dtT  = (float*)take((size_t)ROWS * 32 * 4);
  __hip_bfloat16* po   = (__hip_bfloat16*)take((size_t)ROWS * D_INNER * 2);   // u carrier, then scan output
  float*          pend = (float*)take((size_t)128 * NCH * 64 * 16 * 2 * 4);
  float*          sini = (float*)take((size_t)128 * NCH * 64 * 16 * 2 * 4);
  float*          Pm   = (float*)take((size_t)128 * NCH * 16 * 4 * 4);
  float*          h0f  = (float*)zx;
  float*          h    = (float*)zx;
  __hip_bfloat16* gact = (__hip_bfloat16*)((char*)zx + 33554432);

  hipFuncSetAttribute(reinterpret_cast<const void*>(&gemm8<0>),  hipFuncAttributeMaxDynamicSharedMemorySize, 131072);
  hipFuncSetAttribute(reinterpret_cast<const void*>(&gemm8<2>),  hipFuncAttributeMaxDynamicSharedMemorySize, 131072);
  hipFuncSetAttribute(reinterpret_cast<const void*>(&gemm8<3>),  hipFuncAttributeMaxDynamicSharedMemorySize, 131072);
  hipFuncSetAttribute(reinterpret_cast<const void*>(&gemm8B<1>), hipFuncAttributeMaxDynamicSharedMemorySize, 131072);

  // weight conversions
  cvt_pad_k<<<(PROJ_PAD * D_MODEL + 255) / 256, 256, 0, stream>>>(wi, wbi);
  cvt_k<<<(D_MODEL * D_INNER + 255) / 256, 256, 0, stream>>>(wo, wbo, D_MODEL * D_INNER);
  cvt_k<<<(FFN_DIM * D_MODEL + 255) / 256, 256, 0, stream>>>(wg, wbg, FFN_DIM * D_MODEL);
  cvt_k<<<(FFN_DIM * D_MODEL + 255) / 256, 256, 0, stream>>>(wu, wbu, FFN_DIM * D_MODEL);
  cvt_k<<<(FFN_DIM * D_MODEL + 255) / 256, 256, 0, stream>>>(wd, wbd, FFN_DIM * D_MODEL);

  // mixer
  rmsnorm_k<<<ROWS, 256, 0, stream>>>(x, n1w, h0b, h0f);
  dtproj_k<<<ROWS / 4, 256, 0, stream>>>(h0f, wi, dtb, dtT);
  gemm8<0><<<(ROWS / 256) * (PROJ_PAD / 256), 512, 131072, stream>>>(h0b, wbi, zx, nullptr, nullptr,
                                                                     ROWS, PROJ_PAD, D_MODEL);
  duconv_k<<<ROWS * 512 / 256, 256, 0, stream>>>(zx, cw, cb, po);
  bcdt_k<<<ROWS / 8, 256, 0, stream>>>(zx, cw, cb, bcb);
  pk_k<<<BATCH * N_HEADS, 256, 0, stream>>>(dtT, A_log, Pm);
  scan_k<1><<<BATCH * N_HEADS * NCH * 2, 128, 0, stream>>>(zx, bcb, dtT, A_log, Dp, pend, po);
  prop_k<<<BATCH * N_HEADS * 64 * 16 / 256, 256, 0, stream>>>(Pm, pend, sini);
  scan_k<3><<<BATCH * N_HEADS * NCH * 2, 128, 0, stream>>>(zx, bcb, dtT, A_log, Dp, sini, po);
  gemm8B<1><<<(ROWS / 256) * (D_MODEL / 128), 512, 131072, stream>>>(po, wbo, h, nullptr, x,
                                                                     ROWS, D_MODEL, D_INNER);
  // FFN
  rmsnorm_k<<<ROWS, 256, 0, stream>>>(h, n2w, h0b, nullptr);
  gemm8<2><<<(ROWS / 256) * (FFN_DIM / 256), 512, 131072, stream>>>(h0b, wbg, nullptr, gact, nullptr,
                                                                    ROWS, FFN_DIM, D_MODEL);
  gemm8<3><<<(ROWS / 256) * (FFN_DIM / 256), 512, 131072, stream>>>(h0b, wbu, nullptr, gact, nullptr,
                                                                    ROWS, FFN_DIM, D_MODEL);
  gemm8B<1><<<(ROWS / 256) * (D_MODEL / 128), 512, 131072, stream>>>(gact, wbd, out, nullptr, h,
                                                                     ROWS, D_MODEL, FFN_DIM);
}

// Round 11
// 648.841 us; speedup vs baseline: 2.5944x; 1.0852x over previous
//
#include <hip/hip_runtime.h>
#include <hip/hip_bf16.h>

#define D_MODEL   1024
#define D_STATE   16
#define D_HEAD    64
#define D_CONV    4
#define FFN_DIM   2816
#define D_INNER   2048
#define N_HEADS   32
#define BATCH     4
#define SEQ       2048
#define ROWS      (BATCH*SEQ)     // 8192
#define PROJ_DIM  4160
#define PROJ_PAD  4352            // 17 * 256
#define CONV_CH   2080
#define CH        128             // scan chunk length
#define NCH       (SEQ/CH)        // 16 chunks
#define GU_N      5632            // 2*FFN_DIM interleaved (22 tiles of 256)

typedef __bf16 bf16x8 __attribute__((ext_vector_type(8)));
typedef float  f32x4  __attribute__((ext_vector_type(4)));
typedef float  f32x2  __attribute__((ext_vector_type(2)));

__device__ __forceinline__ float siluf(float x) { return x / (1.0f + __expf(-x)); }

#define SBAR() do { asm volatile("" ::: "memory"); __builtin_amdgcn_s_barrier(); asm volatile("" ::: "memory"); } while (0)
#define LGKM0() asm volatile("s_waitcnt lgkmcnt(0)" ::: "memory")
#define VMCNT4() asm volatile("s_waitcnt vmcnt(4)" ::: "memory")
#define VMCNT2() asm volatile("s_waitcnt vmcnt(2)" ::: "memory")
#define VMCNT0() asm volatile("s_waitcnt vmcnt(0)" ::: "memory")

// ---------------------------------------------------------------- converts
__global__ void cvt_k(const float* __restrict__ src, __hip_bfloat16* __restrict__ dst, int n) {
  int i = blockIdx.x * blockDim.x + threadIdx.x;
  if (i < n) dst[i] = __float2bfloat16(src[i]);
}

__global__ void cvt_pad_k(const float* __restrict__ src, __hip_bfloat16* __restrict__ dst) {
  int i = blockIdx.x * blockDim.x + threadIdx.x;
  if (i >= PROJ_PAD * D_MODEL) return;
  int row = i >> 10;
  dst[i] = (row < PROJ_DIM) ? __float2bfloat16(src[i]) : __float2bfloat16(0.0f);
}

// interleave gate/up weights: tile t rows [0,128)=gate cols t*128.., [128,256)=up cols t*128..
__global__ void cvt_gu_k(const float* __restrict__ wg, const float* __restrict__ wu,
                         __hip_bfloat16* __restrict__ dst) {
  int i = blockIdx.x * blockDim.x + threadIdx.x;
  if (i >= GU_N * D_MODEL) return;
  int r = i >> 10, c = i & 1023;
  int tile = r >> 8, rr = r & 255;
  const float* src = (rr < 128)
      ? wg + (size_t)(tile * 128 + rr) * D_MODEL + c
      : wu + (size_t)(tile * 128 + (rr - 128)) * D_MODEL + c;
  dst[i] = __float2bfloat16(*src);
}

// ---------------------------------------------------------------- rmsnorm
__global__ __launch_bounds__(256) void rmsnorm_k(const float* __restrict__ x,
                                                 const float* __restrict__ w,
                                                 __hip_bfloat16* __restrict__ out,
                                                 float* __restrict__ outf) {
  int row = blockIdx.x;
  int t = threadIdx.x;
  const float* xr = x + (size_t)row * D_MODEL;
  float4 v = ((const float4*)xr)[t];
  float ss = v.x*v.x + v.y*v.y + v.z*v.z + v.w*v.w;
  #pragma unroll
  for (int o = 32; o > 0; o >>= 1) ss += __shfl_xor(ss, o);
  __shared__ float red[4];
  if ((t & 63) == 0) red[t >> 6] = ss;
  __syncthreads();
  ss = red[0] + red[1] + red[2] + red[3];
  float scale = rsqrtf(ss * (1.0f / D_MODEL) + 1e-6f);
  float4 wv = ((const float4*)w)[t];
  float4 r;
  r.x = v.x * scale * wv.x; r.y = v.y * scale * wv.y;
  r.z = v.z * scale * wv.z; r.w = v.w * scale * wv.w;
  __hip_bfloat16* orow = out + (size_t)row * D_MODEL + t * 4;
  orow[0] = __float2bfloat16(r.x);
  orow[1] = __float2bfloat16(r.y);
  orow[2] = __float2bfloat16(r.z);
  orow[3] = __float2bfloat16(r.w);
  if (outf) ((float4*)(outf + (size_t)row * D_MODEL))[t] = r;
}

// ---------------------------------------------------------------- dt projection (f32, block-per-4-rows)
__global__ __launch_bounds__(256) void dtproj_k(const float* __restrict__ xn,
                                                const float* __restrict__ wi,
                                                const float* __restrict__ dtb,
                                                float* __restrict__ dtT) {
  const int r0 = blockIdx.x * 4;
  const int t  = threadIdx.x;
  const int hh  = t >> 3;
  const int seg = t & 7;

  __shared__ float xs[4][D_MODEL];
  #pragma unroll
  for (int i = 0; i < 4; ++i)
    ((float4*)&xs[i][0])[t] = ((const float4*)(xn + (size_t)(r0 + i) * D_MODEL))[t];
  __syncthreads();

  const float4* w4 = (const float4*)(wi + (size_t)(2 * D_INNER + 2 * D_STATE + hh) * D_MODEL) + seg * 32;
  const float4* x0 = (const float4*)&xs[0][0] + seg * 32;
  const float4* x1 = (const float4*)&xs[1][0] + seg * 32;
  const float4* x2 = (const float4*)&xs[2][0] + seg * 32;
  const float4* x3 = (const float4*)&xs[3][0] + seg * 32;
  float a0 = 0.f, a1 = 0.f, a2 = 0.f, a3 = 0.f;
  #pragma unroll 8
  for (int k = 0; k < 32; ++k) {
    float4 wv = w4[k];
    float4 v0 = x0[k], v1 = x1[k], v2 = x2[k], v3 = x3[k];
    a0 = fmaf(wv.x, v0.x, fmaf(wv.y, v0.y, fmaf(wv.z, v0.z, fmaf(wv.w, v0.w, a0))));
    a1 = fmaf(wv.x, v1.x, fmaf(wv.y, v1.y, fmaf(wv.z, v1.z, fmaf(wv.w, v1.w, a1))));
    a2 = fmaf(wv.x, v2.x, fmaf(wv.y, v2.y, fmaf(wv.z, v2.z, fmaf(wv.w, v2.w, a2))));
    a3 = fmaf(wv.x, v3.x, fmaf(wv.y, v3.y, fmaf(wv.z, v3.z, fmaf(wv.w, v3.w, a3))));
  }
  #pragma unroll
  for (int m = 1; m < 8; m <<= 1) {
    a0 += __shfl_xor(a0, m);
    a1 += __shfl_xor(a1, m);
    a2 += __shfl_xor(a2, m);
    a3 += __shfl_xor(a3, m);
  }
  if (seg == 0) {
    float bias = dtb[hh];
    float v[4] = {a0, a1, a2, a3};
    #pragma unroll
    for (int i = 0; i < 4; ++i) {
      float xv = v[i] + bias;
      dtT[(size_t)hh * ROWS + r0 + i] = (xv > 20.f) ? xv : log1pf(__expf(xv));
    }
  }
}

// ---------------------------------------------------------------- 256x256 8-phase GEMM
// EPI: 0 f32 store; 1 f32 + add_src; 4 fused gate/up: interleaved wgu, LDS exchange,
//      output = bf16(silu(g)*u) to Cb with row stride FFN_DIM.
template<int EPI>
__global__ __launch_bounds__(512, 2) void gemm8(
    const __hip_bfloat16* __restrict__ A,
    const __hip_bfloat16* __restrict__ Bw,
    float* __restrict__ Cf,
    __hip_bfloat16* __restrict__ Cb,
    const float* __restrict__ add_src,
    int M, int N, int K)
{
  extern __shared__ char lds[];
  const int nwg = (M >> 8) * (N >> 8);
  int bid = blockIdx.x;
  bid = (bid & 7) * (nwg >> 3) + (bid >> 3);
  const int ntn = N >> 8;
  const int bm = (bid / ntn) << 8;
  const int bn = (bid % ntn) << 8;

  const int tid  = threadIdx.x;
  const int wid  = tid >> 6;
  const int lane = tid & 63;
  const int wm = wid >> 2;
  const int wn = wid & 3;
  const int r16 = lane & 15;
  const int kg  = lane >> 4;

  const int rb = ((r16 << 6) + (kg << 4)) ^ ((r16 & 8) << 2);

  const int s_sub = tid >> 6;
  const int s_w   = (tid & 63) << 4;
  const int s_wp  = s_w ^ ((((s_w) >> 9) & 1) << 5);
  const int s_row = ((s_sub >> 1) << 4) + (s_wp >> 6);
  const int s_col = ((s_sub & 1) << 5) + ((s_wp >> 1) & 31);

  auto stage = [&](int buf, int mat, int half, int c, int kt) {
    const __hip_bfloat16* src = (mat == 0)
        ? A  + (size_t)(bm + half * 128 + c * 64 + s_row) * K + kt * 64 + s_col
        : Bw + (size_t)(bn + half * 128 + c * 64 + s_row) * K + kt * 64 + s_col;
    char* dst = lds + buf * 65536 + mat * 32768 + half * 16384 + c * 8192 + tid * 16;
    __builtin_amdgcn_global_load_lds((const __attribute__((address_space(1))) unsigned int*)src,
                                     (__attribute__((address_space(3))) unsigned int*)dst,
                                     16, 0, 0);
  };

  f32x4 acc[8][4] = {};
  bf16x8 af[4][2], bfr[4][2];

  const int NT = K >> 6;
  stage(0,0,0,0,0); stage(0,0,0,1,0); stage(0,0,1,0,0); stage(0,0,1,1,0);
  stage(0,1,0,0,0); stage(0,1,0,1,0); stage(0,1,1,0,0); stage(0,1,1,1,0);
  __syncthreads();

  for (int kt = 0; kt < NT; ++kt) {
    const int buf = kt & 1, nbuf = buf ^ 1;
    const bool st = (kt + 1 < NT);
    const char* Ab = lds + buf * 65536 + wm * 16384;
    const char* Bb = lds + buf * 65536 + 32768 + (wn >> 1) * 16384 + (wn & 1) * 8192;

    #pragma unroll
    for (int mi2 = 0; mi2 < 4; ++mi2)
      #pragma unroll
      for (int kk = 0; kk < 2; ++kk)
        af[mi2][kk] = *(const bf16x8*)(Ab + (mi2 * 2 + kk) * 1024 + rb);
    #pragma unroll
    for (int ni = 0; ni < 2; ++ni)
      #pragma unroll
      for (int kk = 0; kk < 2; ++kk)
        bfr[ni][kk] = *(const bf16x8*)(Bb + (ni * 2 + kk) * 1024 + rb);
    if (st) { stage(nbuf,1,0,0,kt+1); stage(nbuf,1,0,1,kt+1); }
    SBAR(); LGKM0();
    __builtin_amdgcn_s_setprio(1);
    #pragma unroll
    for (int mi2 = 0; mi2 < 4; ++mi2)
      #pragma unroll
      for (int ni = 0; ni < 2; ++ni)
        #pragma unroll
        for (int kk = 0; kk < 2; ++kk)
          acc[mi2][ni] = __builtin_amdgcn_mfma_f32_16x16x32_bf16(af[mi2][kk], bfr[ni][kk], acc[mi2][ni], 0, 0, 0);
    __builtin_amdgcn_s_setprio(0);
    SBAR();

    #pragma unroll
    for (int ni = 2; ni < 4; ++ni)
      #pragma unroll
      for (int kk = 0; kk < 2; ++kk)
        bfr[ni][kk] = *(const bf16x8*)(Bb + (ni * 2 + kk) * 1024 + rb);
    if (st) { stage(nbuf,1,1,0,kt+1); stage(nbuf,1,1,1,kt+1); }
    SBAR(); LGKM0();
    __builtin_amdgcn_s_setprio(1);
    #pragma unroll
    for (int mi2 = 0; mi2 < 4; ++mi2)
      #pragma unroll
      for (int ni = 2; ni < 4; ++ni)
        #pragma unroll
        for (int kk = 0; kk < 2; ++kk)
          acc[mi2][ni] = __builtin_amdgcn_mfma_f32_16x16x32_bf16(af[mi2][kk], bfr[ni][kk], acc[mi2][ni], 0, 0, 0);
    __builtin_amdgcn_s_setprio(0);
    if (st) { VMCNT4(); } else { VMCNT0(); }
    SBAR();

    #pragma unroll
    for (int mi2 = 0; mi2 < 4; ++mi2)
      #pragma unroll
      for (int kk = 0; kk < 2; ++kk)
        af[mi2][kk] = *(const bf16x8*)(Ab + ((4 + mi2) * 2 + kk) * 1024 + rb);
    if (st) { stage(nbuf,0,0,0,kt+1); stage(nbuf,0,1,0,kt+1); }
    SBAR(); LGKM0();
    __builtin_amdgcn_s_setprio(1);
    #pragma unroll
    for (int mi2 = 0; mi2 < 4; ++mi2)
      #pragma unroll
      for (int ni = 0; ni < 2; ++ni)
        #pragma unroll
        for (int kk = 0; kk < 2; ++kk)
          acc[4 + mi2][ni] = __builtin_amdgcn_mfma_f32_16x16x32_bf16(af[mi2][kk], bfr[ni][kk], acc[4 + mi2][ni], 0, 0, 0);
    __builtin_amdgcn_s_setprio(0);
    SBAR();

    if (st) { stage(nbuf,0,0,1,kt+1); stage(nbuf,0,1,1,kt+1); }
    SBAR(); LGKM0();
    __builtin_amdgcn_s_setprio(1);
    #pragma unroll
    for (int mi2 = 0; mi2 < 4; ++mi2)
      #pragma unroll
      for (int ni = 2; ni < 4; ++ni)
        #pragma unroll
        for (int kk = 0; kk < 2; ++kk)
          acc[4 + mi2][ni] = __builtin_amdgcn_mfma_f32_16x16x32_bf16(af[mi2][kk], bfr[ni][kk], acc[4 + mi2][ni], 0, 0, 0);
    __builtin_amdgcn_s_setprio(0);
    VMCNT2();
    SBAR();
  }

  if constexpr (EPI == 4) {
    // fused gate/up epilogue: wn<2 hold gate (cols 0..127 of tile), wn>=2 hold up.
    // Exchange silu(gate) through LDS (dead after K-loop), 2-way-max bank swizzle.
    float* xch = (float*)lds;                 // [wm][128][128] f32 = 2*64KB
    __syncthreads();
    if (wn < 2) {
      #pragma unroll
      for (int mi = 0; mi < 8; ++mi)
        #pragma unroll
        for (int ni = 0; ni < 4; ++ni)
          #pragma unroll
          for (int j = 0; j < 4; ++j) {
            int row = mi * 16 + kg * 4 + j;
            int col = wn * 64 + ni * 16 + r16;
            int cc = col ^ (((row >> 2) & 1) << 4);
            xch[wm * 16384 + row * 128 + cc] = siluf(acc[mi][ni][j]);
          }
    }
    __syncthreads();
    if (wn >= 2) {
      #pragma unroll
      for (int mi = 0; mi < 8; ++mi)
        #pragma unroll
        for (int ni = 0; ni < 4; ++ni)
          #pragma unroll
          for (int j = 0; j < 4; ++j) {
            int row = mi * 16 + kg * 4 + j;
            int col = (wn - 2) * 64 + ni * 16 + r16;
            int cc = col ^ (((row >> 2) & 1) << 4);
            float g = xch[wm * 16384 + row * 128 + cc];
            int r = bm + wm * 128 + row;
            int tc = (bn >> 1) + col;         // true FFN column
            Cb[(size_t)r * FFN_DIM + tc] = __float2bfloat16(g * acc[mi][ni][j]);
          }
    }
  } else {
    #pragma unroll
    for (int mi = 0; mi < 8; ++mi) {
      #pragma unroll
      for (int ni = 0; ni < 4; ++ni) {
        #pragma unroll
        for (int j = 0; j < 4; ++j) {
          int r = bm + wm * 128 + mi * 16 + kg * 4 + j;
          int c = bn + wn * 64 + ni * 16 + r16;
          size_t idx = (size_t)r * N + c;
          float v = acc[mi][ni][j];
          if constexpr (EPI == 0) {
            Cf[idx] = v;
          } else if constexpr (EPI == 1) {
            Cf[idx] = v + add_src[idx];
          }
        }
      }
    }
  }
}

// ---------------------------------------------------------------- 256x128 8-phase GEMM (full grid at N=1024)
template<int EPI>
__global__ __launch_bounds__(512, 2) void gemm8B(
    const __hip_bfloat16* __restrict__ A,
    const __hip_bfloat16* __restrict__ Bw,
    float* __restrict__ Cf,
    __hip_bfloat16* __restrict__ Cb,
    const float* __restrict__ add_src,
    int M, int N, int K)
{
  extern __shared__ char lds[];
  const int nwg = (M >> 8) * (N >> 7);
  int bid = blockIdx.x;
  bid = (bid & 7) * (nwg >> 3) + (bid >> 3);
  const int ntn = N >> 7;
  const int bm = (bid / ntn) << 8;
  const int bn = (bid % ntn) << 7;

  const int tid  = threadIdx.x;
  const int wid  = tid >> 6;
  const int lane = tid & 63;
  const int wm = wid >> 2;
  const int wn = wid & 3;
  const int r16 = lane & 15;
  const int kg  = lane >> 4;

  const int rb = ((r16 << 6) + (kg << 4)) ^ ((r16 & 8) << 2);

  const int s_sub = tid >> 6;
  const int s_w   = (tid & 63) << 4;
  const int s_wp  = s_w ^ ((((s_w) >> 9) & 1) << 5);
  const int s_row = ((s_sub >> 1) << 4) + (s_wp >> 6);
  const int s_col = ((s_sub & 1) << 5) + ((s_wp >> 1) & 31);

  auto stageA = [&](int buf, int half, int c, int kt) {
    const __hip_bfloat16* src = A + (size_t)(bm + half * 128 + c * 64 + s_row) * K + kt * 64 + s_col;
    char* dst = lds + buf * 65536 + half * 16384 + c * 8192 + tid * 16;
    __builtin_amdgcn_global_load_lds((const __attribute__((address_space(1))) unsigned int*)src,
                                     (__attribute__((address_space(3))) unsigned int*)dst,
                                     16, 0, 0);
  };
  auto stageB = [&](int buf, int c, int kt) {
    const __hip_bfloat16* src = Bw + (size_t)(bn + c * 64 + s_row) * K + kt * 64 + s_col;
    char* dst = lds + buf * 65536 + 32768 + c * 8192 + tid * 16;
    __builtin_amdgcn_global_load_lds((const __attribute__((address_space(1))) unsigned int*)src,
                                     (__attribute__((address_space(3))) unsigned int*)dst,
                                     16, 0, 0);
  };

  f32x4 acc[8][2] = {};
  bf16x8 af[4][2], bfr[2][2];

  const int NT = K >> 6;
  stageB(0,0,0); stageB(0,1,0);
  stageA(0,0,0,0); stageA(0,1,0,0); stageA(0,0,1,0); stageA(0,1,1,0);
  __syncthreads();

  for (int kt = 0; kt < NT; ++kt) {
    const int buf = kt & 1, nbuf = buf ^ 1;
    const bool st = (kt + 1 < NT);
    const char* Ab = lds + buf * 65536 + wm * 16384;
    const char* Bb = lds + buf * 65536 + 32768 + (wn >> 1) * 8192 + (wn & 1) * 4096;

    #pragma unroll
    for (int mi2 = 0; mi2 < 4; ++mi2)
      #pragma unroll
      for (int kk = 0; kk < 2; ++kk)
        af[mi2][kk] = *(const bf16x8*)(Ab + (mi2 * 2 + kk) * 1024 + rb);
    #pragma unroll
    for (int ni = 0; ni < 2; ++ni)
      #pragma unroll
      for (int kk = 0; kk < 2; ++kk)
        bfr[ni][kk] = *(const bf16x8*)(Bb + (ni * 2 + kk) * 1024 + rb);
    if (st) { stageB(nbuf,0,kt+1); stageB(nbuf,1,kt+1); stageA(nbuf,0,0,kt+1); stageA(nbuf,1,0,kt+1); }
    SBAR(); LGKM0();
    __builtin_amdgcn_s_setprio(1);
    #pragma unroll
    for (int mi2 = 0; mi2 < 4; ++mi2)
      #pragma unroll
      for (int ni = 0; ni < 2; ++ni)
        #pragma unroll
        for (int kk = 0; kk < 2; ++kk)
          acc[mi2][ni] = __builtin_amdgcn_mfma_f32_16x16x32_bf16(af[mi2][kk], bfr[ni][kk], acc[mi2][ni], 0, 0, 0);
    __builtin_amdgcn_s_setprio(0);
    if (st) { VMCNT4(); } else { VMCNT0(); }
    SBAR();

    #pragma unroll
    for (int mi2 = 0; mi2 < 4; ++mi2)
      #pragma unroll
      for (int kk = 0; kk < 2; ++kk)
        af[mi2][kk] = *(const bf16x8*)(Ab + ((4 + mi2) * 2 + kk) * 1024 + rb);
    if (st) { stageA(nbuf,0,1,kt+1); stageA(nbuf,1,1,kt+1); }
    SBAR(); LGKM0();
    __builtin_amdgcn_s_setprio(1);
    #pragma unroll
    for (int mi2 = 0; mi2 < 4; ++mi2)
      #pragma unroll
      for (int ni = 0; ni < 2; ++ni)
        #pragma unroll
        for (int kk = 0; kk < 2; ++kk)
          acc[4 + mi2][ni] = __builtin_amdgcn_mfma_f32_16x16x32_bf16(af[mi2][kk], bfr[ni][kk], acc[4 + mi2][ni], 0, 0, 0);
    __builtin_amdgcn_s_setprio(0);
    VMCNT2();
    SBAR();
  }

  #pragma unroll
  for (int mi = 0; mi < 8; ++mi) {
    #pragma unroll
    for (int ni = 0; ni < 2; ++ni) {
      #pragma unroll
      for (int j = 0; j < 4; ++j) {
        int r = bm + wm * 128 + mi * 16 + kg * 4 + j;
        int c = bn + wn * 32 + ni * 16 + r16;
        size_t idx = (size_t)r * N + c;
        float v = acc[mi][ni][j];
        if constexpr (EPI == 0) {
          Cf[idx] = v;
        } else if constexpr (EPI == 1) {
          Cf[idx] = v + add_src[idx];
        }
      }
    }
  }
}

// ---------------------------------------------------------------- u = silu(depthwise conv(x)), bf16 into po buffer
__global__ __launch_bounds__(256) void duconv_k(const float* __restrict__ zx,
                                                const float* __restrict__ cw,
                                                const float* __restrict__ cb,
                                                __hip_bfloat16* __restrict__ u_po) {
  int idx = blockIdx.x * 256 + threadIdx.x;
  int q = idx & 511;
  int r = idx >> 9;
  int d0 = q << 2;
  int l = r & (SEQ - 1);
  float4 cb4 = ((const float4*)cb)[q];
  float tw[4][4];
  #pragma unroll
  for (int i = 0; i < 4; ++i) {
    float4 t = ((const float4*)cw)[d0 + i];
    tw[i][0] = t.x; tw[i][1] = t.y; tw[i][2] = t.z; tw[i][3] = t.w;
  }
  float a[4] = {cb4.x, cb4.y, cb4.z, cb4.w};
  #pragma unroll
  for (int k = 0; k < 4; ++k) {
    if (l - 3 + k >= 0) {
      float4 xv = *(const float4*)(zx + (size_t)(r - 3 + k) * PROJ_PAD + D_INNER + d0);
      a[0] = fmaf(xv.x, tw[0][k], a[0]);
      a[1] = fmaf(xv.y, tw[1][k], a[1]);
      a[2] = fmaf(xv.z, tw[2][k], a[2]);
      a[3] = fmaf(xv.w, tw[3][k], a[3]);
    }
  }
  union { ushort4 u4; __hip_bfloat16 b[4]; } pk;
  #pragma unroll
  for (int i = 0; i < 4; ++i) pk.b[i] = __float2bfloat16(siluf(a[i]));
  *(ushort4*)(u_po + (size_t)r * D_INNER + d0) = pk.u4;
}

// ---------------------------------------------------------------- conv+silu+normalize for the 32 B/C channels
__global__ __launch_bounds__(256) void bcdt_k(const float* __restrict__ zx,
                                              const float* __restrict__ cw,
                                              const float* __restrict__ cb,
                                              float* __restrict__ bc) {
  int t = threadIdx.x;
  int r = blockIdx.x * 8 + (t >> 5);
  int ch = t & 31;
  int l = r & (SEQ - 1);
  int c = D_INNER + ch;
  float acc = cb[c];
  #pragma unroll
  for (int k = 0; k < 4; ++k) {
    int lp = l - 3 + k;
    if (lp >= 0)
      acc = fmaf(zx[(size_t)(r - 3 + k) * PROJ_PAD + 2 * D_INNER + ch], cw[c * 4 + k], acc);
  }
  acc = siluf(acc);
  float ss = acc * acc;
  ss += __shfl_xor(ss, 1);
  ss += __shfl_xor(ss, 2);
  ss += __shfl_xor(ss, 4);
  ss += __shfl_xor(ss, 8);
  bc[r * 32 + ch] = acc / (sqrtf(ss) + 1e-6f);
}

// ---------------------------------------------------------------- chunk transfer matrices
__global__ __launch_bounds__(256) void pk_k(const float* __restrict__ dtT,
                                            const float* __restrict__ A_log,
                                            float* __restrict__ Pm) {
  int bh = blockIdx.x;
  int h = bh & 31;
  int t = threadIdx.x;
  int ch = t >> 4, n = t & 15;
  float a = __expf(A_log[h * 16 + n]);
  const float* dtp = dtT + (size_t)h * ROWS + (size_t)(bh >> 5) * SEQ + ch * CH;
  float p00 = 1.f, p01 = 0.f, p10 = 0.f, p11 = 1.f;
  for (int l = 0; l < CH; ++l) {
    float dt = dtp[l];
    float s  = 1.0f / fmaf(dt * dt, a, 1.0f);
    float m00 = s;
    float m01 = -dt * a * s;
    float m10 = dt * s;
    float m11 = fmaf(-dt * a, m10, 1.0f);
    float q00 = fmaf(m00, p00, m01 * p10);
    float q01 = fmaf(m00, p01, m01 * p11);
    float q10 = fmaf(m10, p00, m11 * p10);
    float q11 = fmaf(m10, p01, m11 * p11);
    p00 = q00; p01 = q01; p10 = q10; p11 = q11;
  }
  float4 v = {p00, p01, p10, p11};
  *(float4*)&Pm[(((size_t)bh * NCH + ch) * 16 + n) * 4] = v;
}

// ---------------------------------------------------------------- propagate chunk-boundary states
__global__ __launch_bounds__(256) void prop_k(const float* __restrict__ Pm,
                                              const float* __restrict__ pend,
                                              float* __restrict__ sinit) {
  int gid = blockIdx.x * 256 + threadIdx.x;
  int n  = gid & 15;
  int d  = (gid >> 4) & 63;
  int bh = gid >> 10;
  float s0 = 0.f, s1 = 0.f;
  for (int c = 0; c < NCH; ++c) {
    size_t i2 = (((size_t)bh * NCH + c) * 64 + d) * 16 + n;
    *(float2*)&sinit[i2 * 2] = make_float2(s0, s1);
    float4 P  = *(const float4*)&Pm[(((size_t)bh * NCH + c) * 16 + n) * 4];
    float2 pe = *(const float2*)&pend[i2 * 2];
    float t0 = fmaf(P.x, s0, fmaf(P.y, s1, pe.x));
    float t1 = fmaf(P.z, s0, fmaf(P.w, s1, pe.y));
    s0 = t0; s1 = t1;
  }
}

// ---------------------------------------------------------------- chunked scan (u precomputed, f32x2 packed recurrence)
#define T_TILE 16
#define TPC (CH / T_TILE)
template<int PHASE>
__global__ __launch_bounds__(128) void scan_k(
    const float* __restrict__ zx, const float* __restrict__ bcb,
    const float* __restrict__ dtT, const float* __restrict__ A_log,
    const float* __restrict__ Dp, float* __restrict__ states,
    __hip_bfloat16* u_po)
{
  const int blk  = blockIdx.x;
  const int half = blk & 1;
  const int ch   = (blk >> 1) & 15;
  const int h    = (blk >> 5) & 31;
  const int b    = blk >> 10;
  const int bh   = b * 32 + h;
  const int tid  = threadIdx.x;
  const int wv   = tid >> 6;
  const int lane = tid & 63;
  const int d16  = lane & 15;
  const int ng   = lane >> 4;
  const int n0   = ng * 4;
  const int dwv  = wv * 16 + d16;
  const int dl   = half * 32 + dwv;
  const int dbase = h * 64 + half * 32;
  const size_t rowbase = (size_t)b * SEQ + (size_t)ch * CH;

  __shared__ __hip_bfloat16 dut[2][T_TILE][32];
  __shared__ float Btl[2][T_TILE][16];
  __shared__ float Ctl[PHASE == 3 ? 2 : 1][T_TILE][16];
  __shared__ float zt [PHASE == 3 ? 2 : 1][T_TILE][32];
  __shared__ float st [2][T_TILE][16];
  __shared__ float dtt[2][T_TILE];
  __shared__ float aexp[16];
  __shared__ float opart[PHASE == 3 ? T_TILE : 1][32][4];

  if (tid < 16) aexp[tid] = __expf(A_log[h * 16 + tid]);

  f32x2 A2[2];
  #pragma unroll
  for (int k = 0; k < 2; ++k) {
    A2[k][0] = __expf(A_log[h * 16 + n0 + 2 * k]);
    A2[k][1] = __expf(A_log[h * 16 + n0 + 2 * k + 1]);
  }
  const float Dh = Dp[h];

  auto stage = [&](int tile, int buf) {
    const size_t r0 = rowbase + (size_t)tile * T_TILE;
    if constexpr (PHASE == 3) {
      {
        int row = wv * 8 + (lane >> 3);
        const float* g = zx + (r0 + row) * PROJ_PAD + dbase + (lane & 7) * 4;
        float* l_ = &zt[buf][0][0] + wv * 256 + lane * 4;
        __builtin_amdgcn_global_load_lds((const __attribute__((address_space(1))) unsigned int*)g,
                                         (__attribute__((address_space(3))) unsigned int*)l_, 16, 0, 0);
      }
      if (wv == 0) {
        const __hip_bfloat16* g = u_po + (r0 + (lane >> 2)) * D_INNER + dbase + (lane & 3) * 8;
        __hip_bfloat16* l_ = &dut[buf][0][0] + lane * 8;
        __builtin_amdgcn_global_load_lds((const __attribute__((address_space(1))) unsigned int*)g,
                                         (__attribute__((address_space(3))) unsigned int*)l_, 16, 0, 0);
      } else {
        const float* gB = bcb + (r0 + (lane >> 2)) * 32 + (lane & 3) * 4;
        float* lB = &Btl[buf][0][0] + lane * 4;
        __builtin_amdgcn_global_load_lds((const __attribute__((address_space(1))) unsigned int*)gB,
                                         (__attribute__((address_space(3))) unsigned int*)lB, 16, 0, 0);
        const float* gC = bcb + (r0 + (lane >> 2)) * 32 + 16 + (lane & 3) * 4;
        float* lC = &Ctl[buf][0][0] + lane * 4;
        __builtin_amdgcn_global_load_lds((const __attribute__((address_space(1))) unsigned int*)gC,
                                         (__attribute__((address_space(3))) unsigned int*)lC, 16, 0, 0);
      }
    } else {
      if (wv == 0) {
        const __hip_bfloat16* g = u_po + (r0 + (lane >> 2)) * D_INNER + dbase + (lane & 3) * 8;
        __hip_bfloat16* l_ = &dut[buf][0][0] + lane * 8;
        __builtin_amdgcn_global_load_lds((const __attribute__((address_space(1))) unsigned int*)g,
                                         (__attribute__((address_space(3))) unsigned int*)l_, 16, 0, 0);
      } else {
        const float* gB = bcb + (r0 + (lane >> 2)) * 32 + (lane & 3) * 4;
        float* lB = &Btl[buf][0][0] + lane * 4;
        __builtin_amdgcn_global_load_lds((const __attribute__((address_space(1))) unsigned int*)gB,
                                         (__attribute__((address_space(3))) unsigned int*)lB, 16, 0, 0);
      }
    }
  };

  auto sprep = [&](int buf, float dtn) {
    #pragma unroll
    for (int i = 0; i < 2; ++i) {
      int idx = tid + 128 * i;
      int row = idx >> 4, n = idx & 15;
      float dv = __shfl(dtn, row);
      float a  = aexp[n];
      st[buf][row][n] = 1.0f / fmaf(dv * dv, a, 1.0f);
    }
  };

  stage(0, 0);
  float dtn = 0.f;
  if (lane < 16) dtn = dtT[(size_t)h * ROWS + rowbase + lane];
  __syncthreads();
  if (tid < 16) dtt[0][tid] = dtn;
  sprep(0, dtn);
  __syncthreads();

  f32x2 w2[2], ys2[2];
  if constexpr (PHASE == 1) {
    #pragma unroll
    for (int k = 0; k < 2; ++k) { w2[k] = (f32x2){0.f, 0.f}; ys2[k] = (f32x2){0.f, 0.f}; }
  } else {
    #pragma unroll
    for (int k = 0; k < 2; ++k)
      #pragma unroll
      for (int j = 0; j < 2; ++j) {
        size_t i2 = (((size_t)bh * NCH + ch) * 64 + dl) * 16 + (n0 + 2 * k + j);
        float2 s = *(const float2*)&states[i2 * 2];
        w2[k][j] = s.x; ys2[k][j] = s.y;
      }
  }
  int cur = 0;

  for (int t = 0; t < TPC; ++t) {
    if (t + 1 < TPC) {
      stage(t + 1, cur ^ 1);
      if (lane < 16) dtn = dtT[(size_t)h * ROWS + rowbase + (size_t)(t + 1) * T_TILE + lane];
    }
    #pragma unroll 4
    for (int l = 0; l < T_TILE; ++l) {
      float uv  = __bfloat162float(dut[cur][l][dwv]);
      float dtv = dtt[cur][l];
      f32x4 Sv4 = *(const f32x4*)&st [cur][l][n0];
      f32x4 Bv4 = *(const f32x4*)&Btl[cur][l][n0];
      float du = dtv * uv;
      f32x2 S2[2] = { {Sv4[0], Sv4[1]}, {Sv4[2], Sv4[3]} };
      f32x2 B2[2] = { {Bv4[0], Bv4[1]}, {Bv4[2], Bv4[3]} };
      if constexpr (PHASE == 3) {
        f32x4 Cv4 = *(const f32x4*)&Ctl[cur][l][n0];
        f32x2 C2[2] = { {Cv4[0], Cv4[1]}, {Cv4[2], Cv4[3]} };
        f32x2 o2 = {0.f, 0.f};
        #pragma unroll
        for (int k = 0; k < 2; ++k) {
          f32x2 dtA = dtv * A2[k];
          f32x2 tmp = w2[k] - dtA * ys2[k];
          tmp = tmp + du * B2[k];
          w2[k] = S2[k] * tmp;
          ys2[k] = ys2[k] + dtv * w2[k];
          o2 = o2 + ys2[k] * C2[k];
        }
        float o = o2[0] + o2[1];
        float ofin = (ng == 0) ? fmaf(Dh, uv, o) : o;
        opart[l][dwv][ng] = ofin;
      } else {
        #pragma unroll
        for (int k = 0; k < 2; ++k) {
          f32x2 dtA = dtv * A2[k];
          f32x2 tmp = w2[k] - dtA * ys2[k];
          tmp = tmp + du * B2[k];
          w2[k] = S2[k] * tmp;
          ys2[k] = ys2[k] + dtv * w2[k];
        }
      }
    }
    if constexpr (PHASE == 3) {
      #pragma unroll
      for (int i = 0; i < 4; ++i) {
        int l  = (lane >> 4) + 4 * i;
        int dd = wv * 16 + d16;
        f32x4 op = *(const f32x4*)&opart[l][dd][0];
        float zv = zt[cur][l][dd];
        float yv = (op[0] + op[1]) + (op[2] + op[3]);
        u_po[(rowbase + (size_t)t * T_TILE + l) * D_INNER + dbase + dd] =
            __float2bfloat16(yv * siluf(zv));
      }
    }
    __syncthreads();
    if (t + 1 < TPC) {
      if (tid < 16) dtt[cur ^ 1][tid] = dtn;
      sprep(cur ^ 1, dtn);
      __syncthreads();
    }
    cur ^= 1;
  }

  if constexpr (PHASE == 1) {
    #pragma unroll
    for (int k = 0; k < 2; ++k)
      #pragma unroll
      for (int j = 0; j < 2; ++j) {
        size_t i2 = (((size_t)bh * NCH + ch) * 64 + dl) * 16 + (n0 + 2 * k + j);
        *(float2*)&states[i2 * 2] = make_float2(w2[k][j], ys2[k][j]);
      }
  }
}

// ---------------------------------------------------------------- launch
extern "C" void kernel_launch(void* const* d_in, const int* in_sizes, int n_in,
                              void* d_out, int out_size, void* d_ws, size_t ws_size,
                              hipStream_t stream) {
  const float* x     = (const float*)d_in[0];
  const float* n1w   = (const float*)d_in[1];
  const float* wi    = (const float*)d_in[2];
  const float* cw    = (const float*)d_in[3];
  const float* cb    = (const float*)d_in[4];
  const float* A_log = (const float*)d_in[5];
  const float* dtb   = (const float*)d_in[6];
  const float* Dp    = (const float*)d_in[7];
  const float* wo    = (const float*)d_in[8];
  const float* n2w   = (const float*)d_in[9];
  const float* wg    = (const float*)d_in[10];
  const float* wu    = (const float*)d_in[11];
  const float* wd    = (const float*)d_in[12];
  float* out = (float*)d_out;

  char* p = (char*)d_ws;
  auto take = [&](size_t b) { char* q = p; p += (b + 255) & ~(size_t)255; return q; };
  __hip_bfloat16* wbi  = (__hip_bfloat16*)take((size_t)PROJ_PAD * D_MODEL * 2);
  __hip_bfloat16* wbo  = (__hip_bfloat16*)take((size_t)D_MODEL * D_INNER * 2);
  __hip_bfloat16* wgu  = (__hip_bfloat16*)take((size_t)GU_N * D_MODEL * 2);
  __hip_bfloat16* wbd  = (__hip_bfloat16*)take((size_t)D_MODEL * FFN_DIM * 2);
  __hip_bfloat16* h0b  = (__hip_bfloat16*)take((size_t)ROWS * D_MODEL * 2);
  float*          zx   = (float*)take((size_t)ROWS * PROJ_PAD * 4);
  float*          bcb  = (float*)take((size_t)ROWS * 32 * 4);
  float*          dtT  = (float*)take((size_t)ROWS * 32 * 4);
  __hip_bfloat16* po   = (__hip_bfloat16*)take((size_t)ROWS * D_INNER * 2);   // u carrier, then scan output
  float*          pend = (float*)take((size_t)128 * NCH * 64 * 16 * 2 * 4);
  float*          sini = (float*)take((size_t)128 * NCH * 64 * 16 * 2 * 4);
  float*          Pm   = (float*)take((size_t)128 * NCH * 16 * 4 * 4);
  float*          h0f  = (float*)zx;
  float*          h    = (float*)zx;
  __hip_bfloat16* gact = (__hip_bfloat16*)((char*)zx + 33554432);

  hipFuncSetAttribute(reinterpret_cast<const void*>(&gemm8<0>),  hipFuncAttributeMaxDynamicSharedMemorySize, 131072);
  hipFuncSetAttribute(reinterpret_cast<const void*>(&gemm8<4>),  hipFuncAttributeMaxDynamicSharedMemorySize, 131072);
  hipFuncSetAttribute(reinterpret_cast<const void*>(&gemm8B<1>), hipFuncAttributeMaxDynamicSharedMemorySize, 131072);

  // weight conversions
  cvt_pad_k<<<(PROJ_PAD * D_MODEL + 255) / 256, 256, 0, stream>>>(wi, wbi);
  cvt_k<<<(D_MODEL * D_INNER + 255) / 256, 256, 0, stream>>>(wo, wbo, D_MODEL * D_INNER);
  cvt_gu_k<<<(GU_N * D_MODEL + 255) / 256, 256, 0, stream>>>(wg, wu, wgu);
  cvt_k<<<(FFN_DIM * D_MODEL + 255) / 256, 256, 0, stream>>>(wd, wbd, FFN_DIM * D_MODEL);

  // mixer
  rmsnorm_k<<<ROWS, 256, 0, stream>>>(x, n1w, h0b, h0f);
  dtproj_k<<<ROWS / 4, 256, 0, stream>>>(h0f, wi, dtb, dtT);
  gemm8<0><<<(ROWS / 256) * (PROJ_PAD / 256), 512, 131072, stream>>>(h0b, wbi, zx, nullptr, nullptr,
                                                                     ROWS, PROJ_PAD, D_MODEL);
  duconv_k<<<ROWS * 512 / 256, 256, 0, stream>>>(zx, cw, cb, po);
  bcdt_k<<<ROWS / 8, 256, 0, stream>>>(zx, cw, cb, bcb);
  pk_k<<<BATCH * N_HEADS, 256, 0, stream>>>(dtT, A_log, Pm);
  scan_k<1><<<BATCH * N_HEADS * NCH * 2, 128, 0, stream>>>(zx, bcb, dtT, A_log, Dp, pend, po);
  prop_k<<<BATCH * N_HEADS * 64 * 16 / 256, 256, 0, stream>>>(Pm, pend, sini);
  scan_k<3><<<BATCH * N_HEADS * NCH * 2, 128, 0, stream>>>(zx, bcb, dtT, A_log, Dp, sini, po);
  gemm8B<1><<<(ROWS / 256) * (D_MODEL / 128), 512, 131072, stream>>>(po, wbo, h, nullptr, x,
                                                                     ROWS, D_MODEL, D_INNER);
  // FFN
  rmsnorm_k<<<ROWS, 256, 0, stream>>>(h, n2w, h0b, nullptr);
  gemm8<4><<<(ROWS / 256) * (GU_N / 256), 512, 131072, stream>>>(h0b, wgu, nullptr, gact, nullptr,
                                                                 ROWS, GU_N, D_MODEL);
  gemm8B<1><<<(ROWS / 256) * (D_MODEL / 128), 512, 131072, stream>>>(gact, wbd, out, nullptr, h,
                                                                     ROWS, D_MODEL, FFN_DIM);
}

// Round 12
// 606.812 us; speedup vs baseline: 2.7741x; 1.0693x over previous
//
#include <hip/hip_runtime.h>
#include <hip/hip_bf16.h>

#define D_MODEL   1024
#define D_STATE   16
#define D_HEAD    64
#define D_CONV    4
#define FFN_DIM   2816
#define D_INNER   2048
#define N_HEADS   32
#define BATCH     4
#define SEQ       2048
#define ROWS      (BATCH*SEQ)     // 8192
#define PROJ_DIM  4160
#define ZX_N      4096            // z + x only (16 tiles of 256)
#define CH        128             // scan chunk length
#define NCH       (SEQ/CH)        // 16 chunks
#define GU_N      5632            // 2*FFN_DIM interleaved (22 tiles of 256)

typedef __bf16 bf16x8 __attribute__((ext_vector_type(8)));
typedef float  f32x4  __attribute__((ext_vector_type(4)));
typedef float  f32x2  __attribute__((ext_vector_type(2)));

__device__ __forceinline__ float siluf(float x) { return x / (1.0f + __expf(-x)); }

#define SBAR() do { asm volatile("" ::: "memory"); __builtin_amdgcn_s_barrier(); asm volatile("" ::: "memory"); } while (0)
#define LGKM0() asm volatile("s_waitcnt lgkmcnt(0)" ::: "memory")
#define VMCNT4() asm volatile("s_waitcnt vmcnt(4)" ::: "memory")
#define VMCNT2() asm volatile("s_waitcnt vmcnt(2)" ::: "memory")
#define VMCNT0() asm volatile("s_waitcnt vmcnt(0)" ::: "memory")

// ---------------------------------------------------------------- converts
__global__ void cvt_k(const float* __restrict__ src, __hip_bfloat16* __restrict__ dst, int n) {
  int i = blockIdx.x * blockDim.x + threadIdx.x;
  if (i < n) dst[i] = __float2bfloat16(src[i]);
}

// interleave gate/up weights: tile t rows [0,128)=gate cols t*128.., [128,256)=up cols t*128..
__global__ void cvt_gu_k(const float* __restrict__ wg, const float* __restrict__ wu,
                         __hip_bfloat16* __restrict__ dst) {
  int i = blockIdx.x * blockDim.x + threadIdx.x;
  if (i >= GU_N * D_MODEL) return;
  int r = i >> 10, c = i & 1023;
  int tile = r >> 8, rr = r & 255;
  const float* src = (rr < 128)
      ? wg + (size_t)(tile * 128 + rr) * D_MODEL + c
      : wu + (size_t)(tile * 128 + (rr - 128)) * D_MODEL + c;
  dst[i] = __float2bfloat16(*src);
}

// ---------------------------------------------------------------- rmsnorm
__global__ __launch_bounds__(256) void rmsnorm_k(const float* __restrict__ x,
                                                 const float* __restrict__ w,
                                                 __hip_bfloat16* __restrict__ out,
                                                 float* __restrict__ outf) {
  int row = blockIdx.x;
  int t = threadIdx.x;
  const float* xr = x + (size_t)row * D_MODEL;
  float4 v = ((const float4*)xr)[t];
  float ss = v.x*v.x + v.y*v.y + v.z*v.z + v.w*v.w;
  #pragma unroll
  for (int o = 32; o > 0; o >>= 1) ss += __shfl_xor(ss, o);
  __shared__ float red[4];
  if ((t & 63) == 0) red[t >> 6] = ss;
  __syncthreads();
  ss = red[0] + red[1] + red[2] + red[3];
  float scale = rsqrtf(ss * (1.0f / D_MODEL) + 1e-6f);
  float4 wv = ((const float4*)w)[t];
  float4 r;
  r.x = v.x * scale * wv.x; r.y = v.y * scale * wv.y;
  r.z = v.z * scale * wv.z; r.w = v.w * scale * wv.w;
  __hip_bfloat16* orow = out + (size_t)row * D_MODEL + t * 4;
  orow[0] = __float2bfloat16(r.x);
  orow[1] = __float2bfloat16(r.y);
  orow[2] = __float2bfloat16(r.z);
  orow[3] = __float2bfloat16(r.w);
  if (outf) ((float4*)(outf + (size_t)row * D_MODEL))[t] = r;
}

// ---------------------------------------------------------------- dt + B/C projection (pure f32, block-per-4-rows)
// 256 threads: o = t>>2 (0..31 -> BC chan, 32..63 -> dt head), seg = t&3 (K quarter).
__global__ __launch_bounds__(256) void vecproj_k(const float* __restrict__ xn,
                                                 const float* __restrict__ wi,
                                                 const float* __restrict__ dtb,
                                                 float* __restrict__ dtT,
                                                 float* __restrict__ bcraw) {
  const int r0 = blockIdx.x * 4;
  const int t  = threadIdx.x;
  const int o   = t >> 2;
  const int seg = t & 3;

  __shared__ float xs[4][D_MODEL];
  #pragma unroll
  for (int i = 0; i < 4; ++i)
    ((float4*)&xs[i][0])[t] = ((const float4*)(xn + (size_t)(r0 + i) * D_MODEL))[t];
  __syncthreads();

  const int wrow = (o < 32) ? (2 * D_INNER + o) : (2 * D_INNER + 2 * D_STATE + (o - 32));
  const float4* w4 = (const float4*)(wi + (size_t)wrow * D_MODEL) + seg * 64;
  const float4* x0 = (const float4*)&xs[0][0] + seg * 64;
  const float4* x1 = (const float4*)&xs[1][0] + seg * 64;
  const float4* x2 = (const float4*)&xs[2][0] + seg * 64;
  const float4* x3 = (const float4*)&xs[3][0] + seg * 64;
  float a0 = 0.f, a1 = 0.f, a2 = 0.f, a3 = 0.f;
  #pragma unroll 8
  for (int k = 0; k < 64; ++k) {
    float4 wv = w4[k];
    float4 v0 = x0[k], v1 = x1[k], v2 = x2[k], v3 = x3[k];
    a0 = fmaf(wv.x, v0.x, fmaf(wv.y, v0.y, fmaf(wv.z, v0.z, fmaf(wv.w, v0.w, a0))));
    a1 = fmaf(wv.x, v1.x, fmaf(wv.y, v1.y, fmaf(wv.z, v1.z, fmaf(wv.w, v1.w, a1))));
    a2 = fmaf(wv.x, v2.x, fmaf(wv.y, v2.y, fmaf(wv.z, v2.z, fmaf(wv.w, v2.w, a2))));
    a3 = fmaf(wv.x, v3.x, fmaf(wv.y, v3.y, fmaf(wv.z, v3.z, fmaf(wv.w, v3.w, a3))));
  }
  #pragma unroll
  for (int m = 1; m < 4; m <<= 1) {
    a0 += __shfl_xor(a0, m);
    a1 += __shfl_xor(a1, m);
    a2 += __shfl_xor(a2, m);
    a3 += __shfl_xor(a3, m);
  }
  if (seg == 0) {
    float v[4] = {a0, a1, a2, a3};
    if (o < 32) {
      #pragma unroll
      for (int i = 0; i < 4; ++i) bcraw[(size_t)(r0 + i) * 32 + o] = v[i];
    } else {
      int hh = o - 32;
      float bias = dtb[hh];
      #pragma unroll
      for (int i = 0; i < 4; ++i) {
        float xv = v[i] + bias;
        dtT[(size_t)hh * ROWS + r0 + i] = (xv > 20.f) ? xv : log1pf(__expf(xv));
      }
    }
  }
}

// ---------------------------------------------------------------- 256x256 8-phase GEMM
// EPI: 0 f32 store; 1 f32 + add_src; 4 fused gate/up (LDS exchange, bf16 silu(g)*u);
//      5 plain bf16 store.
template<int EPI>
__global__ __launch_bounds__(512, 2) void gemm8(
    const __hip_bfloat16* __restrict__ A,
    const __hip_bfloat16* __restrict__ Bw,
    float* __restrict__ Cf,
    __hip_bfloat16* __restrict__ Cb,
    const float* __restrict__ add_src,
    int M, int N, int K)
{
  extern __shared__ char lds[];
  const int nwg = (M >> 8) * (N >> 8);
  int bid = blockIdx.x;
  bid = (bid & 7) * (nwg >> 3) + (bid >> 3);
  const int ntn = N >> 8;
  const int bm = (bid / ntn) << 8;
  const int bn = (bid % ntn) << 8;

  const int tid  = threadIdx.x;
  const int wid  = tid >> 6;
  const int lane = tid & 63;
  const int wm = wid >> 2;
  const int wn = wid & 3;
  const int r16 = lane & 15;
  const int kg  = lane >> 4;

  const int rb = ((r16 << 6) + (kg << 4)) ^ ((r16 & 8) << 2);

  const int s_sub = tid >> 6;
  const int s_w   = (tid & 63) << 4;
  const int s_wp  = s_w ^ ((((s_w) >> 9) & 1) << 5);
  const int s_row = ((s_sub >> 1) << 4) + (s_wp >> 6);
  const int s_col = ((s_sub & 1) << 5) + ((s_wp >> 1) & 31);

  auto stage = [&](int buf, int mat, int half, int c, int kt) {
    const __hip_bfloat16* src = (mat == 0)
        ? A  + (size_t)(bm + half * 128 + c * 64 + s_row) * K + kt * 64 + s_col
        : Bw + (size_t)(bn + half * 128 + c * 64 + s_row) * K + kt * 64 + s_col;
    char* dst = lds + buf * 65536 + mat * 32768 + half * 16384 + c * 8192 + tid * 16;
    __builtin_amdgcn_global_load_lds((const __attribute__((address_space(1))) unsigned int*)src,
                                     (__attribute__((address_space(3))) unsigned int*)dst,
                                     16, 0, 0);
  };

  f32x4 acc[8][4] = {};
  bf16x8 af[4][2], bfr[4][2];

  const int NT = K >> 6;
  stage(0,0,0,0,0); stage(0,0,0,1,0); stage(0,0,1,0,0); stage(0,0,1,1,0);
  stage(0,1,0,0,0); stage(0,1,0,1,0); stage(0,1,1,0,0); stage(0,1,1,1,0);
  __syncthreads();

  for (int kt = 0; kt < NT; ++kt) {
    const int buf = kt & 1, nbuf = buf ^ 1;
    const bool st = (kt + 1 < NT);
    const char* Ab = lds + buf * 65536 + wm * 16384;
    const char* Bb = lds + buf * 65536 + 32768 + (wn >> 1) * 16384 + (wn & 1) * 8192;

    #pragma unroll
    for (int mi2 = 0; mi2 < 4; ++mi2)
      #pragma unroll
      for (int kk = 0; kk < 2; ++kk)
        af[mi2][kk] = *(const bf16x8*)(Ab + (mi2 * 2 + kk) * 1024 + rb);
    #pragma unroll
    for (int ni = 0; ni < 2; ++ni)
      #pragma unroll
      for (int kk = 0; kk < 2; ++kk)
        bfr[ni][kk] = *(const bf16x8*)(Bb + (ni * 2 + kk) * 1024 + rb);
    if (st) { stage(nbuf,1,0,0,kt+1); stage(nbuf,1,0,1,kt+1); }
    SBAR(); LGKM0();
    __builtin_amdgcn_s_setprio(1);
    #pragma unroll
    for (int mi2 = 0; mi2 < 4; ++mi2)
      #pragma unroll
      for (int ni = 0; ni < 2; ++ni)
        #pragma unroll
        for (int kk = 0; kk < 2; ++kk)
          acc[mi2][ni] = __builtin_amdgcn_mfma_f32_16x16x32_bf16(af[mi2][kk], bfr[ni][kk], acc[mi2][ni], 0, 0, 0);
    __builtin_amdgcn_s_setprio(0);
    SBAR();

    #pragma unroll
    for (int ni = 2; ni < 4; ++ni)
      #pragma unroll
      for (int kk = 0; kk < 2; ++kk)
        bfr[ni][kk] = *(const bf16x8*)(Bb + (ni * 2 + kk) * 1024 + rb);
    if (st) { stage(nbuf,1,1,0,kt+1); stage(nbuf,1,1,1,kt+1); }
    SBAR(); LGKM0();
    __builtin_amdgcn_s_setprio(1);
    #pragma unroll
    for (int mi2 = 0; mi2 < 4; ++mi2)
      #pragma unroll
      for (int ni = 2; ni < 4; ++ni)
        #pragma unroll
        for (int kk = 0; kk < 2; ++kk)
          acc[mi2][ni] = __builtin_amdgcn_mfma_f32_16x16x32_bf16(af[mi2][kk], bfr[ni][kk], acc[mi2][ni], 0, 0, 0);
    __builtin_amdgcn_s_setprio(0);
    if (st) { VMCNT4(); } else { VMCNT0(); }
    SBAR();

    #pragma unroll
    for (int mi2 = 0; mi2 < 4; ++mi2)
      #pragma unroll
      for (int kk = 0; kk < 2; ++kk)
        af[mi2][kk] = *(const bf16x8*)(Ab + ((4 + mi2) * 2 + kk) * 1024 + rb);
    if (st) { stage(nbuf,0,0,0,kt+1); stage(nbuf,0,1,0,kt+1); }
    SBAR(); LGKM0();
    __builtin_amdgcn_s_setprio(1);
    #pragma unroll
    for (int mi2 = 0; mi2 < 4; ++mi2)
      #pragma unroll
      for (int ni = 0; ni < 2; ++ni)
        #pragma unroll
        for (int kk = 0; kk < 2; ++kk)
          acc[4 + mi2][ni] = __builtin_amdgcn_mfma_f32_16x16x32_bf16(af[mi2][kk], bfr[ni][kk], acc[4 + mi2][ni], 0, 0, 0);
    __builtin_amdgcn_s_setprio(0);
    SBAR();

    if (st) { stage(nbuf,0,0,1,kt+1); stage(nbuf,0,1,1,kt+1); }
    SBAR(); LGKM0();
    __builtin_amdgcn_s_setprio(1);
    #pragma unroll
    for (int mi2 = 0; mi2 < 4; ++mi2)
      #pragma unroll
      for (int ni = 2; ni < 4; ++ni)
        #pragma unroll
        for (int kk = 0; kk < 2; ++kk)
          acc[4 + mi2][ni] = __builtin_amdgcn_mfma_f32_16x16x32_bf16(af[mi2][kk], bfr[ni][kk], acc[4 + mi2][ni], 0, 0, 0);
    __builtin_amdgcn_s_setprio(0);
    VMCNT2();
    SBAR();
  }

  if constexpr (EPI == 4) {
    // fused gate/up epilogue: wn<2 hold gate, wn>=2 hold up. Exchange through LDS.
    float* xch = (float*)lds;
    __syncthreads();
    if (wn < 2) {
      #pragma unroll
      for (int mi = 0; mi < 8; ++mi)
        #pragma unroll
        for (int ni = 0; ni < 4; ++ni)
          #pragma unroll
          for (int j = 0; j < 4; ++j) {
            int row = mi * 16 + kg * 4 + j;
            int col = wn * 64 + ni * 16 + r16;
            int cc = col ^ (((row >> 2) & 1) << 4);
            xch[wm * 16384 + row * 128 + cc] = siluf(acc[mi][ni][j]);
          }
    }
    __syncthreads();
    if (wn >= 2) {
      #pragma unroll
      for (int mi = 0; mi < 8; ++mi)
        #pragma unroll
        for (int ni = 0; ni < 4; ++ni)
          #pragma unroll
          for (int j = 0; j < 4; ++j) {
            int row = mi * 16 + kg * 4 + j;
            int col = (wn - 2) * 64 + ni * 16 + r16;
            int cc = col ^ (((row >> 2) & 1) << 4);
            float g = xch[wm * 16384 + row * 128 + cc];
            int r = bm + wm * 128 + row;
            int tc = (bn >> 1) + col;
            Cb[(size_t)r * FFN_DIM + tc] = __float2bfloat16(g * acc[mi][ni][j]);
          }
    }
  } else {
    #pragma unroll
    for (int mi = 0; mi < 8; ++mi) {
      #pragma unroll
      for (int ni = 0; ni < 4; ++ni) {
        #pragma unroll
        for (int j = 0; j < 4; ++j) {
          int r = bm + wm * 128 + mi * 16 + kg * 4 + j;
          int c = bn + wn * 64 + ni * 16 + r16;
          size_t idx = (size_t)r * N + c;
          float v = acc[mi][ni][j];
          if constexpr (EPI == 0) {
            Cf[idx] = v;
          } else if constexpr (EPI == 1) {
            Cf[idx] = v + add_src[idx];
          } else if constexpr (EPI == 5) {
            Cb[idx] = __float2bfloat16(v);
          }
        }
      }
    }
  }
}

// ---------------------------------------------------------------- 256x128 8-phase GEMM (full grid at N=1024)
template<int EPI>
__global__ __launch_bounds__(512, 2) void gemm8B(
    const __hip_bfloat16* __restrict__ A,
    const __hip_bfloat16* __restrict__ Bw,
    float* __restrict__ Cf,
    __hip_bfloat16* __restrict__ Cb,
    const float* __restrict__ add_src,
    int M, int N, int K)
{
  extern __shared__ char lds[];
  const int nwg = (M >> 8) * (N >> 7);
  int bid = blockIdx.x;
  bid = (bid & 7) * (nwg >> 3) + (bid >> 3);
  const int ntn = N >> 7;
  const int bm = (bid / ntn) << 8;
  const int bn = (bid % ntn) << 7;

  const int tid  = threadIdx.x;
  const int wid  = tid >> 6;
  const int lane = tid & 63;
  const int wm = wid >> 2;
  const int wn = wid & 3;
  const int r16 = lane & 15;
  const int kg  = lane >> 4;

  const int rb = ((r16 << 6) + (kg << 4)) ^ ((r16 & 8) << 2);

  const int s_sub = tid >> 6;
  const int s_w   = (tid & 63) << 4;
  const int s_wp  = s_w ^ ((((s_w) >> 9) & 1) << 5);
  const int s_row = ((s_sub >> 1) << 4) + (s_wp >> 6);
  const int s_col = ((s_sub & 1) << 5) + ((s_wp >> 1) & 31);

  auto stageA = [&](int buf, int half, int c, int kt) {
    const __hip_bfloat16* src = A + (size_t)(bm + half * 128 + c * 64 + s_row) * K + kt * 64 + s_col;
    char* dst = lds + buf * 65536 + half * 16384 + c * 8192 + tid * 16;
    __builtin_amdgcn_global_load_lds((const __attribute__((address_space(1))) unsigned int*)src,
                                     (__attribute__((address_space(3))) unsigned int*)dst,
                                     16, 0, 0);
  };
  auto stageB = [&](int buf, int c, int kt) {
    const __hip_bfloat16* src = Bw + (size_t)(bn + c * 64 + s_row) * K + kt * 64 + s_col;
    char* dst = lds + buf * 65536 + 32768 + c * 8192 + tid * 16;
    __builtin_amdgcn_global_load_lds((const __attribute__((address_space(1))) unsigned int*)src,
                                     (__attribute__((address_space(3))) unsigned int*)dst,
                                     16, 0, 0);
  };

  f32x4 acc[8][2] = {};
  bf16x8 af[4][2], bfr[2][2];

  const int NT = K >> 6;
  stageB(0,0,0); stageB(0,1,0);
  stageA(0,0,0,0); stageA(0,1,0,0); stageA(0,0,1,0); stageA(0,1,1,0);
  __syncthreads();

  for (int kt = 0; kt < NT; ++kt) {
    const int buf = kt & 1, nbuf = buf ^ 1;
    const bool st = (kt + 1 < NT);
    const char* Ab = lds + buf * 65536 + wm * 16384;
    const char* Bb = lds + buf * 65536 + 32768 + (wn >> 1) * 8192 + (wn & 1) * 4096;

    #pragma unroll
    for (int mi2 = 0; mi2 < 4; ++mi2)
      #pragma unroll
      for (int kk = 0; kk < 2; ++kk)
        af[mi2][kk] = *(const bf16x8*)(Ab + (mi2 * 2 + kk) * 1024 + rb);
    #pragma unroll
    for (int ni = 0; ni < 2; ++ni)
      #pragma unroll
      for (int kk = 0; kk < 2; ++kk)
        bfr[ni][kk] = *(const bf16x8*)(Bb + (ni * 2 + kk) * 1024 + rb);
    if (st) { stageB(nbuf,0,kt+1); stageB(nbuf,1,kt+1); stageA(nbuf,0,0,kt+1); stageA(nbuf,1,0,kt+1); }
    SBAR(); LGKM0();
    __builtin_amdgcn_s_setprio(1);
    #pragma unroll
    for (int mi2 = 0; mi2 < 4; ++mi2)
      #pragma unroll
      for (int ni = 0; ni < 2; ++ni)
        #pragma unroll
        for (int kk = 0; kk < 2; ++kk)
          acc[mi2][ni] = __builtin_amdgcn_mfma_f32_16x16x32_bf16(af[mi2][kk], bfr[ni][kk], acc[mi2][ni], 0, 0, 0);
    __builtin_amdgcn_s_setprio(0);
    if (st) { VMCNT4(); } else { VMCNT0(); }
    SBAR();

    #pragma unroll
    for (int mi2 = 0; mi2 < 4; ++mi2)
      #pragma unroll
      for (int kk = 0; kk < 2; ++kk)
        af[mi2][kk] = *(const bf16x8*)(Ab + ((4 + mi2) * 2 + kk) * 1024 + rb);
    if (st) { stageA(nbuf,0,1,kt+1); stageA(nbuf,1,1,kt+1); }
    SBAR(); LGKM0();
    __builtin_amdgcn_s_setprio(1);
    #pragma unroll
    for (int mi2 = 0; mi2 < 4; ++mi2)
      #pragma unroll
      for (int ni = 0; ni < 2; ++ni)
        #pragma unroll
        for (int kk = 0; kk < 2; ++kk)
          acc[4 + mi2][ni] = __builtin_amdgcn_mfma_f32_16x16x32_bf16(af[mi2][kk], bfr[ni][kk], acc[4 + mi2][ni], 0, 0, 0);
    __builtin_amdgcn_s_setprio(0);
    VMCNT2();
    SBAR();
  }

  #pragma unroll
  for (int mi = 0; mi < 8; ++mi) {
    #pragma unroll
    for (int ni = 0; ni < 2; ++ni) {
      #pragma unroll
      for (int j = 0; j < 4; ++j) {
        int r = bm + wm * 128 + mi * 16 + kg * 4 + j;
        int c = bn + wn * 32 + ni * 16 + r16;
        size_t idx = (size_t)r * N + c;
        float v = acc[mi][ni][j];
        if constexpr (EPI == 0) {
          Cf[idx] = v;
        } else if constexpr (EPI == 1) {
          Cf[idx] = v + add_src[idx];
        }
      }
    }
  }
}

// ---------------------------------------------------------------- u = silu(depthwise conv(x)), x in bf16, u bf16 -> po
__global__ __launch_bounds__(256) void duconv_k(const __hip_bfloat16* __restrict__ zxb,
                                                const float* __restrict__ cw,
                                                const float* __restrict__ cb,
                                                __hip_bfloat16* __restrict__ u_po) {
  int idx = blockIdx.x * 256 + threadIdx.x;
  int q = idx & 511;
  int r = idx >> 9;
  int d0 = q << 2;
  int l = r & (SEQ - 1);
  float4 cb4 = ((const float4*)cb)[q];
  float tw[4][4];
  #pragma unroll
  for (int i = 0; i < 4; ++i) {
    float4 t = ((const float4*)cw)[d0 + i];
    tw[i][0] = t.x; tw[i][1] = t.y; tw[i][2] = t.z; tw[i][3] = t.w;
  }
  float a[4] = {cb4.x, cb4.y, cb4.z, cb4.w};
  #pragma unroll
  for (int k = 0; k < 4; ++k) {
    if (l - 3 + k >= 0) {
      union { ushort4 u4; __hip_bfloat16 b[4]; } R;
      R.u4 = *(const ushort4*)(zxb + (size_t)(r - 3 + k) * ZX_N + D_INNER + d0);
      a[0] = fmaf(__bfloat162float(R.b[0]), tw[0][k], a[0]);
      a[1] = fmaf(__bfloat162float(R.b[1]), tw[1][k], a[1]);
      a[2] = fmaf(__bfloat162float(R.b[2]), tw[2][k], a[2]);
      a[3] = fmaf(__bfloat162float(R.b[3]), tw[3][k], a[3]);
    }
  }
  union { ushort4 u4; __hip_bfloat16 b[4]; } pk;
  #pragma unroll
  for (int i = 0; i < 4; ++i) pk.b[i] = __float2bfloat16(siluf(a[i]));
  *(ushort4*)(u_po + (size_t)r * D_INNER + d0) = pk.u4;
}

// ---------------------------------------------------------------- conv+silu+normalize for the 32 B/C channels (from bcraw f32)
__global__ __launch_bounds__(256) void bcdt_k(const float* __restrict__ bcraw,
                                              const float* __restrict__ cw,
                                              const float* __restrict__ cb,
                                              float* __restrict__ bc) {
  int t = threadIdx.x;
  int r = blockIdx.x * 8 + (t >> 5);
  int ch = t & 31;
  int l = r & (SEQ - 1);
  int c = D_INNER + ch;
  float acc = cb[c];
  #pragma unroll
  for (int k = 0; k < 4; ++k) {
    int lp = l - 3 + k;
    if (lp >= 0)
      acc = fmaf(bcraw[(size_t)(r - 3 + k) * 32 + ch], cw[c * 4 + k], acc);
  }
  acc = siluf(acc);
  float ss = acc * acc;
  ss += __shfl_xor(ss, 1);
  ss += __shfl_xor(ss, 2);
  ss += __shfl_xor(ss, 4);
  ss += __shfl_xor(ss, 8);
  bc[r * 32 + ch] = acc / (sqrtf(ss) + 1e-6f);
}

// ---------------------------------------------------------------- chunk transfer matrices
__global__ __launch_bounds__(256) void pk_k(const float* __restrict__ dtT,
                                            const float* __restrict__ A_log,
                                            float* __restrict__ Pm) {
  int bh = blockIdx.x;
  int h = bh & 31;
  int t = threadIdx.x;
  int ch = t >> 4, n = t & 15;
  float a = __expf(A_log[h * 16 + n]);
  const float* dtp = dtT + (size_t)h * ROWS + (size_t)(bh >> 5) * SEQ + ch * CH;
  float p00 = 1.f, p01 = 0.f, p10 = 0.f, p11 = 1.f;
  for (int l = 0; l < CH; ++l) {
    float dt = dtp[l];
    float s  = 1.0f / fmaf(dt * dt, a, 1.0f);
    float m00 = s;
    float m01 = -dt * a * s;
    float m10 = dt * s;
    float m11 = fmaf(-dt * a, m10, 1.0f);
    float q00 = fmaf(m00, p00, m01 * p10);
    float q01 = fmaf(m00, p01, m01 * p11);
    float q10 = fmaf(m10, p00, m11 * p10);
    float q11 = fmaf(m10, p01, m11 * p11);
    p00 = q00; p01 = q01; p10 = q10; p11 = q11;
  }
  float4 v = {p00, p01, p10, p11};
  *(float4*)&Pm[(((size_t)bh * NCH + ch) * 16 + n) * 4] = v;
}

// ---------------------------------------------------------------- propagate chunk-boundary states
__global__ __launch_bounds__(256) void prop_k(const float* __restrict__ Pm,
                                              const float* __restrict__ pend,
                                              float* __restrict__ sinit) {
  int gid = blockIdx.x * 256 + threadIdx.x;
  int n  = gid & 15;
  int d  = (gid >> 4) & 63;
  int bh = gid >> 10;
  float s0 = 0.f, s1 = 0.f;
  for (int c = 0; c < NCH; ++c) {
    size_t i2 = (((size_t)bh * NCH + c) * 64 + d) * 16 + n;
    *(float2*)&sinit[i2 * 2] = make_float2(s0, s1);
    float4 P  = *(const float4*)&Pm[(((size_t)bh * NCH + c) * 16 + n) * 4];
    float2 pe = *(const float2*)&pend[i2 * 2];
    float t0 = fmaf(P.x, s0, fmaf(P.y, s1, pe.x));
    float t1 = fmaf(P.z, s0, fmaf(P.w, s1, pe.y));
    s0 = t0; s1 = t1;
  }
}

// ---------------------------------------------------------------- chunked scan (u precomputed, f32x2 packed recurrence)
#define T_TILE 16
#define TPC (CH / T_TILE)
template<int PHASE>
__global__ __launch_bounds__(128) void scan_k(
    const __hip_bfloat16* __restrict__ zxb, const float* __restrict__ bcb,
    const float* __restrict__ dtT, const float* __restrict__ A_log,
    const float* __restrict__ Dp, float* __restrict__ states,
    __hip_bfloat16* u_po)
{
  const int blk  = blockIdx.x;
  const int half = blk & 1;
  const int ch   = (blk >> 1) & 15;
  const int h    = (blk >> 5) & 31;
  const int b    = blk >> 10;
  const int bh   = b * 32 + h;
  const int tid  = threadIdx.x;
  const int wv   = tid >> 6;
  const int lane = tid & 63;
  const int d16  = lane & 15;
  const int ng   = lane >> 4;
  const int n0   = ng * 4;
  const int dwv  = wv * 16 + d16;
  const int dl   = half * 32 + dwv;
  const int dbase = h * 64 + half * 32;
  const size_t rowbase = (size_t)b * SEQ + (size_t)ch * CH;

  __shared__ __hip_bfloat16 dut[2][T_TILE][32];
  __shared__ float Btl[2][T_TILE][16];
  __shared__ float Ctl[PHASE == 3 ? 2 : 1][T_TILE][16];
  __shared__ __hip_bfloat16 zt [PHASE == 3 ? 2 : 1][T_TILE][32];
  __shared__ float st [2][T_TILE][16];
  __shared__ float dtt[2][T_TILE];
  __shared__ float aexp[16];
  __shared__ float opart[PHASE == 3 ? T_TILE : 1][32][4];

  if (tid < 16) aexp[tid] = __expf(A_log[h * 16 + tid]);

  f32x2 A2[2];
  #pragma unroll
  for (int k = 0; k < 2; ++k) {
    A2[k][0] = __expf(A_log[h * 16 + n0 + 2 * k]);
    A2[k][1] = __expf(A_log[h * 16 + n0 + 2 * k + 1]);
  }
  const float Dh = Dp[h];

  auto stage = [&](int tile, int buf) {
    const size_t r0 = rowbase + (size_t)tile * T_TILE;
    if constexpr (PHASE == 3) {
      if (wv == 0) {
        // u tile (16 rows x 64B)
        const __hip_bfloat16* g = u_po + (r0 + (lane >> 2)) * D_INNER + dbase + (lane & 3) * 8;
        __hip_bfloat16* l_ = &dut[buf][0][0] + lane * 8;
        __builtin_amdgcn_global_load_lds((const __attribute__((address_space(1))) unsigned int*)g,
                                         (__attribute__((address_space(3))) unsigned int*)l_, 16, 0, 0);
      } else {
        // z tile (bf16, 16 rows x 64B)
        const __hip_bfloat16* gz = zxb + (r0 + (lane >> 2)) * ZX_N + dbase + (lane & 3) * 8;
        __hip_bfloat16* lz = &zt[buf][0][0] + lane * 8;
        __builtin_amdgcn_global_load_lds((const __attribute__((address_space(1))) unsigned int*)gz,
                                         (__attribute__((address_space(3))) unsigned int*)lz, 16, 0, 0);
        // B + C tiles (16 rows x 64B each)
        const float* gB = bcb + (r0 + (lane >> 2)) * 32 + (lane & 3) * 4;
        float* lB = &Btl[buf][0][0] + lane * 4;
        __builtin_amdgcn_global_load_lds((const __attribute__((address_space(1))) unsigned int*)gB,
                                         (__attribute__((address_space(3))) unsigned int*)lB, 16, 0, 0);
        const float* gC = bcb + (r0 + (lane >> 2)) * 32 + 16 + (lane & 3) * 4;
        float* lC = &Ctl[buf][0][0] + lane * 4;
        __builtin_amdgcn_global_load_lds((const __attribute__((address_space(1))) unsigned int*)gC,
                                         (__attribute__((address_space(3))) unsigned int*)lC, 16, 0, 0);
      }
    } else {
      if (wv == 0) {
        const __hip_bfloat16* g = u_po + (r0 + (lane >> 2)) * D_INNER + dbase + (lane & 3) * 8;
        __hip_bfloat16* l_ = &dut[buf][0][0] + lane * 8;
        __builtin_amdgcn_global_load_lds((const __attribute__((address_space(1))) unsigned int*)g,
                                         (__attribute__((address_space(3))) unsigned int*)l_, 16, 0, 0);
      } else {
        const float* gB = bcb + (r0 + (lane >> 2)) * 32 + (lane & 3) * 4;
        float* lB = &Btl[buf][0][0] + lane * 4;
        __builtin_amdgcn_global_load_lds((const __attribute__((address_space(1))) unsigned int*)gB,
                                         (__attribute__((address_space(3))) unsigned int*)lB, 16, 0, 0);
      }
    }
  };

  auto sprep = [&](int buf, float dtn) {
    #pragma unroll
    for (int i = 0; i < 2; ++i) {
      int idx = tid + 128 * i;
      int row = idx >> 4, n = idx & 15;
      float dv = __shfl(dtn, row);
      float a  = aexp[n];
      st[buf][row][n] = 1.0f / fmaf(dv * dv, a, 1.0f);
    }
  };

  stage(0, 0);
  float dtn = 0.f;
  if (lane < 16) dtn = dtT[(size_t)h * ROWS + rowbase + lane];
  __syncthreads();
  if (tid < 16) dtt[0][tid] = dtn;
  sprep(0, dtn);
  __syncthreads();

  f32x2 w2[2], ys2[2];
  if constexpr (PHASE == 1) {
    #pragma unroll
    for (int k = 0; k < 2; ++k) { w2[k] = (f32x2){0.f, 0.f}; ys2[k] = (f32x2){0.f, 0.f}; }
  } else {
    #pragma unroll
    for (int k = 0; k < 2; ++k)
      #pragma unroll
      for (int j = 0; j < 2; ++j) {
        size_t i2 = (((size_t)bh * NCH + ch) * 64 + dl) * 16 + (n0 + 2 * k + j);
        float2 s = *(const float2*)&states[i2 * 2];
        w2[k][j] = s.x; ys2[k][j] = s.y;
      }
  }
  int cur = 0;

  for (int t = 0; t < TPC; ++t) {
    if (t + 1 < TPC) {
      stage(t + 1, cur ^ 1);
      if (lane < 16) dtn = dtT[(size_t)h * ROWS + rowbase + (size_t)(t + 1) * T_TILE + lane];
    }
    #pragma unroll 4
    for (int l = 0; l < T_TILE; ++l) {
      float uv  = __bfloat162float(dut[cur][l][dwv]);
      float dtv = dtt[cur][l];
      f32x4 Sv4 = *(const f32x4*)&st [cur][l][n0];
      f32x4 Bv4 = *(const f32x4*)&Btl[cur][l][n0];
      float du = dtv * uv;
      f32x2 S2[2] = { {Sv4[0], Sv4[1]}, {Sv4[2], Sv4[3]} };
      f32x2 B2[2] = { {Bv4[0], Bv4[1]}, {Bv4[2], Bv4[3]} };
      if constexpr (PHASE == 3) {
        f32x4 Cv4 = *(const f32x4*)&Ctl[cur][l][n0];
        f32x2 C2[2] = { {Cv4[0], Cv4[1]}, {Cv4[2], Cv4[3]} };
        f32x2 o2 = {0.f, 0.f};
        #pragma unroll
        for (int k = 0; k < 2; ++k) {
          f32x2 dtA = dtv * A2[k];
          f32x2 tmp = w2[k] - dtA * ys2[k];
          tmp = tmp + du * B2[k];
          w2[k] = S2[k] * tmp;
          ys2[k] = ys2[k] + dtv * w2[k];
          o2 = o2 + ys2[k] * C2[k];
        }
        float o = o2[0] + o2[1];
        float ofin = (ng == 0) ? fmaf(Dh, uv, o) : o;
        opart[l][dwv][ng] = ofin;
      } else {
        #pragma unroll
        for (int k = 0; k < 2; ++k) {
          f32x2 dtA = dtv * A2[k];
          f32x2 tmp = w2[k] - dtA * ys2[k];
          tmp = tmp + du * B2[k];
          w2[k] = S2[k] * tmp;
          ys2[k] = ys2[k] + dtv * w2[k];
        }
      }
    }
    if constexpr (PHASE == 3) {
      #pragma unroll
      for (int i = 0; i < 4; ++i) {
        int l  = (lane >> 4) + 4 * i;
        int dd = wv * 16 + d16;
        f32x4 op = *(const f32x4*)&opart[l][dd][0];
        float zv = __bfloat162float(zt[cur][l][dd]);
        float yv = (op[0] + op[1]) + (op[2] + op[3]);
        u_po[(rowbase + (size_t)t * T_TILE + l) * D_INNER + dbase + dd] =
            __float2bfloat16(yv * siluf(zv));
      }
    }
    __syncthreads();
    if (t + 1 < TPC) {
      if (tid < 16) dtt[cur ^ 1][tid] = dtn;
      sprep(cur ^ 1, dtn);
      __syncthreads();
    }
    cur ^= 1;
  }

  if constexpr (PHASE == 1) {
    #pragma unroll
    for (int k = 0; k < 2; ++k)
      #pragma unroll
      for (int j = 0; j < 2; ++j) {
        size_t i2 = (((size_t)bh * NCH + ch) * 64 + dl) * 16 + (n0 + 2 * k + j);
        *(float2*)&states[i2 * 2] = make_float2(w2[k][j], ys2[k][j]);
      }
  }
}

// ---------------------------------------------------------------- launch
extern "C" void kernel_launch(void* const* d_in, const int* in_sizes, int n_in,
                              void* d_out, int out_size, void* d_ws, size_t ws_size,
                              hipStream_t stream) {
  const float* x     = (const float*)d_in[0];
  const float* n1w   = (const float*)d_in[1];
  const float* wi    = (const float*)d_in[2];
  const float* cw    = (const float*)d_in[3];
  const float* cb    = (const float*)d_in[4];
  const float* A_log = (const float*)d_in[5];
  const float* dtb   = (const float*)d_in[6];
  const float* Dp    = (const float*)d_in[7];
  const float* wo    = (const float*)d_in[8];
  const float* n2w   = (const float*)d_in[9];
  const float* wg    = (const float*)d_in[10];
  const float* wu    = (const float*)d_in[11];
  const float* wd    = (const float*)d_in[12];
  float* out = (float*)d_out;

  char* p = (char*)d_ws;
  auto take = [&](size_t b) { char* q = p; p += (b + 255) & ~(size_t)255; return q; };
  __hip_bfloat16* wbi  = (__hip_bfloat16*)take((size_t)ZX_N * D_MODEL * 2);       //  8 MB (z,x rows only)
  __hip_bfloat16* wbo  = (__hip_bfloat16*)take((size_t)D_MODEL * D_INNER * 2);
  __hip_bfloat16* wgu  = (__hip_bfloat16*)take((size_t)GU_N * D_MODEL * 2);
  __hip_bfloat16* wbd  = (__hip_bfloat16*)take((size_t)D_MODEL * FFN_DIM * 2);
  __hip_bfloat16* h0b  = (__hip_bfloat16*)take((size_t)ROWS * D_MODEL * 2);
  char*           region = take((size_t)84 * 1024 * 1024);   // h0f(32M f32) / zxb(64M bf16) / h(32M)+gact(44M)
  float*          bcb  = (float*)take((size_t)ROWS * 32 * 4);
  float*          bcraw= (float*)take((size_t)ROWS * 32 * 4);
  float*          dtT  = (float*)take((size_t)ROWS * 32 * 4);
  __hip_bfloat16* po   = (__hip_bfloat16*)take((size_t)ROWS * D_INNER * 2);   // u carrier, then scan output
  float*          pend = (float*)take((size_t)128 * NCH * 64 * 16 * 2 * 4);
  float*          sini = (float*)take((size_t)128 * NCH * 64 * 16 * 2 * 4);
  float*          Pm   = (float*)take((size_t)128 * NCH * 16 * 4 * 4);
  float*          h0f  = (float*)region;
  __hip_bfloat16* zxb  = (__hip_bfloat16*)region;
  float*          h    = (float*)region;
  __hip_bfloat16* gact = (__hip_bfloat16*)(region + 33554432);

  hipFuncSetAttribute(reinterpret_cast<const void*>(&gemm8<5>),  hipFuncAttributeMaxDynamicSharedMemorySize, 131072);
  hipFuncSetAttribute(reinterpret_cast<const void*>(&gemm8<4>),  hipFuncAttributeMaxDynamicSharedMemorySize, 131072);
  hipFuncSetAttribute(reinterpret_cast<const void*>(&gemm8B<1>), hipFuncAttributeMaxDynamicSharedMemorySize, 131072);

  // weight conversions
  cvt_k<<<(ZX_N * D_MODEL + 255) / 256, 256, 0, stream>>>(wi, wbi, ZX_N * D_MODEL);
  cvt_k<<<(D_MODEL * D_INNER + 255) / 256, 256, 0, stream>>>(wo, wbo, D_MODEL * D_INNER);
  cvt_gu_k<<<(GU_N * D_MODEL + 255) / 256, 256, 0, stream>>>(wg, wu, wgu);
  cvt_k<<<(FFN_DIM * D_MODEL + 255) / 256, 256, 0, stream>>>(wd, wbd, FFN_DIM * D_MODEL);

  // mixer
  rmsnorm_k<<<ROWS, 256, 0, stream>>>(x, n1w, h0b, h0f);
  vecproj_k<<<ROWS / 4, 256, 0, stream>>>(h0f, wi, dtb, dtT, bcraw);
  gemm8<5><<<(ROWS / 256) * (ZX_N / 256), 512, 131072, stream>>>(h0b, wbi, nullptr, zxb, nullptr,
                                                                 ROWS, ZX_N, D_MODEL);
  duconv_k<<<ROWS * 512 / 256, 256, 0, stream>>>(zxb, cw, cb, po);
  bcdt_k<<<ROWS / 8, 256, 0, stream>>>(bcraw, cw, cb, bcb);
  pk_k<<<BATCH * N_HEADS, 256, 0, stream>>>(dtT, A_log, Pm);
  scan_k<1><<<BATCH * N_HEADS * NCH * 2, 128, 0, stream>>>(zxb, bcb, dtT, A_log, Dp, pend, po);
  prop_k<<<BATCH * N_HEADS * 64 * 16 / 256, 256, 0, stream>>>(Pm, pend, sini);
  scan_k<3><<<BATCH * N_HEADS * NCH * 2, 128, 0, stream>>>(zxb, bcb, dtT, A_log, Dp, sini, po);
  gemm8B<1><<<(ROWS / 256) * (D_MODEL / 128), 512, 131072, stream>>>(po, wbo, h, nullptr, x,
                                                                     ROWS, D_MODEL, D_INNER);
  // FFN
  rmsnorm_k<<<ROWS, 256, 0, stream>>>(h, n2w, h0b, nullptr);
  gemm8<4><<<(ROWS / 256) * (GU_N / 256), 512, 131072, stream>>>(h0b, wgu, nullptr, gact, nullptr,
                                                                 ROWS, GU_N, D_MODEL);
  gemm8B<1><<<(ROWS / 256) * (D_MODEL / 128), 512, 131072, stream>>>(gact, wbd, out, nullptr, h,
                                                                     ROWS, D_MODEL, FFN_DIM);
}